// Round 2
// baseline (60827.429 us; speedup 1.0000x reference)
//
#include <hip/hip_runtime.h>

#define N_NODES 100000
#define N_EDGES 1600000
#define HD 128
#define NH (N_NODES * HD)

// ---------------------------------------------------------------------------
// GEMM: C[M x Ncols] = A[M x 128] * B (+ bias) (+= C)
//   NT:  B is [Ncols x 128] row-major with row stride ldb (i.e. C = A @ B^T)
//   !NT: B is [128 x Ncols] row-major with row stride ldb (i.e. C = A @ B)
// K is always exactly 128. Ncols must be a multiple of 64.
// Tile: BM=128, BN=64, BK=16, 256 threads, 8x4 per-thread microtile.
// ---------------------------------------------------------------------------
template <bool NT, bool ACC, bool BIAS>
__global__ __launch_bounds__(256) void gemm_k128(
    const float* __restrict__ A, const float* __restrict__ B,
    const float* __restrict__ bias, float* __restrict__ C, int M, int Ncols,
    int ldb) {
  __shared__ float As[16][132];
  __shared__ float Bs[16][68];
  const int tid = threadIdx.x;
  const int row0 = blockIdx.x * 128;
  const int col0 = blockIdx.y * 64;
  const int tx = tid & 15, ty = tid >> 4;

  float acc[8][4];
#pragma unroll
  for (int i = 0; i < 8; i++)
#pragma unroll
    for (int j = 0; j < 4; j++) acc[i][j] = 0.f;

  const int lr = tid >> 2;       // 0..63
  const int kg = (tid & 3) * 4;  // 0,4,8,12

  for (int k0 = 0; k0 < 128; k0 += 16) {
#pragma unroll
    for (int h = 0; h < 2; ++h) {
      int r = lr + h * 64;
      float4 v = make_float4(0.f, 0.f, 0.f, 0.f);
      if (row0 + r < M)
        v = *reinterpret_cast<const float4*>(A + (size_t)(row0 + r) * 128 + k0 + kg);
      As[kg + 0][r] = v.x;
      As[kg + 1][r] = v.y;
      As[kg + 2][r] = v.z;
      As[kg + 3][r] = v.w;
    }
    if (NT) {
      int c = lr;
      float4 v = *reinterpret_cast<const float4*>(B + (size_t)(col0 + c) * ldb + k0 + kg);
      Bs[kg + 0][c] = v.x;
      Bs[kg + 1][c] = v.y;
      Bs[kg + 2][c] = v.z;
      Bs[kg + 3][c] = v.w;
    } else {
      int kk = tid >> 4;
      int cg = (tid & 15) * 4;
      float4 v = *reinterpret_cast<const float4*>(B + (size_t)(k0 + kk) * ldb + col0 + cg);
      Bs[kk][cg + 0] = v.x;
      Bs[kk][cg + 1] = v.y;
      Bs[kk][cg + 2] = v.z;
      Bs[kk][cg + 3] = v.w;
    }
    __syncthreads();
#pragma unroll
    for (int kk = 0; kk < 16; ++kk) {
      float a[8], b[4];
#pragma unroll
      for (int i = 0; i < 8; i++) a[i] = As[kk][ty * 8 + i];
#pragma unroll
      for (int j = 0; j < 4; j++) b[j] = Bs[kk][tx * 4 + j];
#pragma unroll
      for (int i = 0; i < 8; i++)
#pragma unroll
        for (int j = 0; j < 4; j++) acc[i][j] += a[i] * b[j];
    }
    __syncthreads();
  }

#pragma unroll
  for (int i = 0; i < 8; i++) {
    int r = row0 + ty * 8 + i;
    if (r < M) {
#pragma unroll
      for (int j = 0; j < 4; j++) {
        int c = col0 + tx * 4 + j;
        float v = acc[i][j];
        if (BIAS) v += bias[c];
        size_t idx = (size_t)r * Ncols + c;
        if (ACC) v += C[idx];
        C[idx] = v;
      }
    }
  }
}

// ---------------------------------------------------------------------------
// Fused GRU: computes gi = agg@w_ih^T + b_ih, gh = x@w_hh^T + b_hh entirely
// in registers (6 gate slices), applies the GRU update, writes xout.
// Tile: BM=64 rows, BN=32 gate-columns, 256 threads, per-thread 4x2x6 accum.
// xout must NOT alias agg or x (both are read for all k while xout written).
// ---------------------------------------------------------------------------
__global__ __launch_bounds__(256) void gru_fused_k(
    const float* __restrict__ agg, const float* __restrict__ x,
    const float* __restrict__ w_ih, const float* __restrict__ w_hh,
    const float* __restrict__ b_ih, const float* __restrict__ b_hh,
    float* __restrict__ xout, int M) {
  __shared__ float As[2][16][65];   // [agg|x][k][row]
  __shared__ float Bs[6][16][33];   // [slice][k][col]  slices: ir,iz,in,hr,hz,hn
  const int tid = threadIdx.x;
  const int row0 = blockIdx.x * 64;
  const int col0 = blockIdx.y * 32;
  const int tx = tid & 15, ty = tid >> 4;

  float acc[6][4][2];
#pragma unroll
  for (int s = 0; s < 6; s++)
#pragma unroll
    for (int i = 0; i < 4; i++)
#pragma unroll
      for (int j = 0; j < 2; j++) acc[s][i][j] = 0.f;

  const int mat = tid >> 7;           // 0: agg, 1: x
  const int within = tid & 127;
  const int ar = within & 63;         // row within tile
  const int akg = (within >> 6) * 8;  // 0 or 8

  for (int k0 = 0; k0 < 128; k0 += 16) {
    // ---- A tiles (transposed into As[mat][k][row]) ----
    {
      const float* Ab = mat ? x : agg;
      int grow = row0 + ar;
      float4 v1 = make_float4(0.f, 0.f, 0.f, 0.f);
      float4 v2 = make_float4(0.f, 0.f, 0.f, 0.f);
      if (grow < M) {
        v1 = *reinterpret_cast<const float4*>(Ab + (size_t)grow * 128 + k0 + akg);
        v2 = *reinterpret_cast<const float4*>(Ab + (size_t)grow * 128 + k0 + akg + 4);
      }
      As[mat][akg + 0][ar] = v1.x;
      As[mat][akg + 1][ar] = v1.y;
      As[mat][akg + 2][ar] = v1.z;
      As[mat][akg + 3][ar] = v1.w;
      As[mat][akg + 4][ar] = v2.x;
      As[mat][akg + 5][ar] = v2.y;
      As[mat][akg + 6][ar] = v2.z;
      As[mat][akg + 7][ar] = v2.w;
    }
    // ---- B tiles: 6 slices x 32 cols x 16 k = 768 float4 ----
    for (int idx = tid; idx < 768; idx += 256) {
      int part = idx & 3;
      int seg = idx >> 2;  // 0..191
      int s = seg >> 5;    // 0..5
      int c = seg & 31;
      const float* wb = (s < 3) ? w_ih : w_hh;
      int row = (s < 3 ? s : s - 3) * 128 + col0 + c;
      float4 v = *reinterpret_cast<const float4*>(wb + (size_t)row * 128 + k0 + part * 4);
      Bs[s][part * 4 + 0][c] = v.x;
      Bs[s][part * 4 + 1][c] = v.y;
      Bs[s][part * 4 + 2][c] = v.z;
      Bs[s][part * 4 + 3][c] = v.w;
    }
    __syncthreads();
#pragma unroll
    for (int kk = 0; kk < 16; ++kk) {
      float a0[4], a1[4], b[6][2];
#pragma unroll
      for (int i = 0; i < 4; i++) {
        a0[i] = As[0][kk][ty * 4 + i];
        a1[i] = As[1][kk][ty * 4 + i];
      }
#pragma unroll
      for (int s = 0; s < 6; s++)
#pragma unroll
        for (int j = 0; j < 2; j++) b[s][j] = Bs[s][kk][tx * 2 + j];
#pragma unroll
      for (int i = 0; i < 4; i++)
#pragma unroll
        for (int j = 0; j < 2; j++) {
          acc[0][i][j] += a0[i] * b[0][j];
          acc[1][i][j] += a0[i] * b[1][j];
          acc[2][i][j] += a0[i] * b[2][j];
          acc[3][i][j] += a1[i] * b[3][j];
          acc[4][i][j] += a1[i] * b[4][j];
          acc[5][i][j] += a1[i] * b[5][j];
        }
    }
    __syncthreads();
  }

#pragma unroll
  for (int i = 0; i < 4; i++) {
    int r_ = row0 + ty * 4 + i;
    if (r_ >= M) continue;
#pragma unroll
    for (int j = 0; j < 2; j++) {
      int c_ = col0 + tx * 2 + j;
      float ir = acc[0][i][j] + b_ih[c_];
      float iz = acc[1][i][j] + b_ih[128 + c_];
      float in_ = acc[2][i][j] + b_ih[256 + c_];
      float hr = acc[3][i][j] + b_hh[c_];
      float hz = acc[4][i][j] + b_hh[128 + c_];
      float hn = acc[5][i][j] + b_hh[256 + c_];
      float rg = 1.f / (1.f + __expf(-(ir + hr)));
      float zg = 1.f / (1.f + __expf(-(iz + hz)));
      float ng = tanhf(in_ + rg * hn);
      float h = x[(size_t)r_ * 128 + c_];
      xout[(size_t)r_ * 128 + c_] = (1.f - zg) * ng + zg * h;
    }
  }
}

// ---------------------------------------------------------------------------
// agg[dst[e]] += m[src[e]]
// ---------------------------------------------------------------------------
__global__ __launch_bounds__(256) void scatter_add_k(
    const float* __restrict__ m, const int* __restrict__ src,
    const int* __restrict__ dst, float* __restrict__ agg) {
  int gid = blockIdx.x * 256 + threadIdx.x;
  if (gid >= N_EDGES * 32) return;
  int e = gid >> 5;
  int c = (gid & 31) * 4;
  int s = src[e], d = dst[e];
  const float4 v = *reinterpret_cast<const float4*>(m + (size_t)s * 128 + c);
  float* p = agg + (size_t)d * 128 + c;
  atomicAdd(p + 0, v.x);
  atomicAdd(p + 1, v.y);
  atomicAdd(p + 2, v.z);
  atomicAdd(p + 3, v.w);
}

__global__ __launch_bounds__(256) void init_hidden_k(float* __restrict__ hidden,
                                                     const float* __restrict__ cat_b) {
  int gid = blockIdx.x * 256 + threadIdx.x;
  if (gid >= NH) return;
  hidden[gid] = cat_b[gid & 127];
}

__global__ __launch_bounds__(256) void add_k(const float* __restrict__ a,
                                             const float* __restrict__ b,
                                             float* __restrict__ c) {
  int gid = blockIdx.x * 256 + threadIdx.x;
  if (gid >= NH) return;
  c[gid] = a[gid] + b[gid];
}

// lineout = hidden @ line_w^T + line_b   ([N,128] -> [N,16])
__global__ __launch_bounds__(256) void lineout_k(
    const float* __restrict__ hidden, const float* __restrict__ W,
    const float* __restrict__ b, float* __restrict__ out) {
  __shared__ float Ws[16 * 128];
  for (int i = threadIdx.x; i < 2048; i += 256) Ws[i] = W[i];
  __syncthreads();
  int r = threadIdx.x >> 4, c = threadIdx.x & 15;
  int n = blockIdx.x * 16 + r;
  if (n >= N_NODES) return;
  const float* h = hidden + (size_t)n * 128;
  const float* w = Ws + c * 128;
  float acc = 0.f;
#pragma unroll 8
  for (int k = 0; k < 128; k++) acc += h[k] * w[k];
  out[(size_t)n * 16 + c] = acc + b[c];
}

// gate[n] = hidden[n] . gate_w + gate_b;  atomicMax per-graph (ordered-uint)
__global__ __launch_bounds__(256) void gate_k(
    const float* __restrict__ hidden, const float* __restrict__ gw,
    const float* __restrict__ gb, const int* __restrict__ batch,
    float* __restrict__ gate, unsigned* __restrict__ gmax_u) {
  int wid = (blockIdx.x * 256 + threadIdx.x) >> 6;
  int lane = threadIdx.x & 63;
  if (wid >= N_NODES) return;
  const float* h = hidden + (size_t)wid * 128;
  float s = h[lane] * gw[lane] + h[64 + lane] * gw[64 + lane];
#pragma unroll
  for (int off = 32; off; off >>= 1) s += __shfl_down(s, off);
  if (lane == 0) {
    float g = s + gb[0];
    gate[wid] = g;
    unsigned u = __float_as_uint(g);
    unsigned e = (u & 0x80000000u) ? ~u : (u | 0x80000000u);
    atomicMax(&gmax_u[batch[wid]], e);
  }
}

__global__ void init_seg_k(unsigned* __restrict__ gmax_u, float* __restrict__ denom) {
  int t = threadIdx.x;     // 512 threads
  gmax_u[t] = 0x007FFFFFu; // encoding of -inf
  denom[t] = 0.f;
}

__global__ __launch_bounds__(256) void exp_k(
    const float* __restrict__ gate, const unsigned* __restrict__ gmax_u,
    const int* __restrict__ batch, float* __restrict__ ex,
    float* __restrict__ denom) {
  int n = blockIdx.x * 256 + threadIdx.x;
  if (n >= N_NODES) return;
  int g = batch[n];
  unsigned e = gmax_u[g];
  unsigned u = (e & 0x80000000u) ? (e & 0x7FFFFFFFu) : ~e;
  float mx = __uint_as_float(u);
  float v = __expf(gate[n] - mx);
  ex[n] = v;
  atomicAdd(&denom[g], v);
}

__global__ __launch_bounds__(256) void pool_k(
    const float* __restrict__ hidden, const float* __restrict__ ex,
    const float* __restrict__ denom, const int* __restrict__ batch,
    float* __restrict__ pooled) {
  int gid = blockIdx.x * 256 + threadIdx.x;
  if (gid >= N_NODES * 32) return;
  int n = gid >> 5;
  int c = (gid & 31) * 4;
  int g = batch[n];
  float a = ex[n] / denom[g];
  float4 h = *reinterpret_cast<const float4*>(hidden + (size_t)n * 128 + c);
  float* p = pooled + (size_t)g * 128 + c;
  atomicAdd(p + 0, a * h.x);
  atomicAdd(p + 1, a * h.y);
  atomicAdd(p + 2, a * h.z);
  atomicAdd(p + 3, a * h.w);
}

__global__ void mlp1_k(const float* __restrict__ pooled, const float* __restrict__ w,
                       const float* __restrict__ b, float* __restrict__ h1) {
  int g = blockIdx.x, j = threadIdx.x;  // 64 threads
  const float* p = pooled + (size_t)g * 128;
  const float* wr = w + (size_t)j * 128;
  float acc = 0.f;
#pragma unroll 8
  for (int k = 0; k < 128; k++) acc += p[k] * wr[k];
  acc += b[j];
  h1[g * 64 + j] = acc > 0.f ? acc : 0.f;
}

__global__ void mlp2_k(const float* __restrict__ h1, const float* __restrict__ w,
                       const float* __restrict__ b, float* __restrict__ h2) {
  int g = blockIdx.x, j = threadIdx.x;
  const float* p = h1 + (size_t)g * 64;
  const float* wr = w + (size_t)j * 64;
  float acc = 0.f;
#pragma unroll 8
  for (int k = 0; k < 64; k++) acc += p[k] * wr[k];
  acc += b[j];
  h2[g * 64 + j] = acc > 0.f ? acc : 0.f;
}

__global__ void outhead_k(const float* __restrict__ h2, const float* __restrict__ w,
                          const float* __restrict__ b, float* __restrict__ out) {
  int g = blockIdx.x, j = threadIdx.x;
  if (j >= 16) return;
  const float* p = h2 + (size_t)g * 64;
  const float* wr = w + (size_t)j * 64;
  float acc = 0.f;
#pragma unroll 8
  for (int k = 0; k < 64; k++) acc += p[k] * wr[k];
  out[g * 16 + j] = acc + b[j];
}

extern "C" void kernel_launch(void* const* d_in, const int* in_sizes, int n_in,
                              void* d_out, int out_size, void* d_ws, size_t ws_size,
                              hipStream_t stream) {
  const float* node_embed = (const float*)d_in[0];
  const int* eidx = (const int*)d_in[1];
  const int* batch = (const int*)d_in[2];
  const float* node_w = (const float*)d_in[3];
  const float* node_b = (const float*)d_in[4];
  const float* ggc_w = (const float*)d_in[5];
  const float* w_ih = (const float*)d_in[6];
  const float* w_hh = (const float*)d_in[7];
  const float* b_ih = (const float*)d_in[8];
  const float* b_hh = (const float*)d_in[9];
  const float* cat_w = (const float*)d_in[10];
  const float* cat_b = (const float*)d_in[11];
  const float* gate_w = (const float*)d_in[12];
  const float* gate_b = (const float*)d_in[13];
  const float* mlp_w1 = (const float*)d_in[14];
  const float* mlp_b1 = (const float*)d_in[15];
  const float* mlp_w2 = (const float*)d_in[16];
  const float* mlp_b2 = (const float*)d_in[17];
  const float* out_w = (const float*)d_in[18];
  const float* out_b = (const float*)d_in[19];
  const float* line_w = (const float*)d_in[20];
  const float* line_b = (const float*)d_in[21];

  const int* src = eidx;
  const int* dst = eidx + N_EDGES;

  // workspace layout (floats), total 5*NH = 256 MB:
  //   h0[NH] | hidden[NH] | x0[NH] | mbuf[NH] | agg[NH]
  float* ws = (float*)d_ws;
  float* h0 = ws;
  float* hidden = h0 + (size_t)NH;
  float* x0 = hidden + (size_t)NH;
  float* mbuf = x0 + (size_t)NH;
  float* agg = mbuf + (size_t)NH;

  float* out_graph = (float*)d_out;            // [512,16]
  float* out_line = (float*)d_out + 512 * 16;  // [100000,16]

  dim3 blk(256);
  const int gM128 = (N_NODES + 127) / 128;
  const int gM64 = (N_NODES + 63) / 64;
  const int gNH = (NH + 255) / 256;

  // h0 = node_embed @ node_w^T + node_b
  gemm_k128<true, false, true><<<dim3(gM128, 2), blk, 0, stream>>>(
      node_embed, node_w, node_b, h0, N_NODES, 128, 128);
  // hidden starts as broadcast cat_b; cat GEMM accumulates into it per block
  init_hidden_k<<<gNH, blk, 0, stream>>>(hidden, cat_b);

  float* xcur = x0;
  float* xalt = mbuf;
  for (int k = 0; k < 4; k++) {
    hipMemcpyAsync(xcur, h0, (size_t)NH * 4, hipMemcpyDeviceToDevice, stream);
    for (int i = 0; i < 4; i++) {
      // m = x @ W[k][i]  -> xalt
      gemm_k128<false, false, false><<<dim3(gM128, 2), blk, 0, stream>>>(
          xcur, ggc_w + (size_t)(k * 4 + i) * 128 * 128, nullptr, xalt, N_NODES, 128, 128);
      // agg = scatter_add(m[src], dst)
      hipMemsetAsync(agg, 0, (size_t)NH * 4, stream);
      scatter_add_k<<<(N_EDGES * 32 + 255) / 256, blk, 0, stream>>>(xalt, src, dst, agg);
      // x_new = GRU(agg, x)  -> xalt (m is dead; xalt != xcur, agg)
      gru_fused_k<<<dim3(gM64, 4), blk, 0, stream>>>(
          agg, xcur, w_ih + (size_t)k * 384 * 128, w_hh + (size_t)k * 384 * 128,
          b_ih + k * 384, b_hh + k * 384, xalt, N_NODES);
      float* t = xcur; xcur = xalt; xalt = t;
    }
    // residual: xalt = x + h0 ; hidden += xalt @ cat_w[:, k*128:(k+1)*128]^T
    add_k<<<gNH, blk, 0, stream>>>(xcur, h0, xalt);
    gemm_k128<true, true, false><<<dim3(gM128, 2), blk, 0, stream>>>(
        xalt, cat_w + k * 128, nullptr, hidden, N_NODES, 128, 512);
  }
  // after 4 swaps per block, xcur == x0, xalt == mbuf again

  // lineout head
  lineout_k<<<(N_NODES + 15) / 16, blk, 0, stream>>>(hidden, line_w, line_b, out_line);

  // attentional aggregation + MLP heads (reuse dead buffers)
  float* gate = mbuf;
  float* ex = mbuf + N_NODES;
  unsigned* gmax_u = (unsigned*)agg;
  float* denom = agg + 512;
  float* pooled = agg + 1024;
  float* h1 = pooled + 512 * 128;
  float* h2 = h1 + 512 * 64;

  init_seg_k<<<1, 512, 0, stream>>>(gmax_u, denom);
  gate_k<<<(N_NODES * 64 + 255) / 256, blk, 0, stream>>>(hidden, gate_w, gate_b,
                                                         batch, gate, gmax_u);
  exp_k<<<(N_NODES + 255) / 256, blk, 0, stream>>>(gate, gmax_u, batch, ex, denom);
  hipMemsetAsync(pooled, 0, 512 * 128 * 4, stream);
  pool_k<<<(N_NODES * 32 + 255) / 256, blk, 0, stream>>>(hidden, ex, denom, batch, pooled);
  mlp1_k<<<512, 64, 0, stream>>>(pooled, mlp_w1, mlp_b1, h1);
  mlp2_k<<<512, 64, 0, stream>>>(h1, mlp_w2, mlp_b2, h2);
  outhead_k<<<512, 64, 0, stream>>>(h2, out_w, out_b, out_graph);
}

// Round 3
// 16516.930 us; speedup vs baseline: 3.6827x; 3.6827x over previous
//
#include <hip/hip_runtime.h>

#define N_NODES 100000
#define N_EDGES 1600000
#define HD 128
#define NH (N_NODES * HD)

// ---------------------------------------------------------------------------
// GEMM: C[M x Ncols] = A[M x 128] * B (+ bias) (+= C)
//   NT:  B is [Ncols x 128] row-major with row stride ldb (i.e. C = A @ B^T)
//   !NT: B is [128 x Ncols] row-major with row stride ldb (i.e. C = A @ B)
// K is always exactly 128. Ncols must be a multiple of 64.
// ---------------------------------------------------------------------------
template <bool NT, bool ACC, bool BIAS>
__global__ __launch_bounds__(256) void gemm_k128(
    const float* __restrict__ A, const float* __restrict__ B,
    const float* __restrict__ bias, float* __restrict__ C, int M, int Ncols,
    int ldb) {
  __shared__ float As[16][132];
  __shared__ float Bs[16][68];
  const int tid = threadIdx.x;
  const int row0 = blockIdx.x * 128;
  const int col0 = blockIdx.y * 64;
  const int tx = tid & 15, ty = tid >> 4;

  float acc[8][4];
#pragma unroll
  for (int i = 0; i < 8; i++)
#pragma unroll
    for (int j = 0; j < 4; j++) acc[i][j] = 0.f;

  const int lr = tid >> 2;       // 0..63
  const int kg = (tid & 3) * 4;  // 0,4,8,12

  for (int k0 = 0; k0 < 128; k0 += 16) {
#pragma unroll
    for (int h = 0; h < 2; ++h) {
      int r = lr + h * 64;
      float4 v = make_float4(0.f, 0.f, 0.f, 0.f);
      if (row0 + r < M)
        v = *reinterpret_cast<const float4*>(A + (size_t)(row0 + r) * 128 + k0 + kg);
      As[kg + 0][r] = v.x;
      As[kg + 1][r] = v.y;
      As[kg + 2][r] = v.z;
      As[kg + 3][r] = v.w;
    }
    if (NT) {
      int c = lr;
      float4 v = *reinterpret_cast<const float4*>(B + (size_t)(col0 + c) * ldb + k0 + kg);
      Bs[kg + 0][c] = v.x;
      Bs[kg + 1][c] = v.y;
      Bs[kg + 2][c] = v.z;
      Bs[kg + 3][c] = v.w;
    } else {
      int kk = tid >> 4;
      int cg = (tid & 15) * 4;
      float4 v = *reinterpret_cast<const float4*>(B + (size_t)(k0 + kk) * ldb + col0 + cg);
      Bs[kk][cg + 0] = v.x;
      Bs[kk][cg + 1] = v.y;
      Bs[kk][cg + 2] = v.z;
      Bs[kk][cg + 3] = v.w;
    }
    __syncthreads();
#pragma unroll
    for (int kk = 0; kk < 16; ++kk) {
      float a[8], b[4];
#pragma unroll
      for (int i = 0; i < 8; i++) a[i] = As[kk][ty * 8 + i];
#pragma unroll
      for (int j = 0; j < 4; j++) b[j] = Bs[kk][tx * 4 + j];
#pragma unroll
      for (int i = 0; i < 8; i++)
#pragma unroll
        for (int j = 0; j < 4; j++) acc[i][j] += a[i] * b[j];
    }
    __syncthreads();
  }

#pragma unroll
  for (int i = 0; i < 8; i++) {
    int r = row0 + ty * 8 + i;
    if (r < M) {
#pragma unroll
      for (int j = 0; j < 4; j++) {
        int c = col0 + tx * 4 + j;
        float v = acc[i][j];
        if (BIAS) v += bias[c];
        size_t idx = (size_t)r * Ncols + c;
        if (ACC) v += C[idx];
        C[idx] = v;
      }
    }
  }
}

// ---------------------------------------------------------------------------
// Fused GRU: gi = aggpre@WcT^T + b_ih (WcT pre-folds msg weight & w_ih),
// gh = x@w_hh^T + b_hh, all 6 gate slices in registers, GRU update -> xout.
// Tile: BM=64 rows, BN=32 gate-cols, 256 threads.
// xout must NOT alias aggpre or x.
// ---------------------------------------------------------------------------
__global__ __launch_bounds__(256) void gru_fused_k(
    const float* __restrict__ agg, const float* __restrict__ x,
    const float* __restrict__ w_ih, const float* __restrict__ w_hh,
    const float* __restrict__ b_ih, const float* __restrict__ b_hh,
    float* __restrict__ xout, int M) {
  __shared__ float As[2][16][65];   // [agg|x][k][row]
  __shared__ float Bs[6][16][33];   // [slice][k][col]
  const int tid = threadIdx.x;
  const int row0 = blockIdx.x * 64;
  const int col0 = blockIdx.y * 32;
  const int tx = tid & 15, ty = tid >> 4;

  float acc[6][4][2];
#pragma unroll
  for (int s = 0; s < 6; s++)
#pragma unroll
    for (int i = 0; i < 4; i++)
#pragma unroll
      for (int j = 0; j < 2; j++) acc[s][i][j] = 0.f;

  const int mat = tid >> 7;
  const int within = tid & 127;
  const int ar = within & 63;
  const int akg = (within >> 6) * 8;

  for (int k0 = 0; k0 < 128; k0 += 16) {
    {
      const float* Ab = mat ? x : agg;
      int grow = row0 + ar;
      float4 v1 = make_float4(0.f, 0.f, 0.f, 0.f);
      float4 v2 = make_float4(0.f, 0.f, 0.f, 0.f);
      if (grow < M) {
        v1 = *reinterpret_cast<const float4*>(Ab + (size_t)grow * 128 + k0 + akg);
        v2 = *reinterpret_cast<const float4*>(Ab + (size_t)grow * 128 + k0 + akg + 4);
      }
      As[mat][akg + 0][ar] = v1.x;
      As[mat][akg + 1][ar] = v1.y;
      As[mat][akg + 2][ar] = v1.z;
      As[mat][akg + 3][ar] = v1.w;
      As[mat][akg + 4][ar] = v2.x;
      As[mat][akg + 5][ar] = v2.y;
      As[mat][akg + 6][ar] = v2.z;
      As[mat][akg + 7][ar] = v2.w;
    }
    for (int idx = tid; idx < 768; idx += 256) {
      int part = idx & 3;
      int seg = idx >> 2;
      int s = seg >> 5;
      int c = seg & 31;
      const float* wb = (s < 3) ? w_ih : w_hh;
      int row = (s < 3 ? s : s - 3) * 128 + col0 + c;
      float4 v = *reinterpret_cast<const float4*>(wb + (size_t)row * 128 + k0 + part * 4);
      Bs[s][part * 4 + 0][c] = v.x;
      Bs[s][part * 4 + 1][c] = v.y;
      Bs[s][part * 4 + 2][c] = v.z;
      Bs[s][part * 4 + 3][c] = v.w;
    }
    __syncthreads();
#pragma unroll
    for (int kk = 0; kk < 16; ++kk) {
      float a0[4], a1[4], b[6][2];
#pragma unroll
      for (int i = 0; i < 4; i++) {
        a0[i] = As[0][kk][ty * 4 + i];
        a1[i] = As[1][kk][ty * 4 + i];
      }
#pragma unroll
      for (int s = 0; s < 6; s++)
#pragma unroll
        for (int j = 0; j < 2; j++) b[s][j] = Bs[s][kk][tx * 2 + j];
#pragma unroll
      for (int i = 0; i < 4; i++)
#pragma unroll
        for (int j = 0; j < 2; j++) {
          acc[0][i][j] += a0[i] * b[0][j];
          acc[1][i][j] += a0[i] * b[1][j];
          acc[2][i][j] += a0[i] * b[2][j];
          acc[3][i][j] += a1[i] * b[3][j];
          acc[4][i][j] += a1[i] * b[4][j];
          acc[5][i][j] += a1[i] * b[5][j];
        }
    }
    __syncthreads();
  }

#pragma unroll
  for (int i = 0; i < 4; i++) {
    int r_ = row0 + ty * 4 + i;
    if (r_ >= M) continue;
#pragma unroll
    for (int j = 0; j < 2; j++) {
      int c_ = col0 + tx * 2 + j;
      float ir = acc[0][i][j] + b_ih[c_];
      float iz = acc[1][i][j] + b_ih[128 + c_];
      float in_ = acc[2][i][j] + b_ih[256 + c_];
      float hr = acc[3][i][j] + b_hh[c_];
      float hz = acc[4][i][j] + b_hh[128 + c_];
      float hn = acc[5][i][j] + b_hh[256 + c_];
      float rg = 1.f / (1.f + __expf(-(ir + hr)));
      float zg = 1.f / (1.f + __expf(-(iz + hz)));
      float ng = tanhf(in_ + rg * hn);
      float h = x[(size_t)r_ * 128 + c_];
      xout[(size_t)r_ * 128 + c_] = (1.f - zg) * ng + zg * h;
    }
  }
}

// ---------------------------------------------------------------------------
// CSR build: degree histogram -> exclusive scan -> positional fill
// ---------------------------------------------------------------------------
__global__ __launch_bounds__(256) void deg_hist_k(const int* __restrict__ dst,
                                                  int* __restrict__ deg) {
  int e = blockIdx.x * 256 + threadIdx.x;
  if (e >= N_EDGES) return;
  atomicAdd(&deg[dst[e]], 1);
}

__global__ __launch_bounds__(1024) void scan_k(const int* __restrict__ deg,
                                               int* __restrict__ offsets) {
  __shared__ int buf[1024];
  __shared__ int base_s;
  int tid = threadIdx.x;
  if (tid == 0) base_s = 0;
  __syncthreads();
  for (int chunk = 0; chunk < N_NODES; chunk += 1024) {
    int idx = chunk + tid;
    int v = (idx < N_NODES) ? deg[idx] : 0;
    buf[tid] = v;
    __syncthreads();
    for (int off = 1; off < 1024; off <<= 1) {
      int t = (tid >= off) ? buf[tid - off] : 0;
      __syncthreads();
      buf[tid] += t;
      __syncthreads();
    }
    int incl = buf[tid];
    int base = base_s;
    if (idx < N_NODES) offsets[idx] = base + incl - v;
    __syncthreads();
    if (tid == 1023) base_s = base + incl;
    __syncthreads();
  }
  if (tid == 0) offsets[N_NODES] = base_s;
}

__global__ __launch_bounds__(256) void copy_int_k(const int* __restrict__ a,
                                                  int* __restrict__ b, int n) {
  int i = blockIdx.x * 256 + threadIdx.x;
  if (i < n) b[i] = a[i];
}

__global__ __launch_bounds__(256) void fill_k(const int* __restrict__ src,
                                              const int* __restrict__ dst,
                                              int* __restrict__ cursor,
                                              int* __restrict__ srcs_sorted) {
  int e = blockIdx.x * 256 + threadIdx.x;
  if (e >= N_EDGES) return;
  int pos = atomicAdd(&cursor[dst[e]], 1);
  srcs_sorted[pos] = src[e];
}

// ---------------------------------------------------------------------------
// aggpre[n] = sum over incoming edges of x[src]; one wave per node, float2/lane
// ---------------------------------------------------------------------------
__global__ __launch_bounds__(256) void gather_k(
    const float* __restrict__ x, const int* __restrict__ offsets,
    const int* __restrict__ srcs, float* __restrict__ out) {
  int node = (blockIdx.x * 256 + threadIdx.x) >> 6;
  int lane = threadIdx.x & 63;
  if (node >= N_NODES) return;
  int beg = offsets[node], end = offsets[node + 1];
  float2 acc = make_float2(0.f, 0.f);
  for (int e = beg; e < end; e++) {
    int s = srcs[e];
    float2 v = *reinterpret_cast<const float2*>(x + (size_t)s * 128 + lane * 2);
    acc.x += v.x;
    acc.y += v.y;
  }
  *reinterpret_cast<float2*>(out + (size_t)node * 128 + lane * 2) = acc;
}

__global__ __launch_bounds__(256) void init_hidden_k(float* __restrict__ hidden,
                                                     const float* __restrict__ cat_b) {
  int gid = blockIdx.x * 256 + threadIdx.x;
  if (gid >= NH) return;
  hidden[gid] = cat_b[gid & 127];
}

__global__ __launch_bounds__(256) void add_k(const float* __restrict__ a,
                                             const float* __restrict__ b,
                                             float* __restrict__ c) {
  int gid = blockIdx.x * 256 + threadIdx.x;
  if (gid >= NH) return;
  c[gid] = a[gid] + b[gid];
}

// lineout = hidden @ line_w^T + line_b   ([N,128] -> [N,16])
__global__ __launch_bounds__(256) void lineout_k(
    const float* __restrict__ hidden, const float* __restrict__ W,
    const float* __restrict__ b, float* __restrict__ out) {
  __shared__ float Ws[16 * 128];
  for (int i = threadIdx.x; i < 2048; i += 256) Ws[i] = W[i];
  __syncthreads();
  int r = threadIdx.x >> 4, c = threadIdx.x & 15;
  int n = blockIdx.x * 16 + r;
  if (n >= N_NODES) return;
  const float* h = hidden + (size_t)n * 128;
  const float* w = Ws + c * 128;
  float acc = 0.f;
#pragma unroll 8
  for (int k = 0; k < 128; k++) acc += h[k] * w[k];
  out[(size_t)n * 16 + c] = acc + b[c];
}

__global__ __launch_bounds__(256) void gate_k(
    const float* __restrict__ hidden, const float* __restrict__ gw,
    const float* __restrict__ gb, const int* __restrict__ batch,
    float* __restrict__ gate, unsigned* __restrict__ gmax_u) {
  int wid = (blockIdx.x * 256 + threadIdx.x) >> 6;
  int lane = threadIdx.x & 63;
  if (wid >= N_NODES) return;
  const float* h = hidden + (size_t)wid * 128;
  float s = h[lane] * gw[lane] + h[64 + lane] * gw[64 + lane];
#pragma unroll
  for (int off = 32; off; off >>= 1) s += __shfl_down(s, off);
  if (lane == 0) {
    float g = s + gb[0];
    gate[wid] = g;
    unsigned u = __float_as_uint(g);
    unsigned e = (u & 0x80000000u) ? ~u : (u | 0x80000000u);
    atomicMax(&gmax_u[batch[wid]], e);
  }
}

__global__ void init_seg_k(unsigned* __restrict__ gmax_u, float* __restrict__ denom) {
  int t = threadIdx.x;     // 512 threads
  gmax_u[t] = 0x007FFFFFu; // encoding of -inf
  denom[t] = 0.f;
}

__global__ __launch_bounds__(256) void exp_k(
    const float* __restrict__ gate, const unsigned* __restrict__ gmax_u,
    const int* __restrict__ batch, float* __restrict__ ex,
    float* __restrict__ denom) {
  int n = blockIdx.x * 256 + threadIdx.x;
  if (n >= N_NODES) return;
  int g = batch[n];
  unsigned e = gmax_u[g];
  unsigned u = (e & 0x80000000u) ? (e & 0x7FFFFFFFu) : ~e;
  float mx = __uint_as_float(u);
  float v = __expf(gate[n] - mx);
  ex[n] = v;
  atomicAdd(&denom[g], v);
}

__global__ __launch_bounds__(256) void pool_k(
    const float* __restrict__ hidden, const float* __restrict__ ex,
    const float* __restrict__ denom, const int* __restrict__ batch,
    float* __restrict__ pooled) {
  int gid = blockIdx.x * 256 + threadIdx.x;
  if (gid >= N_NODES * 32) return;
  int n = gid >> 5;
  int c = (gid & 31) * 4;
  int g = batch[n];
  float a = ex[n] / denom[g];
  float4 h = *reinterpret_cast<const float4*>(hidden + (size_t)n * 128 + c);
  float* p = pooled + (size_t)g * 128 + c;
  atomicAdd(p + 0, a * h.x);
  atomicAdd(p + 1, a * h.y);
  atomicAdd(p + 2, a * h.z);
  atomicAdd(p + 3, a * h.w);
}

__global__ void mlp1_k(const float* __restrict__ pooled, const float* __restrict__ w,
                       const float* __restrict__ b, float* __restrict__ h1) {
  int g = blockIdx.x, j = threadIdx.x;  // 64 threads
  const float* p = pooled + (size_t)g * 128;
  const float* wr = w + (size_t)j * 128;
  float acc = 0.f;
#pragma unroll 8
  for (int k = 0; k < 128; k++) acc += p[k] * wr[k];
  acc += b[j];
  h1[g * 64 + j] = acc > 0.f ? acc : 0.f;
}

__global__ void mlp2_k(const float* __restrict__ h1, const float* __restrict__ w,
                       const float* __restrict__ b, float* __restrict__ h2) {
  int g = blockIdx.x, j = threadIdx.x;
  const float* p = h1 + (size_t)g * 64;
  const float* wr = w + (size_t)j * 64;
  float acc = 0.f;
#pragma unroll 8
  for (int k = 0; k < 64; k++) acc += p[k] * wr[k];
  acc += b[j];
  h2[g * 64 + j] = acc > 0.f ? acc : 0.f;
}

__global__ void outhead_k(const float* __restrict__ h2, const float* __restrict__ w,
                          const float* __restrict__ b, float* __restrict__ out) {
  int g = blockIdx.x, j = threadIdx.x;
  if (j >= 16) return;
  const float* p = h2 + (size_t)g * 64;
  const float* wr = w + (size_t)j * 64;
  float acc = 0.f;
#pragma unroll 8
  for (int k = 0; k < 64; k++) acc += p[k] * wr[k];
  out[g * 16 + j] = acc + b[j];
}

extern "C" void kernel_launch(void* const* d_in, const int* in_sizes, int n_in,
                              void* d_out, int out_size, void* d_ws, size_t ws_size,
                              hipStream_t stream) {
  const float* node_embed = (const float*)d_in[0];
  const int* eidx = (const int*)d_in[1];
  const int* batch = (const int*)d_in[2];
  const float* node_w = (const float*)d_in[3];
  const float* node_b = (const float*)d_in[4];
  const float* ggc_w = (const float*)d_in[5];
  const float* w_ih = (const float*)d_in[6];
  const float* w_hh = (const float*)d_in[7];
  const float* b_ih = (const float*)d_in[8];
  const float* b_hh = (const float*)d_in[9];
  const float* cat_w = (const float*)d_in[10];
  const float* cat_b = (const float*)d_in[11];
  const float* gate_w = (const float*)d_in[12];
  const float* gate_b = (const float*)d_in[13];
  const float* mlp_w1 = (const float*)d_in[14];
  const float* mlp_b1 = (const float*)d_in[15];
  const float* mlp_w2 = (const float*)d_in[16];
  const float* mlp_b2 = (const float*)d_in[17];
  const float* out_w = (const float*)d_in[18];
  const float* out_b = (const float*)d_in[19];
  const float* line_w = (const float*)d_in[20];
  const float* line_b = (const float*)d_in[21];

  const int* src = eidx;
  const int* dst = eidx + N_EDGES;

  // workspace layout: 5*NH floats (256 MB) + WcT (3.1 MB) + CSR (7.2 MB)
  float* ws = (float*)d_ws;
  float* h0 = ws;
  float* hidden = h0 + (size_t)NH;
  float* xA = hidden + (size_t)NH;
  float* xB = xA + (size_t)NH;
  float* aggpre = xB + (size_t)NH;
  float* WcT = aggpre + (size_t)NH;              // [16][384][128]
  int* offsets = (int*)(WcT + 16 * 384 * 128);   // [N_NODES+1]
  int* cursor = offsets + N_NODES + 1;           // [N_NODES] (also deg)
  int* srcs_sorted = cursor + N_NODES;           // [N_EDGES]

  float* out_graph = (float*)d_out;            // [512,16]
  float* out_line = (float*)d_out + 512 * 16;  // [100000,16]

  dim3 blk(256);
  const int gM128 = (N_NODES + 127) / 128;
  const int gM64 = (N_NODES + 63) / 64;
  const int gNH = (NH + 255) / 256;
  const int gE = (N_EDGES + 255) / 256;

  // ---- CSR build (once per launch) ----
  hipMemsetAsync(cursor, 0, N_NODES * sizeof(int), stream);
  deg_hist_k<<<gE, blk, 0, stream>>>(dst, cursor);
  scan_k<<<1, 1024, 0, stream>>>(cursor, offsets);
  copy_int_k<<<(N_NODES + 255) / 256, blk, 0, stream>>>(offsets, cursor, N_NODES);
  fill_k<<<gE, blk, 0, stream>>>(src, dst, cursor, srcs_sorted);

  // ---- WcT[k,i] = w_ih[k] @ ggc_w[k,i]^T  ([384,128], folds msg GEMM) ----
  for (int k = 0; k < 4; k++)
    for (int i = 0; i < 4; i++)
      gemm_k128<true, false, false><<<dim3(3, 2), blk, 0, stream>>>(
          w_ih + (size_t)k * 384 * 128, ggc_w + (size_t)(k * 4 + i) * 128 * 128,
          nullptr, WcT + (size_t)(k * 4 + i) * 384 * 128, 384, 128, 128);

  // h0 = node_embed @ node_w^T + node_b
  gemm_k128<true, false, true><<<dim3(gM128, 2), blk, 0, stream>>>(
      node_embed, node_w, node_b, h0, N_NODES, 128, 128);
  init_hidden_k<<<gNH, blk, 0, stream>>>(hidden, cat_b);

  float* xcur = xA;
  float* xalt = xB;
  for (int k = 0; k < 4; k++) {
    hipMemcpyAsync(xcur, h0, (size_t)NH * 4, hipMemcpyDeviceToDevice, stream);
    for (int i = 0; i < 4; i++) {
      // aggpre = segment_sum(x[src], dst)
      gather_k<<<(N_NODES * 64 + 255) / 256, blk, 0, stream>>>(xcur, offsets,
                                                               srcs_sorted, aggpre);
      // x_new = GRU(aggpre via WcT, x)
      gru_fused_k<<<dim3(gM64, 4), blk, 0, stream>>>(
          aggpre, xcur, WcT + (size_t)(k * 4 + i) * 384 * 128,
          w_hh + (size_t)k * 384 * 128, b_ih + k * 384, b_hh + k * 384, xalt,
          N_NODES);
      float* t = xcur; xcur = xalt; xalt = t;
    }
    // residual: xalt = x + h0 ; hidden += xalt @ cat_w[:, k*128:(k+1)*128]^T
    add_k<<<gNH, blk, 0, stream>>>(xcur, h0, xalt);
    gemm_k128<true, true, false><<<dim3(gM128, 2), blk, 0, stream>>>(
        xalt, cat_w + k * 128, nullptr, hidden, N_NODES, 128, 512);
  }

  // lineout head
  lineout_k<<<(N_NODES + 15) / 16, blk, 0, stream>>>(hidden, line_w, line_b, out_line);

  // attentional aggregation + MLP heads (reuse dead buffers)
  float* gate = xB;
  float* ex = xB + N_NODES;
  unsigned* gmax_u = (unsigned*)aggpre;
  float* denom = aggpre + 512;
  float* pooled = aggpre + 1024;
  float* h1 = pooled + 512 * 128;
  float* h2 = h1 + 512 * 64;

  init_seg_k<<<1, 512, 0, stream>>>(gmax_u, denom);
  gate_k<<<(N_NODES * 64 + 255) / 256, blk, 0, stream>>>(hidden, gate_w, gate_b,
                                                         batch, gate, gmax_u);
  exp_k<<<(N_NODES + 255) / 256, blk, 0, stream>>>(gate, gmax_u, batch, ex, denom);
  hipMemsetAsync(pooled, 0, 512 * 128 * 4, stream);
  pool_k<<<(N_NODES * 32 + 255) / 256, blk, 0, stream>>>(hidden, ex, denom, batch, pooled);
  mlp1_k<<<512, 64, 0, stream>>>(pooled, mlp_w1, mlp_b1, h1);
  mlp2_k<<<512, 64, 0, stream>>>(h1, mlp_w2, mlp_b2, h2);
  outhead_k<<<512, 64, 0, stream>>>(h2, out_w, out_b, out_graph);
}

// Round 4
// 7038.289 us; speedup vs baseline: 8.6424x; 2.3467x over previous
//
#include <hip/hip_runtime.h>

#define N_NODES 100000
#define N_EDGES 1600000
#define HD 128
#define NH (N_NODES * HD)

typedef __attribute__((ext_vector_type(8))) short bf16x8;
typedef __attribute__((ext_vector_type(4))) float f32x4;

__device__ inline unsigned short f2bf(float f) {
  unsigned u = __float_as_uint(f);
  unsigned r = (u + 0x7FFFu + ((u >> 16) & 1u)) >> 16;
  return (unsigned short)r;
}
__device__ inline float bf2f(unsigned short b) {
  return __uint_as_float(((unsigned)b) << 16);
}

// ---------------------------------------------------------------------------
// fp32 GEMM (kept for h0 / WcT-fold / cat): C[M x Ncols] = A[M x 128] * B
//   NT:  B is [Ncols x 128] row-major, row stride ldb (C = A @ B^T)
// ---------------------------------------------------------------------------
template <bool NT, bool ACC, bool BIAS>
__global__ __launch_bounds__(256) void gemm_k128(
    const float* __restrict__ A, const float* __restrict__ B,
    const float* __restrict__ bias, float* __restrict__ C, int M, int Ncols,
    int ldb) {
  __shared__ float As[16][132];
  __shared__ float Bs[16][68];
  const int tid = threadIdx.x;
  const int row0 = blockIdx.x * 128;
  const int col0 = blockIdx.y * 64;
  const int tx = tid & 15, ty = tid >> 4;

  float acc[8][4];
#pragma unroll
  for (int i = 0; i < 8; i++)
#pragma unroll
    for (int j = 0; j < 4; j++) acc[i][j] = 0.f;

  const int lr = tid >> 2;
  const int kg = (tid & 3) * 4;

  for (int k0 = 0; k0 < 128; k0 += 16) {
#pragma unroll
    for (int h = 0; h < 2; ++h) {
      int r = lr + h * 64;
      float4 v = make_float4(0.f, 0.f, 0.f, 0.f);
      if (row0 + r < M)
        v = *reinterpret_cast<const float4*>(A + (size_t)(row0 + r) * 128 + k0 + kg);
      As[kg + 0][r] = v.x;
      As[kg + 1][r] = v.y;
      As[kg + 2][r] = v.z;
      As[kg + 3][r] = v.w;
    }
    if (NT) {
      int c = lr;
      float4 v = *reinterpret_cast<const float4*>(B + (size_t)(col0 + c) * ldb + k0 + kg);
      Bs[kg + 0][c] = v.x;
      Bs[kg + 1][c] = v.y;
      Bs[kg + 2][c] = v.z;
      Bs[kg + 3][c] = v.w;
    } else {
      int kk = tid >> 4;
      int cg = (tid & 15) * 4;
      float4 v = *reinterpret_cast<const float4*>(B + (size_t)(k0 + kk) * ldb + col0 + cg);
      Bs[kk][cg + 0] = v.x;
      Bs[kk][cg + 1] = v.y;
      Bs[kk][cg + 2] = v.z;
      Bs[kk][cg + 3] = v.w;
    }
    __syncthreads();
#pragma unroll
    for (int kk = 0; kk < 16; ++kk) {
      float a[8], b[4];
#pragma unroll
      for (int i = 0; i < 8; i++) a[i] = As[kk][ty * 8 + i];
#pragma unroll
      for (int j = 0; j < 4; j++) b[j] = Bs[kk][tx * 4 + j];
#pragma unroll
      for (int i = 0; i < 8; i++)
#pragma unroll
        for (int j = 0; j < 4; j++) acc[i][j] += a[i] * b[j];
    }
    __syncthreads();
  }

#pragma unroll
  for (int i = 0; i < 8; i++) {
    int r = row0 + ty * 8 + i;
    if (r < M) {
#pragma unroll
      for (int j = 0; j < 4; j++) {
        int c = col0 + tx * 4 + j;
        float v = acc[i][j];
        if (BIAS) v += bias[c];
        size_t idx = (size_t)r * Ncols + c;
        if (ACC) v += C[idx];
        C[idx] = v;
      }
    }
  }
}

// ---------------------------------------------------------------------------
// float -> bf16 convert, 4 elems/thread (n % 4 == 0)
// ---------------------------------------------------------------------------
__global__ __launch_bounds__(256) void f2b_k(const float* __restrict__ a,
                                             unsigned short* __restrict__ b, int n) {
  int i = blockIdx.x * 256 + threadIdx.x;
  if (i * 4 >= n) return;
  float4 v = reinterpret_cast<const float4*>(a)[i];
  ushort4 o;
  o.x = f2bf(v.x);
  o.y = f2bf(v.y);
  o.z = f2bf(v.z);
  o.w = f2bf(v.w);
  reinterpret_cast<ushort4*>(b)[i] = o;
}

// ---------------------------------------------------------------------------
// MFMA fused GRU: gi = aggb@wctb^T + b_ih, gh = xb@whhb^T + b_hh (bf16 MFMA,
// fp32 acc), GRU elementwise in epilogue, fp32 state in xf -> xout.
// Block: 256 thr = 4 waves x 16 rows; blockIdx.y*32 = gate-col tile.
// ---------------------------------------------------------------------------
__global__ __launch_bounds__(256) void gru_mfma_k(
    const unsigned short* __restrict__ aggb, const unsigned short* __restrict__ xb,
    const float* __restrict__ xf, const unsigned short* __restrict__ wctb,
    const unsigned short* __restrict__ whhb, const float* __restrict__ b_ih,
    const float* __restrict__ b_hh, float* __restrict__ xout, int M) {
  const int lane = threadIdx.x & 63;
  const int wave = threadIdx.x >> 6;
  const int row0 = blockIdx.x * 64 + wave * 16;
  const int c0 = blockIdx.y * 32;
  const int lrow = lane & 15;
  const int kblk = lane >> 4;  // 0..3

  int arow = row0 + lrow;
  if (arow >= M) arow = M - 1;
  const size_t abase = (size_t)arow * 128 + kblk * 8;

  f32x4 acc[6][2];
#pragma unroll
  for (int s = 0; s < 6; s++)
#pragma unroll
    for (int t = 0; t < 2; t++) acc[s][t] = (f32x4)(0.f);

#pragma unroll
  for (int kk = 0; kk < 4; kk++) {
    const int ko = kk * 32;
    bf16x8 a_ag = *reinterpret_cast<const bf16x8*>(aggb + abase + ko);
    bf16x8 a_x = *reinterpret_cast<const bf16x8*>(xb + abase + ko);
#pragma unroll
    for (int s = 0; s < 3; s++) {
#pragma unroll
      for (int t = 0; t < 2; t++) {
        const size_t wrow = (size_t)(s * 128 + c0 + t * 16 + lrow) * 128 + ko + kblk * 8;
        bf16x8 bi = *reinterpret_cast<const bf16x8*>(wctb + wrow);
        bf16x8 bh = *reinterpret_cast<const bf16x8*>(whhb + wrow);
        acc[s][t] = __builtin_amdgcn_mfma_f32_16x16x32_bf16(a_ag, bi, acc[s][t], 0, 0, 0);
        acc[s + 3][t] = __builtin_amdgcn_mfma_f32_16x16x32_bf16(a_x, bh, acc[s + 3][t], 0, 0, 0);
      }
    }
  }

  // C/D layout: col = lane&15, row = (lane>>4)*4 + reg
#pragma unroll
  for (int r = 0; r < 4; r++) {
    int orow = row0 + kblk * 4 + r;
    if (orow >= M) continue;
#pragma unroll
    for (int t = 0; t < 2; t++) {
      int c = c0 + t * 16 + lrow;
      float ir = acc[0][t][r] + b_ih[c];
      float iz = acc[1][t][r] + b_ih[128 + c];
      float in_ = acc[2][t][r] + b_ih[256 + c];
      float hr = acc[3][t][r] + b_hh[c];
      float hz = acc[4][t][r] + b_hh[128 + c];
      float hn = acc[5][t][r] + b_hh[256 + c];
      float rg = 1.f / (1.f + __expf(-(ir + hr)));
      float zg = 1.f / (1.f + __expf(-(iz + hz)));
      float ng = tanhf(in_ + rg * hn);
      float h = xf[(size_t)orow * 128 + c];
      xout[(size_t)orow * 128 + c] = (1.f - zg) * ng + zg * h;
    }
  }
}

// ---------------------------------------------------------------------------
// CSR build
// ---------------------------------------------------------------------------
__global__ __launch_bounds__(256) void deg_hist_k(const int* __restrict__ dst,
                                                  int* __restrict__ deg) {
  int e = blockIdx.x * 256 + threadIdx.x;
  if (e >= N_EDGES) return;
  atomicAdd(&deg[dst[e]], 1);
}

__global__ __launch_bounds__(1024) void scan_k(const int* __restrict__ deg,
                                               int* __restrict__ offsets) {
  __shared__ int buf[1024];
  __shared__ int base_s;
  int tid = threadIdx.x;
  if (tid == 0) base_s = 0;
  __syncthreads();
  for (int chunk = 0; chunk < N_NODES; chunk += 1024) {
    int idx = chunk + tid;
    int v = (idx < N_NODES) ? deg[idx] : 0;
    buf[tid] = v;
    __syncthreads();
    for (int off = 1; off < 1024; off <<= 1) {
      int t = (tid >= off) ? buf[tid - off] : 0;
      __syncthreads();
      buf[tid] += t;
      __syncthreads();
    }
    int incl = buf[tid];
    int base = base_s;
    if (idx < N_NODES) offsets[idx] = base + incl - v;
    __syncthreads();
    if (tid == 1023) base_s = base + incl;
    __syncthreads();
  }
  if (tid == 0) offsets[N_NODES] = base_s;
}

__global__ __launch_bounds__(256) void copy_int_k(const int* __restrict__ a,
                                                  int* __restrict__ b, int n) {
  int i = blockIdx.x * 256 + threadIdx.x;
  if (i < n) b[i] = a[i];
}

__global__ __launch_bounds__(256) void fill_k(const int* __restrict__ src,
                                              const int* __restrict__ dst,
                                              int* __restrict__ cursor,
                                              int* __restrict__ srcs_sorted) {
  int e = blockIdx.x * 256 + threadIdx.x;
  if (e >= N_EDGES) return;
  int pos = atomicAdd(&cursor[dst[e]], 1);
  srcs_sorted[pos] = src[e];
}

// ---------------------------------------------------------------------------
// aggb[n] = sum over incoming edges of xb[src] (bf16 in, fp32 acc, bf16 out)
// one wave per node, 2 cols/lane
// ---------------------------------------------------------------------------
__global__ __launch_bounds__(256) void gather_b_k(
    const unsigned short* __restrict__ xb, const int* __restrict__ offsets,
    const int* __restrict__ srcs, unsigned short* __restrict__ out) {
  int node = (blockIdx.x * 256 + threadIdx.x) >> 6;
  int lane = threadIdx.x & 63;
  if (node >= N_NODES) return;
  int beg = offsets[node], end = offsets[node + 1];
  float ax = 0.f, ay = 0.f;
  for (int e = beg; e < end; e++) {
    int s = srcs[e];
    unsigned v = *reinterpret_cast<const unsigned*>(xb + (size_t)s * 128 + lane * 2);
    ax += bf2f((unsigned short)(v & 0xFFFFu));
    ay += bf2f((unsigned short)(v >> 16));
  }
  unsigned o = (unsigned)f2bf(ax) | ((unsigned)f2bf(ay) << 16);
  *reinterpret_cast<unsigned*>(out + (size_t)node * 128 + lane * 2) = o;
}

__global__ __launch_bounds__(256) void init_hidden_k(float* __restrict__ hidden,
                                                     const float* __restrict__ cat_b) {
  int gid = blockIdx.x * 256 + threadIdx.x;
  if (gid >= NH) return;
  hidden[gid] = cat_b[gid & 127];
}

__global__ __launch_bounds__(256) void add_k(const float* __restrict__ a,
                                             const float* __restrict__ b,
                                             float* __restrict__ c) {
  int gid = blockIdx.x * 256 + threadIdx.x;
  if (gid >= NH) return;
  c[gid] = a[gid] + b[gid];
}

// lineout = hidden @ line_w^T + line_b
__global__ __launch_bounds__(256) void lineout_k(
    const float* __restrict__ hidden, const float* __restrict__ W,
    const float* __restrict__ b, float* __restrict__ out) {
  __shared__ float Ws[16 * 128];
  for (int i = threadIdx.x; i < 2048; i += 256) Ws[i] = W[i];
  __syncthreads();
  int r = threadIdx.x >> 4, c = threadIdx.x & 15;
  int n = blockIdx.x * 16 + r;
  if (n >= N_NODES) return;
  const float* h = hidden + (size_t)n * 128;
  const float* w = Ws + c * 128;
  float acc = 0.f;
#pragma unroll 8
  for (int k = 0; k < 128; k++) acc += h[k] * w[k];
  out[(size_t)n * 16 + c] = acc + b[c];
}

__global__ __launch_bounds__(256) void gate_k(
    const float* __restrict__ hidden, const float* __restrict__ gw,
    const float* __restrict__ gb, const int* __restrict__ batch,
    float* __restrict__ gate, unsigned* __restrict__ gmax_u) {
  int wid = (blockIdx.x * 256 + threadIdx.x) >> 6;
  int lane = threadIdx.x & 63;
  if (wid >= N_NODES) return;
  const float* h = hidden + (size_t)wid * 128;
  float s = h[lane] * gw[lane] + h[64 + lane] * gw[64 + lane];
#pragma unroll
  for (int off = 32; off; off >>= 1) s += __shfl_down(s, off);
  if (lane == 0) {
    float g = s + gb[0];
    gate[wid] = g;
    unsigned u = __float_as_uint(g);
    unsigned e = (u & 0x80000000u) ? ~u : (u | 0x80000000u);
    atomicMax(&gmax_u[batch[wid]], e);
  }
}

__global__ void init_seg_k(unsigned* __restrict__ gmax_u, float* __restrict__ denom) {
  int t = threadIdx.x;
  gmax_u[t] = 0x007FFFFFu;
  denom[t] = 0.f;
}

__global__ __launch_bounds__(256) void exp_k(
    const float* __restrict__ gate, const unsigned* __restrict__ gmax_u,
    const int* __restrict__ batch, float* __restrict__ ex,
    float* __restrict__ denom) {
  int n = blockIdx.x * 256 + threadIdx.x;
  if (n >= N_NODES) return;
  int g = batch[n];
  unsigned e = gmax_u[g];
  unsigned u = (e & 0x80000000u) ? (e & 0x7FFFFFFFu) : ~e;
  float mx = __uint_as_float(u);
  float v = __expf(gate[n] - mx);
  ex[n] = v;
  atomicAdd(&denom[g], v);
}

__global__ __launch_bounds__(256) void pool_k(
    const float* __restrict__ hidden, const float* __restrict__ ex,
    const float* __restrict__ denom, const int* __restrict__ batch,
    float* __restrict__ pooled) {
  int gid = blockIdx.x * 256 + threadIdx.x;
  if (gid >= N_NODES * 32) return;
  int n = gid >> 5;
  int c = (gid & 31) * 4;
  int g = batch[n];
  float a = ex[n] / denom[g];
  float4 h = *reinterpret_cast<const float4*>(hidden + (size_t)n * 128 + c);
  float* p = pooled + (size_t)g * 128 + c;
  atomicAdd(p + 0, a * h.x);
  atomicAdd(p + 1, a * h.y);
  atomicAdd(p + 2, a * h.z);
  atomicAdd(p + 3, a * h.w);
}

__global__ void mlp1_k(const float* __restrict__ pooled, const float* __restrict__ w,
                       const float* __restrict__ b, float* __restrict__ h1) {
  int g = blockIdx.x, j = threadIdx.x;
  const float* p = pooled + (size_t)g * 128;
  const float* wr = w + (size_t)j * 128;
  float acc = 0.f;
#pragma unroll 8
  for (int k = 0; k < 128; k++) acc += p[k] * wr[k];
  acc += b[j];
  h1[g * 64 + j] = acc > 0.f ? acc : 0.f;
}

__global__ void mlp2_k(const float* __restrict__ h1, const float* __restrict__ w,
                       const float* __restrict__ b, float* __restrict__ h2) {
  int g = blockIdx.x, j = threadIdx.x;
  const float* p = h1 + (size_t)g * 64;
  const float* wr = w + (size_t)j * 64;
  float acc = 0.f;
#pragma unroll 8
  for (int k = 0; k < 64; k++) acc += p[k] * wr[k];
  acc += b[j];
  h2[g * 64 + j] = acc > 0.f ? acc : 0.f;
}

__global__ void outhead_k(const float* __restrict__ h2, const float* __restrict__ w,
                          const float* __restrict__ b, float* __restrict__ out) {
  int g = blockIdx.x, j = threadIdx.x;
  if (j >= 16) return;
  const float* p = h2 + (size_t)g * 64;
  const float* wr = w + (size_t)j * 64;
  float acc = 0.f;
#pragma unroll 8
  for (int k = 0; k < 64; k++) acc += p[k] * wr[k];
  out[g * 16 + j] = acc + b[j];
}

extern "C" void kernel_launch(void* const* d_in, const int* in_sizes, int n_in,
                              void* d_out, int out_size, void* d_ws, size_t ws_size,
                              hipStream_t stream) {
  const float* node_embed = (const float*)d_in[0];
  const int* eidx = (const int*)d_in[1];
  const int* batch = (const int*)d_in[2];
  const float* node_w = (const float*)d_in[3];
  const float* node_b = (const float*)d_in[4];
  const float* ggc_w = (const float*)d_in[5];
  const float* w_ih = (const float*)d_in[6];
  const float* w_hh = (const float*)d_in[7];
  const float* b_ih = (const float*)d_in[8];
  const float* b_hh = (const float*)d_in[9];
  const float* cat_w = (const float*)d_in[10];
  const float* cat_b = (const float*)d_in[11];
  const float* gate_w = (const float*)d_in[12];
  const float* gate_b = (const float*)d_in[13];
  const float* mlp_w1 = (const float*)d_in[14];
  const float* mlp_b1 = (const float*)d_in[15];
  const float* mlp_w2 = (const float*)d_in[16];
  const float* mlp_b2 = (const float*)d_in[17];
  const float* out_w = (const float*)d_in[18];
  const float* out_b = (const float*)d_in[19];
  const float* line_w = (const float*)d_in[20];
  const float* line_b = (const float*)d_in[21];

  const int* src = eidx;
  const int* dst = eidx + N_EDGES;

  // workspace: 4*NH f32 + 2*NH bf16 + weights-bf16 + CSR  (~265 MB)
  float* ws = (float*)d_ws;
  float* h0 = ws;                                  // [NH] f32
  float* hidden = h0 + (size_t)NH;                 // [NH] f32
  float* xA = hidden + (size_t)NH;                 // [NH] f32
  float* xB = xA + (size_t)NH;                     // [NH] f32
  unsigned short* xbm = (unsigned short*)(xB + (size_t)NH);  // [NH] bf16
  unsigned short* aggb = xbm + (size_t)NH;                   // [NH] bf16
  unsigned short* wctb = aggb + (size_t)NH;        // [16*384*128] bf16
  unsigned short* whhb = wctb + 16 * 384 * 128;    // [4*384*128] bf16
  int* offsets = (int*)(whhb + 4 * 384 * 128);     // [N+1]
  int* cursor = offsets + N_NODES + 1;             // [N]
  int* srcs_sorted = cursor + N_NODES;             // [E]
  float* WcT = (float*)aggb;                       // overlay (pre-loop only)

  float* out_graph = (float*)d_out;
  float* out_line = (float*)d_out + 512 * 16;

  dim3 blk(256);
  const int gM128 = (N_NODES + 127) / 128;
  const int gM64 = (N_NODES + 63) / 64;
  const int gNH = (NH + 255) / 256;
  const int gE = (N_EDGES + 255) / 256;

  // ---- CSR build ----
  hipMemsetAsync(cursor, 0, N_NODES * sizeof(int), stream);
  deg_hist_k<<<gE, blk, 0, stream>>>(dst, cursor);
  scan_k<<<1, 1024, 0, stream>>>(cursor, offsets);
  copy_int_k<<<(N_NODES + 255) / 256, blk, 0, stream>>>(offsets, cursor, N_NODES);
  fill_k<<<gE, blk, 0, stream>>>(src, dst, cursor, srcs_sorted);

  // ---- WcT[k,i] = w_ih[k] @ ggc_w[k,i]^T, then bf16 convert ----
  for (int k = 0; k < 4; k++)
    for (int i = 0; i < 4; i++)
      gemm_k128<true, false, false><<<dim3(3, 2), blk, 0, stream>>>(
          w_ih + (size_t)k * 384 * 128, ggc_w + (size_t)(k * 4 + i) * 128 * 128,
          nullptr, WcT + (size_t)(k * 4 + i) * 384 * 128, 384, 128, 128);
  f2b_k<<<(16 * 384 * 128 / 4 + 255) / 256, blk, 0, stream>>>(WcT, wctb, 16 * 384 * 128);
  f2b_k<<<(4 * 384 * 128 / 4 + 255) / 256, blk, 0, stream>>>(w_hh, whhb, 4 * 384 * 128);

  // h0 = node_embed @ node_w^T + node_b
  gemm_k128<true, false, true><<<dim3(gM128, 2), blk, 0, stream>>>(
      node_embed, node_w, node_b, h0, N_NODES, 128, 128);
  init_hidden_k<<<gNH, blk, 0, stream>>>(hidden, cat_b);

  float* xcur = xA;
  float* xalt = xB;
  for (int k = 0; k < 4; k++) {
    hipMemcpyAsync(xcur, h0, (size_t)NH * 4, hipMemcpyDeviceToDevice, stream);
    for (int i = 0; i < 4; i++) {
      // bf16 mirror of state
      f2b_k<<<(NH / 4 + 255) / 256, blk, 0, stream>>>(xcur, xbm, NH);
      // aggb = segment_sum(xb[src], dst)
      gather_b_k<<<(N_NODES * 64 + 255) / 256, blk, 0, stream>>>(xbm, offsets,
                                                                 srcs_sorted, aggb);
      // x_new = GRU(aggb via folded WcT, xb; h from fp32 xcur)
      gru_mfma_k<<<dim3(gM64, 4), blk, 0, stream>>>(
          aggb, xbm, xcur, wctb + (size_t)(k * 4 + i) * 384 * 128,
          whhb + (size_t)k * 384 * 128, b_ih + k * 384, b_hh + k * 384, xalt,
          N_NODES);
      float* t = xcur; xcur = xalt; xalt = t;
    }
    // residual + cat-projection accumulate
    add_k<<<gNH, blk, 0, stream>>>(xcur, h0, xalt);
    gemm_k128<true, true, false><<<dim3(gM128, 2), blk, 0, stream>>>(
        xalt, cat_w + k * 128, nullptr, hidden, N_NODES, 128, 512);
  }

  // lineout head
  lineout_k<<<(N_NODES + 15) / 16, blk, 0, stream>>>(hidden, line_w, line_b, out_line);

  // attentional aggregation + MLP heads (reuse dead buffers)
  float* gate = xB;
  float* ex = xB + N_NODES;
  unsigned* gmax_u = (unsigned*)aggb;
  float* denom = (float*)aggb + 512;
  float* pooled = (float*)aggb + 1024;
  float* h1 = pooled + 512 * 128;
  float* h2 = h1 + 512 * 64;

  init_seg_k<<<1, 512, 0, stream>>>(gmax_u, denom);
  gate_k<<<(N_NODES * 64 + 255) / 256, blk, 0, stream>>>(hidden, gate_w, gate_b,
                                                         batch, gate, gmax_u);
  exp_k<<<(N_NODES + 255) / 256, blk, 0, stream>>>(gate, gmax_u, batch, ex, denom);
  hipMemsetAsync(pooled, 0, 512 * 128 * 4, stream);
  pool_k<<<(N_NODES * 32 + 255) / 256, blk, 0, stream>>>(hidden, ex, denom, batch, pooled);
  mlp1_k<<<512, 64, 0, stream>>>(pooled, mlp_w1, mlp_b1, h1);
  mlp2_k<<<512, 64, 0, stream>>>(h1, mlp_w2, mlp_b2, h2);
  outhead_k<<<512, 64, 0, stream>>>(h2, out_w, out_b, out_graph);
}

// Round 5
// 5987.527 us; speedup vs baseline: 10.1590x; 1.1755x over previous
//
#include <hip/hip_runtime.h>

#define N_NODES 100000
#define N_EDGES 1600000
#define HD 128
#define NH (N_NODES * HD)

typedef __attribute__((ext_vector_type(8))) short bf16x8;
typedef __attribute__((ext_vector_type(4))) float f32x4;

__device__ inline unsigned short f2bf(float f) {
  unsigned u = __float_as_uint(f);
  unsigned r = (u + 0x7FFFu + ((u >> 16) & 1u)) >> 16;
  return (unsigned short)r;
}
__device__ inline float bf2f(unsigned short b) {
  return __uint_as_float(((unsigned)b) << 16);
}

// ---------------------------------------------------------------------------
// fp32 GEMM: C[M x Ncols] = (A [+ H0]) [M x 128] * B (+ bias) (+= C)
//   NT: B is [Ncols x 128] row-major, stride ldb (C = A @ B^T)
// ---------------------------------------------------------------------------
template <bool NT, bool ACC, bool BIAS, bool ADDH0>
__global__ __launch_bounds__(256) void gemm_k128(
    const float* __restrict__ A, const float* __restrict__ H0,
    const float* __restrict__ B, const float* __restrict__ bias,
    float* __restrict__ C, int M, int Ncols, int ldb) {
  __shared__ float As[16][132];
  __shared__ float Bs[16][68];
  const int tid = threadIdx.x;
  const int row0 = blockIdx.x * 128;
  const int col0 = blockIdx.y * 64;
  const int tx = tid & 15, ty = tid >> 4;

  float acc[8][4];
#pragma unroll
  for (int i = 0; i < 8; i++)
#pragma unroll
    for (int j = 0; j < 4; j++) acc[i][j] = 0.f;

  const int lr = tid >> 2;
  const int kg = (tid & 3) * 4;

  for (int k0 = 0; k0 < 128; k0 += 16) {
#pragma unroll
    for (int h = 0; h < 2; ++h) {
      int r = lr + h * 64;
      float4 v = make_float4(0.f, 0.f, 0.f, 0.f);
      if (row0 + r < M) {
        v = *reinterpret_cast<const float4*>(A + (size_t)(row0 + r) * 128 + k0 + kg);
        if (ADDH0) {
          float4 w = *reinterpret_cast<const float4*>(H0 + (size_t)(row0 + r) * 128 + k0 + kg);
          v.x += w.x; v.y += w.y; v.z += w.z; v.w += w.w;
        }
      }
      As[kg + 0][r] = v.x;
      As[kg + 1][r] = v.y;
      As[kg + 2][r] = v.z;
      As[kg + 3][r] = v.w;
    }
    if (NT) {
      int c = lr;
      float4 v = *reinterpret_cast<const float4*>(B + (size_t)(col0 + c) * ldb + k0 + kg);
      Bs[kg + 0][c] = v.x;
      Bs[kg + 1][c] = v.y;
      Bs[kg + 2][c] = v.z;
      Bs[kg + 3][c] = v.w;
    } else {
      int kk = tid >> 4;
      int cg = (tid & 15) * 4;
      float4 v = *reinterpret_cast<const float4*>(B + (size_t)(k0 + kk) * ldb + col0 + cg);
      Bs[kk][cg + 0] = v.x;
      Bs[kk][cg + 1] = v.y;
      Bs[kk][cg + 2] = v.z;
      Bs[kk][cg + 3] = v.w;
    }
    __syncthreads();
#pragma unroll
    for (int kk = 0; kk < 16; ++kk) {
      float a[8], b[4];
#pragma unroll
      for (int i = 0; i < 8; i++) a[i] = As[kk][ty * 8 + i];
#pragma unroll
      for (int j = 0; j < 4; j++) b[j] = Bs[kk][tx * 4 + j];
#pragma unroll
      for (int i = 0; i < 8; i++)
#pragma unroll
        for (int j = 0; j < 4; j++) acc[i][j] += a[i] * b[j];
    }
    __syncthreads();
  }

#pragma unroll
  for (int i = 0; i < 8; i++) {
    int r = row0 + ty * 8 + i;
    if (r < M) {
#pragma unroll
      for (int j = 0; j < 4; j++) {
        int c = col0 + tx * 4 + j;
        float v = acc[i][j];
        if (BIAS) v += bias[c];
        size_t idx = (size_t)r * Ncols + c;
        if (ACC) v += C[idx];
        C[idx] = v;
      }
    }
  }
}

// ---------------------------------------------------------------------------
// Batched WcT fold: C[z] = w_ih[z>>2] @ ggc_w[z]^T   ([384,128] each, z=0..15)
// ---------------------------------------------------------------------------
__global__ __launch_bounds__(256) void gemm_wct_k(
    const float* __restrict__ w_ih, const float* __restrict__ ggc_w,
    float* __restrict__ Cout) {
  const int z = blockIdx.z;
  const float* A = w_ih + (size_t)(z >> 2) * 384 * 128;
  const float* B = ggc_w + (size_t)z * 128 * 128;
  float* C = Cout + (size_t)z * 384 * 128;
  __shared__ float As[16][132];
  __shared__ float Bs[16][68];
  const int tid = threadIdx.x;
  const int row0 = blockIdx.x * 128;
  const int col0 = blockIdx.y * 64;
  const int tx = tid & 15, ty = tid >> 4;

  float acc[8][4];
#pragma unroll
  for (int i = 0; i < 8; i++)
#pragma unroll
    for (int j = 0; j < 4; j++) acc[i][j] = 0.f;

  const int lr = tid >> 2;
  const int kg = (tid & 3) * 4;

  for (int k0 = 0; k0 < 128; k0 += 16) {
#pragma unroll
    for (int h = 0; h < 2; ++h) {
      int r = lr + h * 64;
      float4 v = *reinterpret_cast<const float4*>(A + (size_t)(row0 + r) * 128 + k0 + kg);
      As[kg + 0][r] = v.x;
      As[kg + 1][r] = v.y;
      As[kg + 2][r] = v.z;
      As[kg + 3][r] = v.w;
    }
    {
      int c = lr;
      float4 v = *reinterpret_cast<const float4*>(B + (size_t)(col0 + c) * 128 + k0 + kg);
      Bs[kg + 0][c] = v.x;
      Bs[kg + 1][c] = v.y;
      Bs[kg + 2][c] = v.z;
      Bs[kg + 3][c] = v.w;
    }
    __syncthreads();
#pragma unroll
    for (int kk = 0; kk < 16; ++kk) {
      float a[8], b[4];
#pragma unroll
      for (int i = 0; i < 8; i++) a[i] = As[kk][ty * 8 + i];
#pragma unroll
      for (int j = 0; j < 4; j++) b[j] = Bs[kk][tx * 4 + j];
#pragma unroll
      for (int i = 0; i < 8; i++)
#pragma unroll
        for (int j = 0; j < 4; j++) acc[i][j] += a[i] * b[j];
    }
    __syncthreads();
  }

#pragma unroll
  for (int i = 0; i < 8; i++) {
    int r = row0 + ty * 8 + i;
#pragma unroll
    for (int j = 0; j < 4; j++) {
      int c = col0 + tx * 4 + j;
      C[(size_t)r * 128 + c] = acc[i][j];
    }
  }
}

// ---------------------------------------------------------------------------
// float -> bf16, 4 elems/thread (n % 4 == 0)
// ---------------------------------------------------------------------------
__global__ __launch_bounds__(256) void f2b_k(const float* __restrict__ a,
                                             unsigned short* __restrict__ b, int n) {
  int i = blockIdx.x * 256 + threadIdx.x;
  if (i * 4 >= n) return;
  float4 v = reinterpret_cast<const float4*>(a)[i];
  ushort4 o;
  o.x = f2bf(v.x);
  o.y = f2bf(v.y);
  o.z = f2bf(v.z);
  o.w = f2bf(v.w);
  reinterpret_cast<ushort4*>(b)[i] = o;
}

// ---------------------------------------------------------------------------
// MFMA fused GRU; epilogue writes fp32 state AND its bf16 mirror.
// xf may alias xout (in-place: each element read+written by its own thread).
// xbout must NOT alias xb.
// ---------------------------------------------------------------------------
__global__ __launch_bounds__(256) void gru_mfma_k(
    const unsigned short* __restrict__ aggb, const unsigned short* __restrict__ xb,
    const float* __restrict__ xf, const unsigned short* __restrict__ wctb,
    const unsigned short* __restrict__ whhb, const float* __restrict__ b_ih,
    const float* __restrict__ b_hh, float* __restrict__ xout,
    unsigned short* __restrict__ xbout, int M) {
  const int lane = threadIdx.x & 63;
  const int wave = threadIdx.x >> 6;
  const int row0 = blockIdx.x * 64 + wave * 16;
  const int c0 = blockIdx.y * 32;
  const int lrow = lane & 15;
  const int kblk = lane >> 4;  // 0..3

  int arow = row0 + lrow;
  if (arow >= M) arow = M - 1;
  const size_t abase = (size_t)arow * 128 + kblk * 8;

  f32x4 acc[6][2];
#pragma unroll
  for (int s = 0; s < 6; s++)
#pragma unroll
    for (int t = 0; t < 2; t++) acc[s][t] = (f32x4)(0.f);

#pragma unroll
  for (int kk = 0; kk < 4; kk++) {
    const int ko = kk * 32;
    bf16x8 a_ag = *reinterpret_cast<const bf16x8*>(aggb + abase + ko);
    bf16x8 a_x = *reinterpret_cast<const bf16x8*>(xb + abase + ko);
#pragma unroll
    for (int s = 0; s < 3; s++) {
#pragma unroll
      for (int t = 0; t < 2; t++) {
        const size_t wrow = (size_t)(s * 128 + c0 + t * 16 + lrow) * 128 + ko + kblk * 8;
        bf16x8 bi = *reinterpret_cast<const bf16x8*>(wctb + wrow);
        bf16x8 bh = *reinterpret_cast<const bf16x8*>(whhb + wrow);
        acc[s][t] = __builtin_amdgcn_mfma_f32_16x16x32_bf16(a_ag, bi, acc[s][t], 0, 0, 0);
        acc[s + 3][t] = __builtin_amdgcn_mfma_f32_16x16x32_bf16(a_x, bh, acc[s + 3][t], 0, 0, 0);
      }
    }
  }

  // C/D layout: col = lane&15, row = (lane>>4)*4 + reg
#pragma unroll
  for (int r = 0; r < 4; r++) {
    int orow = row0 + kblk * 4 + r;
    if (orow >= M) continue;
#pragma unroll
    for (int t = 0; t < 2; t++) {
      int c = c0 + t * 16 + lrow;
      float ir = acc[0][t][r] + b_ih[c];
      float iz = acc[1][t][r] + b_ih[128 + c];
      float in_ = acc[2][t][r] + b_ih[256 + c];
      float hr = acc[3][t][r] + b_hh[c];
      float hz = acc[4][t][r] + b_hh[128 + c];
      float hn = acc[5][t][r] + b_hh[256 + c];
      float rg = 1.f / (1.f + __expf(-(ir + hr)));
      float zg = 1.f / (1.f + __expf(-(iz + hz)));
      float ng = tanhf(in_ + rg * hn);
      float h = xf[(size_t)orow * 128 + c];
      float nv = (1.f - zg) * ng + zg * h;
      xout[(size_t)orow * 128 + c] = nv;
      xbout[(size_t)orow * 128 + c] = f2bf(nv);
    }
  }
}

// ---------------------------------------------------------------------------
// CSR build: histogram -> hierarchical scan -> positional fill
// ---------------------------------------------------------------------------
__global__ __launch_bounds__(256) void deg_hist_k(const int* __restrict__ dst,
                                                  int* __restrict__ deg) {
  int e = blockIdx.x * 256 + threadIdx.x;
  if (e >= N_EDGES) return;
  atomicAdd(&deg[dst[e]], 1);
}

__global__ __launch_bounds__(256) void scan1_k(const int* __restrict__ deg,
                                               int* __restrict__ offsets,
                                               int* __restrict__ bsum) {
  __shared__ int buf[256];
  int tid = threadIdx.x;
  int idx = blockIdx.x * 256 + tid;
  int v = (idx < N_NODES) ? deg[idx] : 0;
  buf[tid] = v;
  __syncthreads();
  for (int off = 1; off < 256; off <<= 1) {
    int t = (tid >= off) ? buf[tid - off] : 0;
    __syncthreads();
    buf[tid] += t;
    __syncthreads();
  }
  if (idx < N_NODES) offsets[idx] = buf[tid] - v;
  if (tid == 255) bsum[blockIdx.x] = buf[255];
}

__global__ __launch_bounds__(512) void scan2_k(int* __restrict__ bsum, int nb) {
  __shared__ int buf[512];
  int tid = threadIdx.x;
  int v = (tid < nb) ? bsum[tid] : 0;
  buf[tid] = v;
  __syncthreads();
  for (int off = 1; off < 512; off <<= 1) {
    int t = (tid >= off) ? buf[tid - off] : 0;
    __syncthreads();
    buf[tid] += t;
    __syncthreads();
  }
  if (tid < nb) bsum[tid] = buf[tid] - v;
}

__global__ __launch_bounds__(256) void scan3_k(int* __restrict__ offsets,
                                               const int* __restrict__ bsum) {
  int idx = blockIdx.x * 256 + threadIdx.x;
  if (idx < N_NODES) offsets[idx] += bsum[idx >> 8];
  if (idx == 0) offsets[N_NODES] = N_EDGES;
}

__global__ __launch_bounds__(256) void copy_int_k(const int* __restrict__ a,
                                                  int* __restrict__ b, int n) {
  int i = blockIdx.x * 256 + threadIdx.x;
  if (i < n) b[i] = a[i];
}

__global__ __launch_bounds__(256) void fill_k(const int* __restrict__ src,
                                              const int* __restrict__ dst,
                                              int* __restrict__ cursor,
                                              int* __restrict__ srcs_sorted) {
  int e = blockIdx.x * 256 + threadIdx.x;
  if (e >= N_EDGES) return;
  int pos = atomicAdd(&cursor[dst[e]], 1);
  srcs_sorted[pos] = src[e];
}

// ---------------------------------------------------------------------------
// aggb[n] = sum over incoming edges of xb[src]; one wave per node
// ---------------------------------------------------------------------------
__global__ __launch_bounds__(256) void gather_b_k(
    const unsigned short* __restrict__ xb, const int* __restrict__ offsets,
    const int* __restrict__ srcs, unsigned short* __restrict__ out) {
  int node = (blockIdx.x * 256 + threadIdx.x) >> 6;
  int lane = threadIdx.x & 63;
  if (node >= N_NODES) return;
  int beg = offsets[node], end = offsets[node + 1];
  float ax = 0.f, ay = 0.f;
  for (int e = beg; e < end; e++) {
    int s = srcs[e];
    unsigned v = *reinterpret_cast<const unsigned*>(xb + (size_t)s * 128 + lane * 2);
    ax += bf2f((unsigned short)(v & 0xFFFFu));
    ay += bf2f((unsigned short)(v >> 16));
  }
  unsigned o = (unsigned)f2bf(ax) | ((unsigned)f2bf(ay) << 16);
  *reinterpret_cast<unsigned*>(out + (size_t)node * 128 + lane * 2) = o;
}

__global__ __launch_bounds__(256) void init_hidden_k(float* __restrict__ hidden,
                                                     const float* __restrict__ cat_b) {
  int gid = blockIdx.x * 256 + threadIdx.x;
  if (gid >= NH) return;
  hidden[gid] = cat_b[gid & 127];
}

// lineout = hidden @ line_w^T + line_b
__global__ __launch_bounds__(256) void lineout_k(
    const float* __restrict__ hidden, const float* __restrict__ W,
    const float* __restrict__ b, float* __restrict__ out) {
  __shared__ float Ws[16 * 128];
  for (int i = threadIdx.x; i < 2048; i += 256) Ws[i] = W[i];
  __syncthreads();
  int r = threadIdx.x >> 4, c = threadIdx.x & 15;
  int n = blockIdx.x * 16 + r;
  if (n >= N_NODES) return;
  const float* h = hidden + (size_t)n * 128;
  const float* w = Ws + c * 128;
  float acc = 0.f;
#pragma unroll 8
  for (int k = 0; k < 128; k++) acc += h[k] * w[k];
  out[(size_t)n * 16 + c] = acc + b[c];
}

// gate[n] = hidden[n] . gate_w + gate_b
__global__ __launch_bounds__(256) void gate_k(
    const float* __restrict__ hidden, const float* __restrict__ gw,
    const float* __restrict__ gb, float* __restrict__ gate) {
  int wid = (blockIdx.x * 256 + threadIdx.x) >> 6;
  int lane = threadIdx.x & 63;
  if (wid >= N_NODES) return;
  const float* h = hidden + (size_t)wid * 128;
  float s = h[lane] * gw[lane] + h[64 + lane] * gw[64 + lane];
#pragma unroll
  for (int off = 32; off; off >>= 1) s += __shfl_down(s, off);
  if (lane == 0) gate[wid] = s + gb[0];
}

// gs[g] = lower_bound(batch, g); gs[512] = N  (batch is sorted)
__global__ void graph_start_k(const int* __restrict__ batch, int* __restrict__ gs) {
  int g = threadIdx.x;
  if (g > 512) return;
  if (g == 512) {
    gs[512] = N_NODES;
    return;
  }
  int lo = 0, hi = N_NODES;
  while (lo < hi) {
    int mid = (lo + hi) >> 1;
    if (batch[mid] < g) lo = mid + 1;
    else hi = mid;
  }
  gs[g] = lo;
}

// ---------------------------------------------------------------------------
// Per-graph attention pool: max -> exp-sum -> weighted column accumulate.
// One block per graph; batch sorted so node range is contiguous. No atomics.
// ---------------------------------------------------------------------------
__global__ __launch_bounds__(256) void pool_fused_k(
    const float* __restrict__ hidden, const float* __restrict__ gate,
    const int* __restrict__ gs, float* __restrict__ ex,
    float* __restrict__ pooled) {
  const int g = blockIdx.x;
  const int beg = gs[g], end = gs[g + 1];
  const int tid = threadIdx.x, lane = tid & 63, wv = tid >> 6;
  __shared__ float red[4];
  __shared__ float sval;
  __shared__ float colbuf[256];

  if (end <= beg) {
    if (tid < 128) pooled[(size_t)g * 128 + tid] = 0.f;
    return;
  }
  // pass 1: max
  float m = -3.4e38f;
  for (int n = beg + tid; n < end; n += 256) m = fmaxf(m, gate[n]);
#pragma unroll
  for (int off = 32; off; off >>= 1) m = fmaxf(m, __shfl_down(m, off));
  if (lane == 0) red[wv] = m;
  __syncthreads();
  if (tid == 0) sval = fmaxf(fmaxf(red[0], red[1]), fmaxf(red[2], red[3]));
  __syncthreads();
  const float mx = sval;
  // pass 2: exp + sum
  float s = 0.f;
  for (int n = beg + tid; n < end; n += 256) {
    float e = __expf(gate[n] - mx);
    ex[n] = e;
    s += e;
  }
#pragma unroll
  for (int off = 32; off; off >>= 1) s += __shfl_down(s, off);
  if (lane == 0) red[wv] = s;
  __syncthreads();
  if (tid == 0) sval = red[0] + red[1] + red[2] + red[3];
  __syncthreads();
  const float denom = sval;
  // pass 3: pooled[g, col] = sum_n ex[n] * hidden[n, col] / denom
  const int col = tid & 127, half = tid >> 7;
  float acc = 0.f;
  for (int n = beg + half; n < end; n += 2)
    acc += ex[n] * hidden[(size_t)n * 128 + col];
  colbuf[tid] = acc;
  __syncthreads();
  if (tid < 128)
    pooled[(size_t)g * 128 + tid] = (colbuf[tid] + colbuf[tid + 128]) / denom;
}

__global__ void mlp1_k(const float* __restrict__ pooled, const float* __restrict__ w,
                       const float* __restrict__ b, float* __restrict__ h1) {
  int g = blockIdx.x, j = threadIdx.x;
  const float* p = pooled + (size_t)g * 128;
  const float* wr = w + (size_t)j * 128;
  float acc = 0.f;
#pragma unroll 8
  for (int k = 0; k < 128; k++) acc += p[k] * wr[k];
  acc += b[j];
  h1[g * 64 + j] = acc > 0.f ? acc : 0.f;
}

__global__ void mlp2_k(const float* __restrict__ h1, const float* __restrict__ w,
                       const float* __restrict__ b, float* __restrict__ h2) {
  int g = blockIdx.x, j = threadIdx.x;
  const float* p = h1 + (size_t)g * 64;
  const float* wr = w + (size_t)j * 64;
  float acc = 0.f;
#pragma unroll 8
  for (int k = 0; k < 64; k++) acc += p[k] * wr[k];
  acc += b[j];
  h2[g * 64 + j] = acc > 0.f ? acc : 0.f;
}

__global__ void outhead_k(const float* __restrict__ h2, const float* __restrict__ w,
                          const float* __restrict__ b, float* __restrict__ out) {
  int g = blockIdx.x, j = threadIdx.x;
  if (j >= 16) return;
  const float* p = h2 + (size_t)g * 64;
  const float* wr = w + (size_t)j * 64;
  float acc = 0.f;
#pragma unroll 8
  for (int k = 0; k < 64; k++) acc += p[k] * wr[k];
  out[g * 16 + j] = acc + b[j];
}

extern "C" void kernel_launch(void* const* d_in, const int* in_sizes, int n_in,
                              void* d_out, int out_size, void* d_ws, size_t ws_size,
                              hipStream_t stream) {
  const float* node_embed = (const float*)d_in[0];
  const int* eidx = (const int*)d_in[1];
  const int* batch = (const int*)d_in[2];
  const float* node_w = (const float*)d_in[3];
  const float* node_b = (const float*)d_in[4];
  const float* ggc_w = (const float*)d_in[5];
  const float* w_ih = (const float*)d_in[6];
  const float* w_hh = (const float*)d_in[7];
  const float* b_ih = (const float*)d_in[8];
  const float* b_hh = (const float*)d_in[9];
  const float* cat_w = (const float*)d_in[10];
  const float* cat_b = (const float*)d_in[11];
  const float* gate_w = (const float*)d_in[12];
  const float* gate_b = (const float*)d_in[13];
  const float* mlp_w1 = (const float*)d_in[14];
  const float* mlp_b1 = (const float*)d_in[15];
  const float* mlp_w2 = (const float*)d_in[16];
  const float* mlp_b2 = (const float*)d_in[17];
  const float* out_w = (const float*)d_in[18];
  const float* out_b = (const float*)d_in[19];
  const float* line_w = (const float*)d_in[20];
  const float* line_b = (const float*)d_in[21];

  const int* src = eidx;
  const int* dst = eidx + N_EDGES;

  // workspace (~265 MB): 3*NH f32 | 4*NH bf16 | weights bf16 | CSR ints
  float* ws = (float*)d_ws;
  float* h0 = ws;                                   // [NH] f32
  float* hidden = h0 + (size_t)NH;                  // [NH] f32
  float* xfS = hidden + (size_t)NH;                 // [NH] f32 (in-place state)
  unsigned short* h0b = (unsigned short*)(xfS + (size_t)NH);  // [NH] bf16
  unsigned short* xbA = h0b + (size_t)NH;           // [NH] bf16
  unsigned short* xbB = xbA + (size_t)NH;           // [NH] bf16
  unsigned short* aggb = xbB + (size_t)NH;          // [NH] bf16
  unsigned short* wctb = aggb + (size_t)NH;         // 16*384*128 bf16
  unsigned short* whhb = wctb + 16 * 384 * 128;     // 4*384*128 bf16
  int* offsets = (int*)(whhb + 4 * 384 * 128);      // [N+1]
  int* cursor = offsets + N_NODES + 1;              // [N]
  int* srcs_sorted = cursor + N_NODES;              // [E]
  int* bsum = srcs_sorted + N_EDGES;                // [512]
  int* gs = bsum + 512;                             // [513]
  float* WcTf = xfS;                                // fp32 staging overlay (pre-loop)

  float* out_graph = (float*)d_out;
  float* out_line = (float*)d_out + 512 * 16;

  dim3 blk(256);
  const int gM128 = (N_NODES + 127) / 128;
  const int gM64 = (N_NODES + 63) / 64;
  const int gNH = (NH + 255) / 256;
  const int gE = (N_EDGES + 255) / 256;
  const int nScanBlk = (N_NODES + 255) / 256;  // 391

  // ---- CSR build ----
  hipMemsetAsync(cursor, 0, N_NODES * sizeof(int), stream);
  deg_hist_k<<<gE, blk, 0, stream>>>(dst, cursor);
  scan1_k<<<nScanBlk, blk, 0, stream>>>(cursor, offsets, bsum);
  scan2_k<<<1, 512, 0, stream>>>(bsum, nScanBlk);
  scan3_k<<<nScanBlk, blk, 0, stream>>>(offsets, bsum);
  copy_int_k<<<(N_NODES + 255) / 256, blk, 0, stream>>>(offsets, cursor, N_NODES);
  fill_k<<<gE, blk, 0, stream>>>(src, dst, cursor, srcs_sorted);
  graph_start_k<<<1, 576, 0, stream>>>(batch, gs);

  // ---- WcT[k,i] = w_ih[k] @ ggc_w[k,i]^T (batched), convert weights ----
  gemm_wct_k<<<dim3(3, 2, 16), blk, 0, stream>>>(w_ih, ggc_w, WcTf);
  f2b_k<<<(16 * 384 * 128 / 4 + 255) / 256, blk, 0, stream>>>(WcTf, wctb, 16 * 384 * 128);
  f2b_k<<<(4 * 384 * 128 / 4 + 255) / 256, blk, 0, stream>>>(w_hh, whhb, 4 * 384 * 128);

  // ---- h0 = node_embed @ node_w^T + node_b; bf16 mirror ----
  gemm_k128<true, false, true, false><<<dim3(gM128, 2), blk, 0, stream>>>(
      node_embed, nullptr, node_w, node_b, h0, N_NODES, 128, 128);
  f2b_k<<<(NH / 4 + 255) / 256, blk, 0, stream>>>(h0, h0b, NH);
  init_hidden_k<<<gNH, blk, 0, stream>>>(hidden, cat_b);

  for (int k = 0; k < 4; k++) {
    const unsigned short* xbcur = h0b;
    const float* xfcur = h0;
    unsigned short* xbalt = xbA;
    for (int i = 0; i < 4; i++) {
      gather_b_k<<<(N_NODES * 64 + 255) / 256, blk, 0, stream>>>(xbcur, offsets,
                                                                 srcs_sorted, aggb);
      gru_mfma_k<<<dim3(gM64, 4), blk, 0, stream>>>(
          aggb, xbcur, xfcur, wctb + (size_t)(k * 4 + i) * 384 * 128,
          whhb + (size_t)k * 384 * 128, b_ih + k * 384, b_hh + k * 384, xfS,
          xbalt, N_NODES);
      xbcur = xbalt;
      xbalt = (xbalt == xbA) ? xbB : xbA;
      xfcur = xfS;  // in-place from step 1 on
    }
    // hidden += (xfS + h0) @ cat_w[:, k*128:(k+1)*128]^T   (residual fused)
    gemm_k128<true, true, false, true><<<dim3(gM128, 2), blk, 0, stream>>>(
        xfS, h0, cat_w + k * 128, nullptr, hidden, N_NODES, 128, 512);
  }

  // ---- heads ----
  lineout_k<<<(N_NODES + 15) / 16, blk, 0, stream>>>(hidden, line_w, line_b, out_line);

  float* gate = (float*)xbA;   // dead buffers post-loop
  float* ex = (float*)xbB;
  float* pooled = (float*)aggb;
  float* h1 = pooled + 512 * 128;
  float* h2 = h1 + 512 * 64;

  gate_k<<<(N_NODES * 64 + 255) / 256, blk, 0, stream>>>(hidden, gate_w, gate_b, gate);
  pool_fused_k<<<512, blk, 0, stream>>>(hidden, gate, gs, ex, pooled);
  mlp1_k<<<512, 64, 0, stream>>>(pooled, mlp_w1, mlp_b1, h1);
  mlp2_k<<<512, 64, 0, stream>>>(h1, mlp_w2, mlp_b2, h2);
  outhead_k<<<512, 64, 0, stream>>>(h2, out_w, out_b, out_graph);
}

// Round 6
// 4048.767 us; speedup vs baseline: 15.0237x; 1.4789x over previous
//
#include <hip/hip_runtime.h>

#define N_NODES 100000
#define N_EDGES 1600000
#define HD 128
#define NH (N_NODES * HD)

typedef __attribute__((ext_vector_type(8))) short bf16x8;
typedef __attribute__((ext_vector_type(4))) float f32x4;

__device__ inline unsigned short f2bf(float f) {
  unsigned u = __float_as_uint(f);
  unsigned r = (u + 0x7FFFu + ((u >> 16) & 1u)) >> 16;
  return (unsigned short)r;
}
__device__ inline float bf2f(unsigned short b) {
  return __uint_as_float(((unsigned)b) << 16);
}

// ---------------------------------------------------------------------------
// fp32 GEMM (h0 only): C = A[Mx128] @ B^T + bias, B [Ncols x 128] stride ldb
// ---------------------------------------------------------------------------
template <bool NT, bool ACC, bool BIAS, bool ADDH0>
__global__ __launch_bounds__(256) void gemm_k128(
    const float* __restrict__ A, const float* __restrict__ H0,
    const float* __restrict__ B, const float* __restrict__ bias,
    float* __restrict__ C, int M, int Ncols, int ldb) {
  __shared__ float As[16][132];
  __shared__ float Bs[16][68];
  const int tid = threadIdx.x;
  const int row0 = blockIdx.x * 128;
  const int col0 = blockIdx.y * 64;
  const int tx = tid & 15, ty = tid >> 4;

  float acc[8][4];
#pragma unroll
  for (int i = 0; i < 8; i++)
#pragma unroll
    for (int j = 0; j < 4; j++) acc[i][j] = 0.f;

  const int lr = tid >> 2;
  const int kg = (tid & 3) * 4;

  for (int k0 = 0; k0 < 128; k0 += 16) {
#pragma unroll
    for (int h = 0; h < 2; ++h) {
      int r = lr + h * 64;
      float4 v = make_float4(0.f, 0.f, 0.f, 0.f);
      if (row0 + r < M) {
        v = *reinterpret_cast<const float4*>(A + (size_t)(row0 + r) * 128 + k0 + kg);
        if (ADDH0) {
          float4 w = *reinterpret_cast<const float4*>(H0 + (size_t)(row0 + r) * 128 + k0 + kg);
          v.x += w.x; v.y += w.y; v.z += w.z; v.w += w.w;
        }
      }
      As[kg + 0][r] = v.x;
      As[kg + 1][r] = v.y;
      As[kg + 2][r] = v.z;
      As[kg + 3][r] = v.w;
    }
    if (NT) {
      int c = lr;
      float4 v = *reinterpret_cast<const float4*>(B + (size_t)(col0 + c) * ldb + k0 + kg);
      Bs[kg + 0][c] = v.x;
      Bs[kg + 1][c] = v.y;
      Bs[kg + 2][c] = v.z;
      Bs[kg + 3][c] = v.w;
    } else {
      int kk = tid >> 4;
      int cg = (tid & 15) * 4;
      float4 v = *reinterpret_cast<const float4*>(B + (size_t)(k0 + kk) * ldb + col0 + cg);
      Bs[kk][cg + 0] = v.x;
      Bs[kk][cg + 1] = v.y;
      Bs[kk][cg + 2] = v.z;
      Bs[kk][cg + 3] = v.w;
    }
    __syncthreads();
#pragma unroll
    for (int kk = 0; kk < 16; ++kk) {
      float a[8], b[4];
#pragma unroll
      for (int i = 0; i < 8; i++) a[i] = As[kk][ty * 8 + i];
#pragma unroll
      for (int j = 0; j < 4; j++) b[j] = Bs[kk][tx * 4 + j];
#pragma unroll
      for (int i = 0; i < 8; i++)
#pragma unroll
        for (int j = 0; j < 4; j++) acc[i][j] += a[i] * b[j];
    }
    __syncthreads();
  }

#pragma unroll
  for (int i = 0; i < 8; i++) {
    int r = row0 + ty * 8 + i;
    if (r < M) {
#pragma unroll
      for (int j = 0; j < 4; j++) {
        int c = col0 + tx * 4 + j;
        float v = acc[i][j];
        if (BIAS) v += bias[c];
        size_t idx = (size_t)r * Ncols + c;
        if (ACC) v += C[idx];
        C[idx] = v;
      }
    }
  }
}

// ---------------------------------------------------------------------------
// Batched WcT fold: C[z] = w_ih[z>>2] @ ggc_w[z]^T   ([384,128] each, z=0..15)
// ---------------------------------------------------------------------------
__global__ __launch_bounds__(256) void gemm_wct_k(
    const float* __restrict__ w_ih, const float* __restrict__ ggc_w,
    float* __restrict__ Cout) {
  const int z = blockIdx.z;
  const float* A = w_ih + (size_t)(z >> 2) * 384 * 128;
  const float* B = ggc_w + (size_t)z * 128 * 128;
  float* C = Cout + (size_t)z * 384 * 128;
  __shared__ float As[16][132];
  __shared__ float Bs[16][68];
  const int tid = threadIdx.x;
  const int row0 = blockIdx.x * 128;
  const int col0 = blockIdx.y * 64;
  const int tx = tid & 15, ty = tid >> 4;

  float acc[8][4];
#pragma unroll
  for (int i = 0; i < 8; i++)
#pragma unroll
    for (int j = 0; j < 4; j++) acc[i][j] = 0.f;

  const int lr = tid >> 2;
  const int kg = (tid & 3) * 4;

  for (int k0 = 0; k0 < 128; k0 += 16) {
#pragma unroll
    for (int h = 0; h < 2; ++h) {
      int r = lr + h * 64;
      float4 v = *reinterpret_cast<const float4*>(A + (size_t)(row0 + r) * 128 + k0 + kg);
      As[kg + 0][r] = v.x;
      As[kg + 1][r] = v.y;
      As[kg + 2][r] = v.z;
      As[kg + 3][r] = v.w;
    }
    {
      int c = lr;
      float4 v = *reinterpret_cast<const float4*>(B + (size_t)(col0 + c) * 128 + k0 + kg);
      Bs[kg + 0][c] = v.x;
      Bs[kg + 1][c] = v.y;
      Bs[kg + 2][c] = v.z;
      Bs[kg + 3][c] = v.w;
    }
    __syncthreads();
#pragma unroll
    for (int kk = 0; kk < 16; ++kk) {
      float a[8], b[4];
#pragma unroll
      for (int i = 0; i < 8; i++) a[i] = As[kk][ty * 8 + i];
#pragma unroll
      for (int j = 0; j < 4; j++) b[j] = Bs[kk][tx * 4 + j];
#pragma unroll
      for (int i = 0; i < 8; i++)
#pragma unroll
        for (int j = 0; j < 4; j++) acc[i][j] += a[i] * b[j];
    }
    __syncthreads();
  }

#pragma unroll
  for (int i = 0; i < 8; i++) {
    int r = row0 + ty * 8 + i;
#pragma unroll
    for (int j = 0; j < 4; j++) {
      int c = col0 + tx * 4 + j;
      C[(size_t)r * 128 + c] = acc[i][j];
    }
  }
}

// ---------------------------------------------------------------------------
// float -> bf16, 4 elems/thread
// ---------------------------------------------------------------------------
__global__ __launch_bounds__(256) void f2b_k(const float* __restrict__ a,
                                             unsigned short* __restrict__ b, int n) {
  int i = blockIdx.x * 256 + threadIdx.x;
  if (i * 4 >= n) return;
  float4 v = reinterpret_cast<const float4*>(a)[i];
  ushort4 o;
  o.x = f2bf(v.x);
  o.y = f2bf(v.y);
  o.z = f2bf(v.z);
  o.w = f2bf(v.w);
  reinterpret_cast<ushort4*>(b)[i] = o;
}

// ---------------------------------------------------------------------------
// GRU v2: per-wave 16-col slice, 24 weight fragments resident in VGPR,
// grid-stride over 16-row tiles. gi = aggb@wct^T, gh = xb@whh^T (bf16 MFMA),
// GRU elementwise epilogue.
//   LAST=0: write xout(fp32) + xbout(bf16 mirror)
//   LAST=1: write only xbout = bf16(x_new + h0)   (residual fused, outs)
// ---------------------------------------------------------------------------
template <bool LAST>
__global__ __launch_bounds__(256) void gru_mfma2_k(
    const unsigned short* __restrict__ aggb, const unsigned short* __restrict__ xb,
    const float* __restrict__ xf, const float* __restrict__ h0,
    const unsigned short* __restrict__ wctb, const unsigned short* __restrict__ whhb,
    const float* __restrict__ b_ih, const float* __restrict__ b_hh,
    float* __restrict__ xout, unsigned short* __restrict__ xbout,
    int M, int nRowTiles) {
  const int lane = threadIdx.x & 63;
  const int wave = threadIdx.x >> 6;
  const int lrow = lane & 15;
  const int kblk = lane >> 4;  // 0..3
  const int c = blockIdx.y * 16 + lrow;

  // 24 weight fragments, persistent
  bf16x8 wf[6][4];
#pragma unroll
  for (int s = 0; s < 3; s++)
#pragma unroll
    for (int kk = 0; kk < 4; kk++) {
      size_t off = (size_t)(s * 128 + c) * 128 + kk * 32 + kblk * 8;
      wf[s][kk] = *reinterpret_cast<const bf16x8*>(wctb + off);
      wf[s + 3][kk] = *reinterpret_cast<const bf16x8*>(whhb + off);
    }
  const float bi0 = b_ih[c], bi1 = b_ih[128 + c], bi2 = b_ih[256 + c];
  const float bh0 = b_hh[c], bh1 = b_hh[128 + c], bh2 = b_hh[256 + c];

  const int tstride = gridDim.x * 4;
  for (int rt = blockIdx.x * 4 + wave; rt < nRowTiles; rt += tstride) {
    const int row0 = rt * 16;
    int arow = row0 + lrow;
    if (arow >= M) arow = M - 1;
    const size_t abase = (size_t)arow * 128 + kblk * 8;

    f32x4 acc[6];
#pragma unroll
    for (int s = 0; s < 6; s++) acc[s] = (f32x4)(0.f);
#pragma unroll
    for (int kk = 0; kk < 4; kk++) {
      bf16x8 a_ag = *reinterpret_cast<const bf16x8*>(aggb + abase + kk * 32);
      bf16x8 a_x = *reinterpret_cast<const bf16x8*>(xb + abase + kk * 32);
      acc[0] = __builtin_amdgcn_mfma_f32_16x16x32_bf16(a_ag, wf[0][kk], acc[0], 0, 0, 0);
      acc[1] = __builtin_amdgcn_mfma_f32_16x16x32_bf16(a_ag, wf[1][kk], acc[1], 0, 0, 0);
      acc[2] = __builtin_amdgcn_mfma_f32_16x16x32_bf16(a_ag, wf[2][kk], acc[2], 0, 0, 0);
      acc[3] = __builtin_amdgcn_mfma_f32_16x16x32_bf16(a_x, wf[3][kk], acc[3], 0, 0, 0);
      acc[4] = __builtin_amdgcn_mfma_f32_16x16x32_bf16(a_x, wf[4][kk], acc[4], 0, 0, 0);
      acc[5] = __builtin_amdgcn_mfma_f32_16x16x32_bf16(a_x, wf[5][kk], acc[5], 0, 0, 0);
    }
    // C/D: col = lane&15 (= lrow -> c), row = kblk*4 + r
#pragma unroll
    for (int r = 0; r < 4; r++) {
      int orow = row0 + kblk * 4 + r;
      if (orow >= M) continue;
      size_t idx = (size_t)orow * 128 + c;
      float ir = acc[0][r] + bi0;
      float iz = acc[1][r] + bi1;
      float in_ = acc[2][r] + bi2;
      float hr = acc[3][r] + bh0;
      float hz = acc[4][r] + bh1;
      float hn = acc[5][r] + bh2;
      float rg = 1.f / (1.f + __expf(-(ir + hr)));
      float zg = 1.f / (1.f + __expf(-(iz + hz)));
      float ng = tanhf(in_ + rg * hn);
      float h = xf[idx];
      float nv = (1.f - zg) * ng + zg * h;
      if (LAST) {
        xbout[idx] = f2bf(nv + h0[idx]);
      } else {
        xout[idx] = nv;
        xbout[idx] = f2bf(nv);
      }
    }
  }
}

// ---------------------------------------------------------------------------
// cat projection via MFMA: hidden (+)= outs @ wcat_k^T  (+cat_b at k==0)
// wcatb: [128][512] bf16 row-major (full cat_w); slice cols k*128..+127
// ---------------------------------------------------------------------------
__global__ __launch_bounds__(256) void cat_mfma_k(
    const unsigned short* __restrict__ outsb, const unsigned short* __restrict__ wcatb,
    const float* __restrict__ cat_b, float* __restrict__ hidden, int M, int kblock) {
  const int lane = threadIdx.x & 63;
  const int wave = threadIdx.x >> 6;
  const int row0 = blockIdx.x * 64 + wave * 16;
  const int c0 = blockIdx.y * 32;
  const int lrow = lane & 15;
  const int kb = lane >> 4;
  int arow = row0 + lrow;
  if (arow >= M) arow = M - 1;
  const size_t abase = (size_t)arow * 128 + kb * 8;

  f32x4 acc[2];
  acc[0] = (f32x4)(0.f);
  acc[1] = (f32x4)(0.f);
#pragma unroll
  for (int kk = 0; kk < 4; kk++) {
    bf16x8 a = *reinterpret_cast<const bf16x8*>(outsb + abase + kk * 32);
#pragma unroll
    for (int t = 0; t < 2; t++) {
      bf16x8 b = *reinterpret_cast<const bf16x8*>(
          wcatb + (size_t)(c0 + t * 16 + lrow) * 512 + kblock * 128 + kk * 32 + kb * 8);
      acc[t] = __builtin_amdgcn_mfma_f32_16x16x32_bf16(a, b, acc[t], 0, 0, 0);
    }
  }
#pragma unroll
  for (int r = 0; r < 4; r++) {
    int orow = row0 + kb * 4 + r;
    if (orow >= M) continue;
#pragma unroll
    for (int t = 0; t < 2; t++) {
      int c = c0 + t * 16 + lrow;
      size_t idx = (size_t)orow * 128 + c;
      float v = acc[t][r];
      v += (kblock == 0) ? cat_b[c] : hidden[idx];
      hidden[idx] = v;
    }
  }
}

// ---------------------------------------------------------------------------
// CSR build
// ---------------------------------------------------------------------------
__global__ __launch_bounds__(256) void deg_hist_k(const int* __restrict__ dst,
                                                  int* __restrict__ deg) {
  int e = blockIdx.x * 256 + threadIdx.x;
  if (e >= N_EDGES) return;
  atomicAdd(&deg[dst[e]], 1);
}

__global__ __launch_bounds__(256) void scan1_k(const int* __restrict__ deg,
                                               int* __restrict__ offsets,
                                               int* __restrict__ bsum) {
  __shared__ int buf[256];
  int tid = threadIdx.x;
  int idx = blockIdx.x * 256 + tid;
  int v = (idx < N_NODES) ? deg[idx] : 0;
  buf[tid] = v;
  __syncthreads();
  for (int off = 1; off < 256; off <<= 1) {
    int t = (tid >= off) ? buf[tid - off] : 0;
    __syncthreads();
    buf[tid] += t;
    __syncthreads();
  }
  if (idx < N_NODES) offsets[idx] = buf[tid] - v;
  if (tid == 255) bsum[blockIdx.x] = buf[255];
}

__global__ __launch_bounds__(512) void scan2_k(int* __restrict__ bsum, int nb) {
  __shared__ int buf[512];
  int tid = threadIdx.x;
  int v = (tid < nb) ? bsum[tid] : 0;
  buf[tid] = v;
  __syncthreads();
  for (int off = 1; off < 512; off <<= 1) {
    int t = (tid >= off) ? buf[tid - off] : 0;
    __syncthreads();
    buf[tid] += t;
    __syncthreads();
  }
  if (tid < nb) bsum[tid] = buf[tid] - v;
}

__global__ __launch_bounds__(256) void scan3_k(int* __restrict__ offsets,
                                               const int* __restrict__ bsum) {
  int idx = blockIdx.x * 256 + threadIdx.x;
  if (idx < N_NODES) offsets[idx] += bsum[idx >> 8];
  if (idx == 0) offsets[N_NODES] = N_EDGES;
}

__global__ __launch_bounds__(256) void copy_int_k(const int* __restrict__ a,
                                                  int* __restrict__ b, int n) {
  int i = blockIdx.x * 256 + threadIdx.x;
  if (i < n) b[i] = a[i];
}

__global__ __launch_bounds__(256) void fill_k(const int* __restrict__ src,
                                              const int* __restrict__ dst,
                                              int* __restrict__ cursor,
                                              int* __restrict__ srcs_sorted) {
  int e = blockIdx.x * 256 + threadIdx.x;
  if (e >= N_EDGES) return;
  int pos = atomicAdd(&cursor[dst[e]], 1);
  srcs_sorted[pos] = src[e];
}

// ---------------------------------------------------------------------------
// gather: 2 edges/iter per wave (lanes split 32/32, 8B loads), shfl combine
// ---------------------------------------------------------------------------
__global__ __launch_bounds__(256) void gather_b_k(
    const unsigned short* __restrict__ xb, const int* __restrict__ offsets,
    const int* __restrict__ srcs, unsigned short* __restrict__ out) {
  int node = (blockIdx.x * 256 + threadIdx.x) >> 6;
  int lane = threadIdx.x & 63;
  if (node >= N_NODES) return;
  int beg = offsets[node], end = offsets[node + 1];
  int half = lane >> 5;
  int cg = (lane & 31) * 4;
  float a0 = 0.f, a1 = 0.f, a2 = 0.f, a3 = 0.f;
  for (int e = beg + half; e < end; e += 2) {
    int s = srcs[e];
    uint2 v = *reinterpret_cast<const uint2*>(xb + (size_t)s * 128 + cg);
    a0 += bf2f((unsigned short)(v.x & 0xFFFFu));
    a1 += bf2f((unsigned short)(v.x >> 16));
    a2 += bf2f((unsigned short)(v.y & 0xFFFFu));
    a3 += bf2f((unsigned short)(v.y >> 16));
  }
  a0 += __shfl_down(a0, 32);
  a1 += __shfl_down(a1, 32);
  a2 += __shfl_down(a2, 32);
  a3 += __shfl_down(a3, 32);
  if (half == 0) {
    uint2 o;
    o.x = (unsigned)f2bf(a0) | ((unsigned)f2bf(a1) << 16);
    o.y = (unsigned)f2bf(a2) | ((unsigned)f2bf(a3) << 16);
    *reinterpret_cast<uint2*>(out + (size_t)node * 128 + cg) = o;
  }
}

// lineout = hidden @ line_w^T + line_b
__global__ __launch_bounds__(256) void lineout_k(
    const float* __restrict__ hidden, const float* __restrict__ W,
    const float* __restrict__ b, float* __restrict__ out) {
  __shared__ float Ws[16 * 128];
  for (int i = threadIdx.x; i < 2048; i += 256) Ws[i] = W[i];
  __syncthreads();
  int r = threadIdx.x >> 4, c = threadIdx.x & 15;
  int n = blockIdx.x * 16 + r;
  if (n >= N_NODES) return;
  const float* h = hidden + (size_t)n * 128;
  const float* w = Ws + c * 128;
  float acc = 0.f;
#pragma unroll 8
  for (int k = 0; k < 128; k++) acc += h[k] * w[k];
  out[(size_t)n * 16 + c] = acc + b[c];
}

// gate[n] = hidden[n] . gate_w + gate_b
__global__ __launch_bounds__(256) void gate_k(
    const float* __restrict__ hidden, const float* __restrict__ gw,
    const float* __restrict__ gb, float* __restrict__ gate) {
  int wid = (blockIdx.x * 256 + threadIdx.x) >> 6;
  int lane = threadIdx.x & 63;
  if (wid >= N_NODES) return;
  const float* h = hidden + (size_t)wid * 128;
  float s = h[lane] * gw[lane] + h[64 + lane] * gw[64 + lane];
#pragma unroll
  for (int off = 32; off; off >>= 1) s += __shfl_down(s, off);
  if (lane == 0) gate[wid] = s + gb[0];
}

// gs[g] = lower_bound(batch, g)
__global__ void graph_start_k(const int* __restrict__ batch, int* __restrict__ gs) {
  int g = threadIdx.x;
  if (g > 512) return;
  if (g == 512) {
    gs[512] = N_NODES;
    return;
  }
  int lo = 0, hi = N_NODES;
  while (lo < hi) {
    int mid = (lo + hi) >> 1;
    if (batch[mid] < g) lo = mid + 1;
    else hi = mid;
  }
  gs[g] = lo;
}

// ---------------------------------------------------------------------------
// Per-graph attention pool (batch sorted, no atomics)
// ---------------------------------------------------------------------------
__global__ __launch_bounds__(256) void pool_fused_k(
    const float* __restrict__ hidden, const float* __restrict__ gate,
    const int* __restrict__ gs, float* __restrict__ ex,
    float* __restrict__ pooled) {
  const int g = blockIdx.x;
  const int beg = gs[g], end = gs[g + 1];
  const int tid = threadIdx.x, lane = tid & 63, wv = tid >> 6;
  __shared__ float red[4];
  __shared__ float sval;
  __shared__ float colbuf[256];

  if (end <= beg) {
    if (tid < 128) pooled[(size_t)g * 128 + tid] = 0.f;
    return;
  }
  float m = -3.4e38f;
  for (int n = beg + tid; n < end; n += 256) m = fmaxf(m, gate[n]);
#pragma unroll
  for (int off = 32; off; off >>= 1) m = fmaxf(m, __shfl_down(m, off));
  if (lane == 0) red[wv] = m;
  __syncthreads();
  if (tid == 0) sval = fmaxf(fmaxf(red[0], red[1]), fmaxf(red[2], red[3]));
  __syncthreads();
  const float mx = sval;
  float s = 0.f;
  for (int n = beg + tid; n < end; n += 256) {
    float e = __expf(gate[n] - mx);
    ex[n] = e;
    s += e;
  }
#pragma unroll
  for (int off = 32; off; off >>= 1) s += __shfl_down(s, off);
  if (lane == 0) red[wv] = s;
  __syncthreads();
  if (tid == 0) sval = red[0] + red[1] + red[2] + red[3];
  __syncthreads();
  const float denom = sval;
  const int col = tid & 127, half = tid >> 7;
  float acc = 0.f;
  for (int n = beg + half; n < end; n += 2)
    acc += ex[n] * hidden[(size_t)n * 128 + col];
  colbuf[tid] = acc;
  __syncthreads();
  if (tid < 128)
    pooled[(size_t)g * 128 + tid] = (colbuf[tid] + colbuf[tid + 128]) / denom;
}

__global__ void mlp1_k(const float* __restrict__ pooled, const float* __restrict__ w,
                       const float* __restrict__ b, float* __restrict__ h1) {
  int g = blockIdx.x, j = threadIdx.x;
  const float* p = pooled + (size_t)g * 128;
  const float* wr = w + (size_t)j * 128;
  float acc = 0.f;
#pragma unroll 8
  for (int k = 0; k < 128; k++) acc += p[k] * wr[k];
  acc += b[j];
  h1[g * 64 + j] = acc > 0.f ? acc : 0.f;
}

__global__ void mlp2_k(const float* __restrict__ h1, const float* __restrict__ w,
                       const float* __restrict__ b, float* __restrict__ h2) {
  int g = blockIdx.x, j = threadIdx.x;
  const float* p = h1 + (size_t)g * 64;
  const float* wr = w + (size_t)j * 64;
  float acc = 0.f;
#pragma unroll 8
  for (int k = 0; k < 64; k++) acc += p[k] * wr[k];
  acc += b[j];
  h2[g * 64 + j] = acc > 0.f ? acc : 0.f;
}

__global__ void outhead_k(const float* __restrict__ h2, const float* __restrict__ w,
                          const float* __restrict__ b, float* __restrict__ out) {
  int g = blockIdx.x, j = threadIdx.x;
  if (j >= 16) return;
  const float* p = h2 + (size_t)g * 64;
  const float* wr = w + (size_t)j * 64;
  float acc = 0.f;
#pragma unroll 8
  for (int k = 0; k < 64; k++) acc += p[k] * wr[k];
  out[g * 16 + j] = acc + b[j];
}

extern "C" void kernel_launch(void* const* d_in, const int* in_sizes, int n_in,
                              void* d_out, int out_size, void* d_ws, size_t ws_size,
                              hipStream_t stream) {
  const float* node_embed = (const float*)d_in[0];
  const int* eidx = (const int*)d_in[1];
  const int* batch = (const int*)d_in[2];
  const float* node_w = (const float*)d_in[3];
  const float* node_b = (const float*)d_in[4];
  const float* ggc_w = (const float*)d_in[5];
  const float* w_ih = (const float*)d_in[6];
  const float* w_hh = (const float*)d_in[7];
  const float* b_ih = (const float*)d_in[8];
  const float* b_hh = (const float*)d_in[9];
  const float* cat_w = (const float*)d_in[10];
  const float* cat_b = (const float*)d_in[11];
  const float* gate_w = (const float*)d_in[12];
  const float* gate_b = (const float*)d_in[13];
  const float* mlp_w1 = (const float*)d_in[14];
  const float* mlp_b1 = (const float*)d_in[15];
  const float* mlp_w2 = (const float*)d_in[16];
  const float* mlp_b2 = (const float*)d_in[17];
  const float* out_w = (const float*)d_in[18];
  const float* out_b = (const float*)d_in[19];
  const float* line_w = (const float*)d_in[20];
  const float* line_b = (const float*)d_in[21];

  const int* src = eidx;
  const int* dst = eidx + N_EDGES;

  // workspace (~265 MB, same extent as proven round-5 layout)
  float* ws = (float*)d_ws;
  float* h0 = ws;                                   // [NH] f32
  float* hidden = h0 + (size_t)NH;                  // [NH] f32
  float* xfS = hidden + (size_t)NH;                 // [NH] f32 (in-place state)
  unsigned short* h0b = (unsigned short*)(xfS + (size_t)NH);  // [NH] bf16
  unsigned short* xbA = h0b + (size_t)NH;           // [NH] bf16
  unsigned short* xbB = xbA + (size_t)NH;           // [NH] bf16 (also outs)
  unsigned short* aggb = xbB + (size_t)NH;          // [NH] bf16
  unsigned short* wctb = aggb + (size_t)NH;         // 16*384*128 bf16
  unsigned short* whhb = wctb + 16 * 384 * 128;     // 4*384*128 bf16
  unsigned short* wcatb = whhb + 4 * 384 * 128;     // 128*512 bf16
  int* offsets = (int*)(wcatb + 128 * 512);         // [N+1]
  int* cursor = offsets + N_NODES + 1;              // [N]
  int* srcs_sorted = cursor + N_NODES;              // [E]
  int* bsum = srcs_sorted + N_EDGES;                // [512]
  int* gs = bsum + 512;                             // [513]
  float* WcTf = xfS;                                // fp32 staging overlay (pre-loop)

  float* out_graph = (float*)d_out;
  float* out_line = (float*)d_out + 512 * 16;

  dim3 blk(256);
  const int gM128 = (N_NODES + 127) / 128;
  const int gM64 = (N_NODES + 63) / 64;
  const int gE = (N_EDGES + 255) / 256;
  const int nScanBlk = (N_NODES + 255) / 256;
  const int nRowTiles = (N_NODES + 15) / 16;  // 6250

  // ---- CSR build ----
  hipMemsetAsync(cursor, 0, N_NODES * sizeof(int), stream);
  deg_hist_k<<<gE, blk, 0, stream>>>(dst, cursor);
  scan1_k<<<nScanBlk, blk, 0, stream>>>(cursor, offsets, bsum);
  scan2_k<<<1, 512, 0, stream>>>(bsum, nScanBlk);
  scan3_k<<<nScanBlk, blk, 0, stream>>>(offsets, bsum);
  copy_int_k<<<(N_NODES + 255) / 256, blk, 0, stream>>>(offsets, cursor, N_NODES);
  fill_k<<<gE, blk, 0, stream>>>(src, dst, cursor, srcs_sorted);
  graph_start_k<<<1, 576, 0, stream>>>(batch, gs);

  // ---- weights: WcT fold (fp32) -> bf16; w_hh, cat_w -> bf16 ----
  gemm_wct_k<<<dim3(3, 2, 16), blk, 0, stream>>>(w_ih, ggc_w, WcTf);
  f2b_k<<<(16 * 384 * 128 / 4 + 255) / 256, blk, 0, stream>>>(WcTf, wctb, 16 * 384 * 128);
  f2b_k<<<(4 * 384 * 128 / 4 + 255) / 256, blk, 0, stream>>>(w_hh, whhb, 4 * 384 * 128);
  f2b_k<<<(128 * 512 / 4 + 255) / 256, blk, 0, stream>>>(cat_w, wcatb, 128 * 512);

  // ---- h0 = node_embed @ node_w^T + node_b; bf16 mirror ----
  gemm_k128<true, false, true, false><<<dim3(gM128, 2), blk, 0, stream>>>(
      node_embed, nullptr, node_w, node_b, h0, N_NODES, 128, 128);
  f2b_k<<<(NH / 4 + 255) / 256, blk, 0, stream>>>(h0, h0b, NH);

  const dim3 gruGrid(200, 8);  // gridDim.x % 8 == 0 -> col-tiles share XCD
  for (int k = 0; k < 4; k++) {
    const unsigned short* wct_k = wctb + (size_t)(k * 4) * 384 * 128;
    const unsigned short* whh_k = whhb + (size_t)k * 384 * 128;
    const float* bih_k = b_ih + k * 384;
    const float* bhh_k = b_hh + k * 384;
    // i=0: read h0b/h0 -> xfS, xbA
    gather_b_k<<<(N_NODES * 64 + 255) / 256, blk, 0, stream>>>(h0b, offsets, srcs_sorted, aggb);
    gru_mfma2_k<false><<<gruGrid, blk, 0, stream>>>(
        aggb, h0b, h0, h0, wct_k, whh_k, bih_k, bhh_k, xfS, xbA, N_NODES, nRowTiles);
    // i=1: read xbA/xfS -> xfS, xbB
    gather_b_k<<<(N_NODES * 64 + 255) / 256, blk, 0, stream>>>(xbA, offsets, srcs_sorted, aggb);
    gru_mfma2_k<false><<<gruGrid, blk, 0, stream>>>(
        aggb, xbA, xfS, h0, wct_k + (size_t)384 * 128, whh_k, bih_k, bhh_k, xfS, xbB, N_NODES, nRowTiles);
    // i=2: read xbB/xfS -> xfS, xbA
    gather_b_k<<<(N_NODES * 64 + 255) / 256, blk, 0, stream>>>(xbB, offsets, srcs_sorted, aggb);
    gru_mfma2_k<false><<<gruGrid, blk, 0, stream>>>(
        aggb, xbB, xfS, h0, wct_k + (size_t)2 * 384 * 128, whh_k, bih_k, bhh_k, xfS, xbA, N_NODES, nRowTiles);
    // i=3 (LAST): read xbA/xfS -> outs (=xbB) = bf16(x_new + h0)
    gather_b_k<<<(N_NODES * 64 + 255) / 256, blk, 0, stream>>>(xbA, offsets, srcs_sorted, aggb);
    gru_mfma2_k<true><<<gruGrid, blk, 0, stream>>>(
        aggb, xbA, xfS, h0, wct_k + (size_t)3 * 384 * 128, whh_k, bih_k, bhh_k, xfS, xbB, N_NODES, nRowTiles);
    // hidden (+)= outs @ cat_w[:, k*128:(k+1)*128]^T  (+cat_b at k==0)
    cat_mfma_k<<<dim3(gM64, 4), blk, 0, stream>>>(xbB, wcatb, cat_b, hidden, N_NODES, k);
  }

  // ---- heads ----
  lineout_k<<<(N_NODES + 15) / 16, blk, 0, stream>>>(hidden, line_w, line_b, out_line);

  float* gate = (float*)xbA;
  float* ex = (float*)xbB;
  float* pooled = (float*)aggb;
  float* h1 = pooled + 512 * 128;
  float* h2 = h1 + 512 * 64;

  gate_k<<<(N_NODES * 64 + 255) / 256, blk, 0, stream>>>(hidden, gate_w, gate_b, gate);
  pool_fused_k<<<512, blk, 0, stream>>>(hidden, gate, gs, ex, pooled);
  mlp1_k<<<512, 64, 0, stream>>>(pooled, mlp_w1, mlp_b1, h1);
  mlp2_k<<<512, 64, 0, stream>>>(h1, mlp_w2, mlp_b2, h2);
  outhead_k<<<512, 64, 0, stream>>>(h2, out_w, out_b, out_graph);
}

// Round 7
// 3411.353 us; speedup vs baseline: 17.8309x; 1.1869x over previous
//
#include <hip/hip_runtime.h>

#define N_NODES 100000
#define N_EDGES 1600000
#define HD 128
#define NH (N_NODES * HD)

typedef __attribute__((ext_vector_type(8))) short bf16x8;
typedef __attribute__((ext_vector_type(4))) float f32x4;

__device__ inline unsigned short f2bf(float f) {
  unsigned u = __float_as_uint(f);
  unsigned r = (u + 0x7FFFu + ((u >> 16) & 1u)) >> 16;
  return (unsigned short)r;
}
__device__ inline float bf2f(unsigned short b) {
  return __uint_as_float(((unsigned)b) << 16);
}
// fast sigmoid / tanh (rcp approx ~1e-6 rel; saturates correctly at +-inf)
__device__ inline float sigm_f(float x) {
  return __builtin_amdgcn_rcpf(1.f + __expf(-x));
}
__device__ inline float tanh_f(float x) {
  return 1.f - 2.f * __builtin_amdgcn_rcpf(__expf(2.f * x) + 1.f);
}

// ---------------------------------------------------------------------------
// fp32 GEMM (h0 only): C = A[Mx128] @ B^T + bias, B [Ncols x 128] stride ldb
// ---------------------------------------------------------------------------
template <bool NT, bool ACC, bool BIAS, bool ADDH0>
__global__ __launch_bounds__(256) void gemm_k128(
    const float* __restrict__ A, const float* __restrict__ H0,
    const float* __restrict__ B, const float* __restrict__ bias,
    float* __restrict__ C, int M, int Ncols, int ldb) {
  __shared__ float As[16][132];
  __shared__ float Bs[16][68];
  const int tid = threadIdx.x;
  const int row0 = blockIdx.x * 128;
  const int col0 = blockIdx.y * 64;
  const int tx = tid & 15, ty = tid >> 4;

  float acc[8][4];
#pragma unroll
  for (int i = 0; i < 8; i++)
#pragma unroll
    for (int j = 0; j < 4; j++) acc[i][j] = 0.f;

  const int lr = tid >> 2;
  const int kg = (tid & 3) * 4;

  for (int k0 = 0; k0 < 128; k0 += 16) {
#pragma unroll
    for (int h = 0; h < 2; ++h) {
      int r = lr + h * 64;
      float4 v = make_float4(0.f, 0.f, 0.f, 0.f);
      if (row0 + r < M) {
        v = *reinterpret_cast<const float4*>(A + (size_t)(row0 + r) * 128 + k0 + kg);
        if (ADDH0) {
          float4 w = *reinterpret_cast<const float4*>(H0 + (size_t)(row0 + r) * 128 + k0 + kg);
          v.x += w.x; v.y += w.y; v.z += w.z; v.w += w.w;
        }
      }
      As[kg + 0][r] = v.x;
      As[kg + 1][r] = v.y;
      As[kg + 2][r] = v.z;
      As[kg + 3][r] = v.w;
    }
    if (NT) {
      int c = lr;
      float4 v = *reinterpret_cast<const float4*>(B + (size_t)(col0 + c) * ldb + k0 + kg);
      Bs[kg + 0][c] = v.x;
      Bs[kg + 1][c] = v.y;
      Bs[kg + 2][c] = v.z;
      Bs[kg + 3][c] = v.w;
    } else {
      int kk = tid >> 4;
      int cg = (tid & 15) * 4;
      float4 v = *reinterpret_cast<const float4*>(B + (size_t)(k0 + kk) * ldb + col0 + cg);
      Bs[kk][cg + 0] = v.x;
      Bs[kk][cg + 1] = v.y;
      Bs[kk][cg + 2] = v.z;
      Bs[kk][cg + 3] = v.w;
    }
    __syncthreads();
#pragma unroll
    for (int kk = 0; kk < 16; ++kk) {
      float a[8], b[4];
#pragma unroll
      for (int i = 0; i < 8; i++) a[i] = As[kk][ty * 8 + i];
#pragma unroll
      for (int j = 0; j < 4; j++) b[j] = Bs[kk][tx * 4 + j];
#pragma unroll
      for (int i = 0; i < 8; i++)
#pragma unroll
        for (int j = 0; j < 4; j++) acc[i][j] += a[i] * b[j];
    }
    __syncthreads();
  }

#pragma unroll
  for (int i = 0; i < 8; i++) {
    int r = row0 + ty * 8 + i;
    if (r < M) {
#pragma unroll
      for (int j = 0; j < 4; j++) {
        int c = col0 + tx * 4 + j;
        float v = acc[i][j];
        if (BIAS) v += bias[c];
        size_t idx = (size_t)r * Ncols + c;
        if (ACC) v += C[idx];
        C[idx] = v;
      }
    }
  }
}

// ---------------------------------------------------------------------------
// Batched WcT fold: C[z] = w_ih[z>>2] @ ggc_w[z]^T   ([384,128] each, z=0..15)
// ---------------------------------------------------------------------------
__global__ __launch_bounds__(256) void gemm_wct_k(
    const float* __restrict__ w_ih, const float* __restrict__ ggc_w,
    float* __restrict__ Cout) {
  const int z = blockIdx.z;
  const float* A = w_ih + (size_t)(z >> 2) * 384 * 128;
  const float* B = ggc_w + (size_t)z * 128 * 128;
  float* C = Cout + (size_t)z * 384 * 128;
  __shared__ float As[16][132];
  __shared__ float Bs[16][68];
  const int tid = threadIdx.x;
  const int row0 = blockIdx.x * 128;
  const int col0 = blockIdx.y * 64;
  const int tx = tid & 15, ty = tid >> 4;

  float acc[8][4];
#pragma unroll
  for (int i = 0; i < 8; i++)
#pragma unroll
    for (int j = 0; j < 4; j++) acc[i][j] = 0.f;

  const int lr = tid >> 2;
  const int kg = (tid & 3) * 4;

  for (int k0 = 0; k0 < 128; k0 += 16) {
#pragma unroll
    for (int h = 0; h < 2; ++h) {
      int r = lr + h * 64;
      float4 v = *reinterpret_cast<const float4*>(A + (size_t)(row0 + r) * 128 + k0 + kg);
      As[kg + 0][r] = v.x;
      As[kg + 1][r] = v.y;
      As[kg + 2][r] = v.z;
      As[kg + 3][r] = v.w;
    }
    {
      int c = lr;
      float4 v = *reinterpret_cast<const float4*>(B + (size_t)(col0 + c) * 128 + k0 + kg);
      Bs[kg + 0][c] = v.x;
      Bs[kg + 1][c] = v.y;
      Bs[kg + 2][c] = v.z;
      Bs[kg + 3][c] = v.w;
    }
    __syncthreads();
#pragma unroll
    for (int kk = 0; kk < 16; ++kk) {
      float a[8], b[4];
#pragma unroll
      for (int i = 0; i < 8; i++) a[i] = As[kk][ty * 8 + i];
#pragma unroll
      for (int j = 0; j < 4; j++) b[j] = Bs[kk][tx * 4 + j];
#pragma unroll
      for (int i = 0; i < 8; i++)
#pragma unroll
        for (int j = 0; j < 4; j++) acc[i][j] += a[i] * b[j];
    }
    __syncthreads();
  }

#pragma unroll
  for (int i = 0; i < 8; i++) {
    int r = row0 + ty * 8 + i;
#pragma unroll
    for (int j = 0; j < 4; j++) {
      int c = col0 + tx * 4 + j;
      C[(size_t)r * 128 + c] = acc[i][j];
    }
  }
}

// ---------------------------------------------------------------------------
// float -> bf16, 4 elems/thread
// ---------------------------------------------------------------------------
__global__ __launch_bounds__(256) void f2b_k(const float* __restrict__ a,
                                             unsigned short* __restrict__ b, int n) {
  int i = blockIdx.x * 256 + threadIdx.x;
  if (i * 4 >= n) return;
  float4 v = reinterpret_cast<const float4*>(a)[i];
  ushort4 o;
  o.x = f2bf(v.x);
  o.y = f2bf(v.y);
  o.z = f2bf(v.z);
  o.w = f2bf(v.w);
  reinterpret_cast<ushort4*>(b)[i] = o;
}

// ---------------------------------------------------------------------------
// GRU v3: bf16-only state. Per-wave 16-col slice, 24 weight fragments in
// VGPR, grid-stride over 16-row tiles. gi = aggb@wct^T, gh = xb@whh^T.
// Epilogue: fast sigmoid/tanh; h read as bf16.
//   LAST=0: xbout = bf16(x_new)
//   LAST=1: xbout = bf16(x_new + h0b)   (residual fused -> outs)
// ---------------------------------------------------------------------------
template <bool LAST>
__global__ __launch_bounds__(256) void gru_mfma3_k(
    const unsigned short* __restrict__ aggb, const unsigned short* __restrict__ xb,
    const unsigned short* __restrict__ h0b,
    const unsigned short* __restrict__ wctb, const unsigned short* __restrict__ whhb,
    const float* __restrict__ b_ih, const float* __restrict__ b_hh,
    unsigned short* __restrict__ xbout, int M, int nRowTiles) {
  const int lane = threadIdx.x & 63;
  const int wave = threadIdx.x >> 6;
  const int lrow = lane & 15;
  const int kblk = lane >> 4;  // 0..3
  const int c = blockIdx.y * 16 + lrow;

  // 24 weight fragments, persistent in regs
  bf16x8 wf[6][4];
#pragma unroll
  for (int s = 0; s < 3; s++)
#pragma unroll
    for (int kk = 0; kk < 4; kk++) {
      size_t off = (size_t)(s * 128 + c) * 128 + kk * 32 + kblk * 8;
      wf[s][kk] = *reinterpret_cast<const bf16x8*>(wctb + off);
      wf[s + 3][kk] = *reinterpret_cast<const bf16x8*>(whhb + off);
    }
  const float bi0 = b_ih[c], bi1 = b_ih[128 + c], bi2 = b_ih[256 + c];
  const float bh0 = b_hh[c], bh1 = b_hh[128 + c], bh2 = b_hh[256 + c];

  const int tstride = gridDim.x * 4;
  for (int rt = blockIdx.x * 4 + wave; rt < nRowTiles; rt += tstride) {
    const int row0 = rt * 16;
    int arow = row0 + lrow;
    if (arow >= M) arow = M - 1;
    const size_t abase = (size_t)arow * 128 + kblk * 8;

    f32x4 acc[6];
#pragma unroll
    for (int s = 0; s < 6; s++) acc[s] = (f32x4)(0.f);
#pragma unroll
    for (int kk = 0; kk < 4; kk++) {
      bf16x8 a_ag = *reinterpret_cast<const bf16x8*>(aggb + abase + kk * 32);
      bf16x8 a_x = *reinterpret_cast<const bf16x8*>(xb + abase + kk * 32);
      acc[0] = __builtin_amdgcn_mfma_f32_16x16x32_bf16(a_ag, wf[0][kk], acc[0], 0, 0, 0);
      acc[1] = __builtin_amdgcn_mfma_f32_16x16x32_bf16(a_ag, wf[1][kk], acc[1], 0, 0, 0);
      acc[2] = __builtin_amdgcn_mfma_f32_16x16x32_bf16(a_ag, wf[2][kk], acc[2], 0, 0, 0);
      acc[3] = __builtin_amdgcn_mfma_f32_16x16x32_bf16(a_x, wf[3][kk], acc[3], 0, 0, 0);
      acc[4] = __builtin_amdgcn_mfma_f32_16x16x32_bf16(a_x, wf[4][kk], acc[4], 0, 0, 0);
      acc[5] = __builtin_amdgcn_mfma_f32_16x16x32_bf16(a_x, wf[5][kk], acc[5], 0, 0, 0);
    }
    // C/D: col = lane&15 (= lrow -> c), row = kblk*4 + r
#pragma unroll
    for (int r = 0; r < 4; r++) {
      int orow = row0 + kblk * 4 + r;
      if (orow >= M) continue;
      size_t idx = (size_t)orow * 128 + c;
      float ir = acc[0][r] + bi0;
      float iz = acc[1][r] + bi1;
      float in_ = acc[2][r] + bi2;
      float hr = acc[3][r] + bh0;
      float hz = acc[4][r] + bh1;
      float hn = acc[5][r] + bh2;
      float rg = sigm_f(ir + hr);
      float zg = sigm_f(iz + hz);
      float ng = tanh_f(in_ + rg * hn);
      float h = bf2f(xb[idx]);
      float nv = (1.f - zg) * ng + zg * h;
      if (LAST) nv += bf2f(h0b[idx]);
      xbout[idx] = f2bf(nv);
    }
  }
}

// ---------------------------------------------------------------------------
// cat projection via MFMA: hidden (+)= outs @ wcat_k^T  (+cat_b at k==0)
// ---------------------------------------------------------------------------
__global__ __launch_bounds__(256) void cat_mfma_k(
    const unsigned short* __restrict__ outsb, const unsigned short* __restrict__ wcatb,
    const float* __restrict__ cat_b, float* __restrict__ hidden, int M, int kblock) {
  const int lane = threadIdx.x & 63;
  const int wave = threadIdx.x >> 6;
  const int row0 = blockIdx.x * 64 + wave * 16;
  const int c0 = blockIdx.y * 32;
  const int lrow = lane & 15;
  const int kb = lane >> 4;
  int arow = row0 + lrow;
  if (arow >= M) arow = M - 1;
  const size_t abase = (size_t)arow * 128 + kb * 8;

  f32x4 acc[2];
  acc[0] = (f32x4)(0.f);
  acc[1] = (f32x4)(0.f);
#pragma unroll
  for (int kk = 0; kk < 4; kk++) {
    bf16x8 a = *reinterpret_cast<const bf16x8*>(outsb + abase + kk * 32);
#pragma unroll
    for (int t = 0; t < 2; t++) {
      bf16x8 b = *reinterpret_cast<const bf16x8*>(
          wcatb + (size_t)(c0 + t * 16 + lrow) * 512 + kblock * 128 + kk * 32 + kb * 8);
      acc[t] = __builtin_amdgcn_mfma_f32_16x16x32_bf16(a, b, acc[t], 0, 0, 0);
    }
  }
#pragma unroll
  for (int r = 0; r < 4; r++) {
    int orow = row0 + kb * 4 + r;
    if (orow >= M) continue;
#pragma unroll
    for (int t = 0; t < 2; t++) {
      int c = c0 + t * 16 + lrow;
      size_t idx = (size_t)orow * 128 + c;
      float v = acc[t][r];
      v += (kblock == 0) ? cat_b[c] : hidden[idx];
      hidden[idx] = v;
    }
  }
}

// ---------------------------------------------------------------------------
// CSR build
// ---------------------------------------------------------------------------
__global__ __launch_bounds__(256) void deg_hist_k(const int* __restrict__ dst,
                                                  int* __restrict__ deg) {
  int e = blockIdx.x * 256 + threadIdx.x;
  if (e >= N_EDGES) return;
  atomicAdd(&deg[dst[e]], 1);
}

__global__ __launch_bounds__(256) void scan1_k(const int* __restrict__ deg,
                                               int* __restrict__ offsets,
                                               int* __restrict__ bsum) {
  __shared__ int buf[256];
  int tid = threadIdx.x;
  int idx = blockIdx.x * 256 + tid;
  int v = (idx < N_NODES) ? deg[idx] : 0;
  buf[tid] = v;
  __syncthreads();
  for (int off = 1; off < 256; off <<= 1) {
    int t = (tid >= off) ? buf[tid - off] : 0;
    __syncthreads();
    buf[tid] += t;
    __syncthreads();
  }
  if (idx < N_NODES) offsets[idx] = buf[tid] - v;
  if (tid == 255) bsum[blockIdx.x] = buf[255];
}

__global__ __launch_bounds__(512) void scan2_k(int* __restrict__ bsum, int nb) {
  __shared__ int buf[512];
  int tid = threadIdx.x;
  int v = (tid < nb) ? bsum[tid] : 0;
  buf[tid] = v;
  __syncthreads();
  for (int off = 1; off < 512; off <<= 1) {
    int t = (tid >= off) ? buf[tid - off] : 0;
    __syncthreads();
    buf[tid] += t;
    __syncthreads();
  }
  if (tid < nb) bsum[tid] = buf[tid] - v;
}

__global__ __launch_bounds__(256) void scan3_k(int* __restrict__ offsets,
                                               const int* __restrict__ bsum) {
  int idx = blockIdx.x * 256 + threadIdx.x;
  if (idx < N_NODES) offsets[idx] += bsum[idx >> 8];
  if (idx == 0) offsets[N_NODES] = N_EDGES;
}

__global__ __launch_bounds__(256) void copy_int_k(const int* __restrict__ a,
                                                  int* __restrict__ b, int n) {
  int i = blockIdx.x * 256 + threadIdx.x;
  if (i < n) b[i] = a[i];
}

__global__ __launch_bounds__(256) void fill_k(const int* __restrict__ src,
                                              const int* __restrict__ dst,
                                              int* __restrict__ cursor,
                                              int* __restrict__ srcs_sorted) {
  int e = blockIdx.x * 256 + threadIdx.x;
  if (e >= N_EDGES) return;
  int pos = atomicAdd(&cursor[dst[e]], 1);
  srcs_sorted[pos] = src[e];
}

// ---------------------------------------------------------------------------
// gather: 2 edges/iter per wave (lanes split 32/32, 8B loads), shfl combine
// ---------------------------------------------------------------------------
__global__ __launch_bounds__(256) void gather_b_k(
    const unsigned short* __restrict__ xb, const int* __restrict__ offsets,
    const int* __restrict__ srcs, unsigned short* __restrict__ out) {
  int node = (blockIdx.x * 256 + threadIdx.x) >> 6;
  int lane = threadIdx.x & 63;
  if (node >= N_NODES) return;
  int beg = offsets[node], end = offsets[node + 1];
  int half = lane >> 5;
  int cg = (lane & 31) * 4;
  float a0 = 0.f, a1 = 0.f, a2 = 0.f, a3 = 0.f;
  for (int e = beg + half; e < end; e += 2) {
    int s = srcs[e];
    uint2 v = *reinterpret_cast<const uint2*>(xb + (size_t)s * 128 + cg);
    a0 += bf2f((unsigned short)(v.x & 0xFFFFu));
    a1 += bf2f((unsigned short)(v.x >> 16));
    a2 += bf2f((unsigned short)(v.y & 0xFFFFu));
    a3 += bf2f((unsigned short)(v.y >> 16));
  }
  a0 += __shfl_down(a0, 32);
  a1 += __shfl_down(a1, 32);
  a2 += __shfl_down(a2, 32);
  a3 += __shfl_down(a3, 32);
  if (half == 0) {
    uint2 o;
    o.x = (unsigned)f2bf(a0) | ((unsigned)f2bf(a1) << 16);
    o.y = (unsigned)f2bf(a2) | ((unsigned)f2bf(a3) << 16);
    *reinterpret_cast<uint2*>(out + (size_t)node * 128 + cg) = o;
  }
}

// lineout = hidden @ line_w^T + line_b
__global__ __launch_bounds__(256) void lineout_k(
    const float* __restrict__ hidden, const float* __restrict__ W,
    const float* __restrict__ b, float* __restrict__ out) {
  __shared__ float Ws[16 * 128];
  for (int i = threadIdx.x; i < 2048; i += 256) Ws[i] = W[i];
  __syncthreads();
  int r = threadIdx.x >> 4, c = threadIdx.x & 15;
  int n = blockIdx.x * 16 + r;
  if (n >= N_NODES) return;
  const float* h = hidden + (size_t)n * 128;
  const float* w = Ws + c * 128;
  float acc = 0.f;
#pragma unroll 8
  for (int k = 0; k < 128; k++) acc += h[k] * w[k];
  out[(size_t)n * 16 + c] = acc + b[c];
}

// gate[n] = hidden[n] . gate_w + gate_b
__global__ __launch_bounds__(256) void gate_k(
    const float* __restrict__ hidden, const float* __restrict__ gw,
    const float* __restrict__ gb, float* __restrict__ gate) {
  int wid = (blockIdx.x * 256 + threadIdx.x) >> 6;
  int lane = threadIdx.x & 63;
  if (wid >= N_NODES) return;
  const float* h = hidden + (size_t)wid * 128;
  float s = h[lane] * gw[lane] + h[64 + lane] * gw[64 + lane];
#pragma unroll
  for (int off = 32; off; off >>= 1) s += __shfl_down(s, off);
  if (lane == 0) gate[wid] = s + gb[0];
}

// gs[g] = lower_bound(batch, g)
__global__ void graph_start_k(const int* __restrict__ batch, int* __restrict__ gs) {
  int g = threadIdx.x;
  if (g > 512) return;
  if (g == 512) {
    gs[512] = N_NODES;
    return;
  }
  int lo = 0, hi = N_NODES;
  while (lo < hi) {
    int mid = (lo + hi) >> 1;
    if (batch[mid] < g) lo = mid + 1;
    else hi = mid;
  }
  gs[g] = lo;
}

// ---------------------------------------------------------------------------
// Per-graph attention pool (batch sorted, no atomics)
// ---------------------------------------------------------------------------
__global__ __launch_bounds__(256) void pool_fused_k(
    const float* __restrict__ hidden, const float* __restrict__ gate,
    const int* __restrict__ gs, float* __restrict__ ex,
    float* __restrict__ pooled) {
  const int g = blockIdx.x;
  const int beg = gs[g], end = gs[g + 1];
  const int tid = threadIdx.x, lane = tid & 63, wv = tid >> 6;
  __shared__ float red[4];
  __shared__ float sval;
  __shared__ float colbuf[256];

  if (end <= beg) {
    if (tid < 128) pooled[(size_t)g * 128 + tid] = 0.f;
    return;
  }
  float m = -3.4e38f;
  for (int n = beg + tid; n < end; n += 256) m = fmaxf(m, gate[n]);
#pragma unroll
  for (int off = 32; off; off >>= 1) m = fmaxf(m, __shfl_down(m, off));
  if (lane == 0) red[wv] = m;
  __syncthreads();
  if (tid == 0) sval = fmaxf(fmaxf(red[0], red[1]), fmaxf(red[2], red[3]));
  __syncthreads();
  const float mx = sval;
  float s = 0.f;
  for (int n = beg + tid; n < end; n += 256) {
    float e = __expf(gate[n] - mx);
    ex[n] = e;
    s += e;
  }
#pragma unroll
  for (int off = 32; off; off >>= 1) s += __shfl_down(s, off);
  if (lane == 0) red[wv] = s;
  __syncthreads();
  if (tid == 0) sval = red[0] + red[1] + red[2] + red[3];
  __syncthreads();
  const float denom = sval;
  const int col = tid & 127, half = tid >> 7;
  float acc = 0.f;
  for (int n = beg + half; n < end; n += 2)
    acc += ex[n] * hidden[(size_t)n * 128 + col];
  colbuf[tid] = acc;
  __syncthreads();
  if (tid < 128)
    pooled[(size_t)g * 128 + tid] = (colbuf[tid] + colbuf[tid + 128]) / denom;
}

__global__ void mlp1_k(const float* __restrict__ pooled, const float* __restrict__ w,
                       const float* __restrict__ b, float* __restrict__ h1) {
  int g = blockIdx.x, j = threadIdx.x;
  const float* p = pooled + (size_t)g * 128;
  const float* wr = w + (size_t)j * 128;
  float acc = 0.f;
#pragma unroll 8
  for (int k = 0; k < 128; k++) acc += p[k] * wr[k];
  acc += b[j];
  h1[g * 64 + j] = acc > 0.f ? acc : 0.f;
}

__global__ void mlp2_k(const float* __restrict__ h1, const float* __restrict__ w,
                       const float* __restrict__ b, float* __restrict__ h2) {
  int g = blockIdx.x, j = threadIdx.x;
  const float* p = h1 + (size_t)g * 64;
  const float* wr = w + (size_t)j * 64;
  float acc = 0.f;
#pragma unroll 8
  for (int k = 0; k < 64; k++) acc += p[k] * wr[k];
  acc += b[j];
  h2[g * 64 + j] = acc > 0.f ? acc : 0.f;
}

__global__ void outhead_k(const float* __restrict__ h2, const float* __restrict__ w,
                          const float* __restrict__ b, float* __restrict__ out) {
  int g = blockIdx.x, j = threadIdx.x;
  if (j >= 16) return;
  const float* p = h2 + (size_t)g * 64;
  const float* wr = w + (size_t)j * 64;
  float acc = 0.f;
#pragma unroll 8
  for (int k = 0; k < 64; k++) acc += p[k] * wr[k];
  out[g * 16 + j] = acc + b[j];
}

extern "C" void kernel_launch(void* const* d_in, const int* in_sizes, int n_in,
                              void* d_out, int out_size, void* d_ws, size_t ws_size,
                              hipStream_t stream) {
  const float* node_embed = (const float*)d_in[0];
  const int* eidx = (const int*)d_in[1];
  const int* batch = (const int*)d_in[2];
  const float* node_w = (const float*)d_in[3];
  const float* node_b = (const float*)d_in[4];
  const float* ggc_w = (const float*)d_in[5];
  const float* w_ih = (const float*)d_in[6];
  const float* w_hh = (const float*)d_in[7];
  const float* b_ih = (const float*)d_in[8];
  const float* b_hh = (const float*)d_in[9];
  const float* cat_w = (const float*)d_in[10];
  const float* cat_b = (const float*)d_in[11];
  const float* gate_w = (const float*)d_in[12];
  const float* gate_b = (const float*)d_in[13];
  const float* mlp_w1 = (const float*)d_in[14];
  const float* mlp_b1 = (const float*)d_in[15];
  const float* mlp_w2 = (const float*)d_in[16];
  const float* mlp_b2 = (const float*)d_in[17];
  const float* out_w = (const float*)d_in[18];
  const float* out_b = (const float*)d_in[19];
  const float* line_w = (const float*)d_in[20];
  const float* line_b = (const float*)d_in[21];

  const int* src = eidx;
  const int* dst = eidx + N_EDGES;

  // workspace (same proven extent as round 5/6)
  float* ws = (float*)d_ws;
  float* h0 = ws;                                   // [NH] f32 (feeds f2b only)
  float* hidden = h0 + (size_t)NH;                  // [NH] f32
  float* xfS = hidden + (size_t)NH;                 // [NH] f32 (WcT staging only)
  unsigned short* h0b = (unsigned short*)(xfS + (size_t)NH);  // [NH] bf16
  unsigned short* xbA = h0b + (size_t)NH;           // [NH] bf16
  unsigned short* xbB = xbA + (size_t)NH;           // [NH] bf16 (also outs)
  unsigned short* aggb = xbB + (size_t)NH;          // [NH] bf16
  unsigned short* wctb = aggb + (size_t)NH;         // 16*384*128 bf16
  unsigned short* whhb = wctb + 16 * 384 * 128;     // 4*384*128 bf16
  unsigned short* wcatb = whhb + 4 * 384 * 128;     // 128*512 bf16
  int* offsets = (int*)(wcatb + 128 * 512);         // [N+1]
  int* cursor = offsets + N_NODES + 1;              // [N]
  int* srcs_sorted = cursor + N_NODES;              // [E]
  int* bsum = srcs_sorted + N_EDGES;                // [512]
  int* gs = bsum + 512;                             // [513]
  float* WcTf = xfS;                                // fp32 staging overlay (pre-loop)

  float* out_graph = (float*)d_out;
  float* out_line = (float*)d_out + 512 * 16;

  dim3 blk(256);
  const int gM128 = (N_NODES + 127) / 128;
  const int gM64 = (N_NODES + 63) / 64;
  const int gE = (N_EDGES + 255) / 256;
  const int nScanBlk = (N_NODES + 255) / 256;
  const int nRowTiles = (N_NODES + 15) / 16;  // 6250

  // ---- CSR build ----
  hipMemsetAsync(cursor, 0, N_NODES * sizeof(int), stream);
  deg_hist_k<<<gE, blk, 0, stream>>>(dst, cursor);
  scan1_k<<<nScanBlk, blk, 0, stream>>>(cursor, offsets, bsum);
  scan2_k<<<1, 512, 0, stream>>>(bsum, nScanBlk);
  scan3_k<<<nScanBlk, blk, 0, stream>>>(offsets, bsum);
  copy_int_k<<<(N_NODES + 255) / 256, blk, 0, stream>>>(offsets, cursor, N_NODES);
  fill_k<<<gE, blk, 0, stream>>>(src, dst, cursor, srcs_sorted);
  graph_start_k<<<1, 576, 0, stream>>>(batch, gs);

  // ---- weights: WcT fold (fp32) -> bf16; w_hh, cat_w -> bf16 ----
  gemm_wct_k<<<dim3(3, 2, 16), blk, 0, stream>>>(w_ih, ggc_w, WcTf);
  f2b_k<<<(16 * 384 * 128 / 4 + 255) / 256, blk, 0, stream>>>(WcTf, wctb, 16 * 384 * 128);
  f2b_k<<<(4 * 384 * 128 / 4 + 255) / 256, blk, 0, stream>>>(w_hh, whhb, 4 * 384 * 128);
  f2b_k<<<(128 * 512 / 4 + 255) / 256, blk, 0, stream>>>(cat_w, wcatb, 128 * 512);

  // ---- h0 = node_embed @ node_w^T + node_b; bf16 mirror ----
  gemm_k128<true, false, true, false><<<dim3(gM128, 2), blk, 0, stream>>>(
      node_embed, nullptr, node_w, node_b, h0, N_NODES, 128, 128);
  f2b_k<<<(NH / 4 + 255) / 256, blk, 0, stream>>>(h0, h0b, NH);

  const dim3 gruGrid(200, 8);
  const int gGather = (N_NODES * 64 + 255) / 256;
  for (int k = 0; k < 4; k++) {
    const unsigned short* wct_k = wctb + (size_t)(k * 4) * 384 * 128;
    const unsigned short* whh_k = whhb + (size_t)k * 384 * 128;
    const float* bih_k = b_ih + k * 384;
    const float* bhh_k = b_hh + k * 384;
    // i=0: h0b -> xbA
    gather_b_k<<<gGather, blk, 0, stream>>>(h0b, offsets, srcs_sorted, aggb);
    gru_mfma3_k<false><<<gruGrid, blk, 0, stream>>>(
        aggb, h0b, h0b, wct_k, whh_k, bih_k, bhh_k, xbA, N_NODES, nRowTiles);
    // i=1: xbA -> xbB
    gather_b_k<<<gGather, blk, 0, stream>>>(xbA, offsets, srcs_sorted, aggb);
    gru_mfma3_k<false><<<gruGrid, blk, 0, stream>>>(
        aggb, xbA, h0b, wct_k + (size_t)384 * 128, whh_k, bih_k, bhh_k, xbB, N_NODES, nRowTiles);
    // i=2: xbB -> xbA
    gather_b_k<<<gGather, blk, 0, stream>>>(xbB, offsets, srcs_sorted, aggb);
    gru_mfma3_k<false><<<gruGrid, blk, 0, stream>>>(
        aggb, xbB, h0b, wct_k + (size_t)2 * 384 * 128, whh_k, bih_k, bhh_k, xbA, N_NODES, nRowTiles);
    // i=3 (LAST): xbA -> outs (=xbB) = bf16(x_new + h0)
    gather_b_k<<<gGather, blk, 0, stream>>>(xbA, offsets, srcs_sorted, aggb);
    gru_mfma3_k<true><<<gruGrid, blk, 0, stream>>>(
        aggb, xbA, h0b, wct_k + (size_t)3 * 384 * 128, whh_k, bih_k, bhh_k, xbB, N_NODES, nRowTiles);
    // hidden (+)= outs @ cat_w[:, k*128:(k+1)*128]^T  (+cat_b at k==0)
    cat_mfma_k<<<dim3(gM64, 4), blk, 0, stream>>>(xbB, wcatb, cat_b, hidden, N_NODES, k);
  }

  // ---- heads ----
  lineout_k<<<(N_NODES + 15) / 16, blk, 0, stream>>>(hidden, line_w, line_b, out_line);

  float* gate = (float*)xbA;
  float* ex = (float*)xbB;
  float* pooled = (float*)aggb;
  float* h1 = pooled + 512 * 128;
  float* h2 = h1 + 512 * 64;

  gate_k<<<(N_NODES * 64 + 255) / 256, blk, 0, stream>>>(hidden, gate_w, gate_b, gate);
  pool_fused_k<<<512, blk, 0, stream>>>(hidden, gate, gs, ex, pooled);
  mlp1_k<<<512, 64, 0, stream>>>(pooled, mlp_w1, mlp_b1, h1);
  mlp2_k<<<512, 64, 0, stream>>>(h1, mlp_w2, mlp_b2, h2);
  outhead_k<<<512, 64, 0, stream>>>(h2, out_w, out_b, out_graph);
}

// Round 8
// 2844.944 us; speedup vs baseline: 21.3809x; 1.1991x over previous
//
#include <hip/hip_runtime.h>

#define N_NODES 100000
#define N_EDGES 1600000
#define HD 128
#define NH (N_NODES * HD)

typedef __attribute__((ext_vector_type(8))) short bf16x8;
typedef __attribute__((ext_vector_type(4))) float f32x4;

__device__ inline unsigned short f2bf(float f) {
  unsigned u = __float_as_uint(f);
  unsigned r = (u + 0x7FFFu + ((u >> 16) & 1u)) >> 16;
  return (unsigned short)r;
}
__device__ inline float bf2f(unsigned short b) {
  return __uint_as_float(((unsigned)b) << 16);
}
__device__ inline float sigm_f(float x) {
  return __builtin_amdgcn_rcpf(1.f + __expf(-x));
}
__device__ inline float tanh_f(float x) {
  return 1.f - 2.f * __builtin_amdgcn_rcpf(__expf(2.f * x) + 1.f);
}

// ---------------------------------------------------------------------------
// h0 GEMM: h0b = bf16(node_embed @ node_w^T + node_b)  (fp32 in, bf16 out)
// ---------------------------------------------------------------------------
__global__ __launch_bounds__(256) void gemm_h0_k(
    const float* __restrict__ A, const float* __restrict__ B,
    const float* __restrict__ bias, unsigned short* __restrict__ Cb, int M) {
  __shared__ float As[16][132];
  __shared__ float Bs[16][68];
  const int tid = threadIdx.x;
  const int row0 = blockIdx.x * 128;
  const int col0 = blockIdx.y * 64;
  const int tx = tid & 15, ty = tid >> 4;

  float acc[8][4];
#pragma unroll
  for (int i = 0; i < 8; i++)
#pragma unroll
    for (int j = 0; j < 4; j++) acc[i][j] = 0.f;

  const int lr = tid >> 2;
  const int kg = (tid & 3) * 4;

  for (int k0 = 0; k0 < 128; k0 += 16) {
#pragma unroll
    for (int h = 0; h < 2; ++h) {
      int r = lr + h * 64;
      float4 v = make_float4(0.f, 0.f, 0.f, 0.f);
      if (row0 + r < M)
        v = *reinterpret_cast<const float4*>(A + (size_t)(row0 + r) * 128 + k0 + kg);
      As[kg + 0][r] = v.x;
      As[kg + 1][r] = v.y;
      As[kg + 2][r] = v.z;
      As[kg + 3][r] = v.w;
    }
    {
      int c = lr;
      float4 v = *reinterpret_cast<const float4*>(B + (size_t)(col0 + c) * 128 + k0 + kg);
      Bs[kg + 0][c] = v.x;
      Bs[kg + 1][c] = v.y;
      Bs[kg + 2][c] = v.z;
      Bs[kg + 3][c] = v.w;
    }
    __syncthreads();
#pragma unroll
    for (int kk = 0; kk < 16; ++kk) {
      float a[8], b[4];
#pragma unroll
      for (int i = 0; i < 8; i++) a[i] = As[kk][ty * 8 + i];
#pragma unroll
      for (int j = 0; j < 4; j++) b[j] = Bs[kk][tx * 4 + j];
#pragma unroll
      for (int i = 0; i < 8; i++)
#pragma unroll
        for (int j = 0; j < 4; j++) acc[i][j] += a[i] * b[j];
    }
    __syncthreads();
  }

#pragma unroll
  for (int i = 0; i < 8; i++) {
    int r = row0 + ty * 8 + i;
    if (r < M) {
#pragma unroll
      for (int j = 0; j < 4; j++) {
        int c = col0 + tx * 4 + j;
        Cb[(size_t)r * 128 + c] = f2bf(acc[i][j] + bias[c]);
      }
    }
  }
}

// ---------------------------------------------------------------------------
// Batched WcT fold: C[z] = w_ih[z>>2] @ ggc_w[z]^T   ([384,128] each, z=0..15)
// ---------------------------------------------------------------------------
__global__ __launch_bounds__(256) void gemm_wct_k(
    const float* __restrict__ w_ih, const float* __restrict__ ggc_w,
    float* __restrict__ Cout) {
  const int z = blockIdx.z;
  const float* A = w_ih + (size_t)(z >> 2) * 384 * 128;
  const float* B = ggc_w + (size_t)z * 128 * 128;
  float* C = Cout + (size_t)z * 384 * 128;
  __shared__ float As[16][132];
  __shared__ float Bs[16][68];
  const int tid = threadIdx.x;
  const int row0 = blockIdx.x * 128;
  const int col0 = blockIdx.y * 64;
  const int tx = tid & 15, ty = tid >> 4;

  float acc[8][4];
#pragma unroll
  for (int i = 0; i < 8; i++)
#pragma unroll
    for (int j = 0; j < 4; j++) acc[i][j] = 0.f;

  const int lr = tid >> 2;
  const int kg = (tid & 3) * 4;

  for (int k0 = 0; k0 < 128; k0 += 16) {
#pragma unroll
    for (int h = 0; h < 2; ++h) {
      int r = lr + h * 64;
      float4 v = *reinterpret_cast<const float4*>(A + (size_t)(row0 + r) * 128 + k0 + kg);
      As[kg + 0][r] = v.x;
      As[kg + 1][r] = v.y;
      As[kg + 2][r] = v.z;
      As[kg + 3][r] = v.w;
    }
    {
      int c = lr;
      float4 v = *reinterpret_cast<const float4*>(B + (size_t)(col0 + c) * 128 + k0 + kg);
      Bs[kg + 0][c] = v.x;
      Bs[kg + 1][c] = v.y;
      Bs[kg + 2][c] = v.z;
      Bs[kg + 3][c] = v.w;
    }
    __syncthreads();
#pragma unroll
    for (int kk = 0; kk < 16; ++kk) {
      float a[8], b[4];
#pragma unroll
      for (int i = 0; i < 8; i++) a[i] = As[kk][ty * 8 + i];
#pragma unroll
      for (int j = 0; j < 4; j++) b[j] = Bs[kk][tx * 4 + j];
#pragma unroll
      for (int i = 0; i < 8; i++)
#pragma unroll
        for (int j = 0; j < 4; j++) acc[i][j] += a[i] * b[j];
    }
    __syncthreads();
  }

#pragma unroll
  for (int i = 0; i < 8; i++) {
    int r = row0 + ty * 8 + i;
#pragma unroll
    for (int j = 0; j < 4; j++) {
      int c = col0 + tx * 4 + j;
      C[(size_t)r * 128 + c] = acc[i][j];
    }
  }
}

// ---------------------------------------------------------------------------
// float -> bf16, 4 elems/thread
// ---------------------------------------------------------------------------
__global__ __launch_bounds__(256) void f2b_k(const float* __restrict__ a,
                                             unsigned short* __restrict__ b, int n) {
  int i = blockIdx.x * 256 + threadIdx.x;
  if (i * 4 >= n) return;
  float4 v = reinterpret_cast<const float4*>(a)[i];
  ushort4 o;
  o.x = f2bf(v.x);
  o.y = f2bf(v.y);
  o.z = f2bf(v.z);
  o.w = f2bf(v.w);
  reinterpret_cast<ushort4*>(b)[i] = o;
}

// ---------------------------------------------------------------------------
// GRU v4: 2-way block-batched (grid.z selects chain). bf16 state, 24 weight
// fragments persistent in VGPR, grid-stride over 16-row tiles.
//   LAST=0: out = bf16(x_new); LAST=1: out = bf16(x_new + h0b)
// ---------------------------------------------------------------------------
template <bool LAST>
__global__ __launch_bounds__(256) void gru_mfma4_k(
    const unsigned short* __restrict__ aggb,  // [2][NH]
    const unsigned short* __restrict__ xb_base, size_t xstride,
    const unsigned short* __restrict__ h0b,
    const unsigned short* __restrict__ wct_base, size_t wct_zs,
    const unsigned short* __restrict__ whh_base, size_t whh_zs,
    const float* __restrict__ bih_base, const float* __restrict__ bhh_base,
    unsigned short* __restrict__ xbout,       // [2][NH]
    int M, int nRowTiles) {
  const int z = blockIdx.z;
  const unsigned short* agg = aggb + (size_t)z * NH;
  const unsigned short* xb = xb_base + (size_t)z * xstride;
  unsigned short* out = xbout + (size_t)z * NH;
  const unsigned short* wctb = wct_base + (size_t)z * wct_zs;
  const unsigned short* whhb = whh_base + (size_t)z * whh_zs;
  const float* b_ih = bih_base + z * 384;
  const float* b_hh = bhh_base + z * 384;

  const int lane = threadIdx.x & 63;
  const int wave = threadIdx.x >> 6;
  const int lrow = lane & 15;
  const int kblk = lane >> 4;  // 0..3
  const int c = blockIdx.y * 16 + lrow;

  bf16x8 wf[6][4];
#pragma unroll
  for (int s = 0; s < 3; s++)
#pragma unroll
    for (int kk = 0; kk < 4; kk++) {
      size_t off = (size_t)(s * 128 + c) * 128 + kk * 32 + kblk * 8;
      wf[s][kk] = *reinterpret_cast<const bf16x8*>(wctb + off);
      wf[s + 3][kk] = *reinterpret_cast<const bf16x8*>(whhb + off);
    }
  const float bi0 = b_ih[c], bi1 = b_ih[128 + c], bi2 = b_ih[256 + c];
  const float bh0 = b_hh[c], bh1 = b_hh[128 + c], bh2 = b_hh[256 + c];

  const int tstride = gridDim.x * 4;
  for (int rt = blockIdx.x * 4 + wave; rt < nRowTiles; rt += tstride) {
    const int row0 = rt * 16;
    int arow = row0 + lrow;
    if (arow >= M) arow = M - 1;
    const size_t abase = (size_t)arow * 128 + kblk * 8;

    f32x4 acc[6];
#pragma unroll
    for (int s = 0; s < 6; s++) acc[s] = (f32x4)(0.f);
#pragma unroll
    for (int kk = 0; kk < 4; kk++) {
      bf16x8 a_ag = *reinterpret_cast<const bf16x8*>(agg + abase + kk * 32);
      bf16x8 a_x = *reinterpret_cast<const bf16x8*>(xb + abase + kk * 32);
      acc[0] = __builtin_amdgcn_mfma_f32_16x16x32_bf16(a_ag, wf[0][kk], acc[0], 0, 0, 0);
      acc[1] = __builtin_amdgcn_mfma_f32_16x16x32_bf16(a_ag, wf[1][kk], acc[1], 0, 0, 0);
      acc[2] = __builtin_amdgcn_mfma_f32_16x16x32_bf16(a_ag, wf[2][kk], acc[2], 0, 0, 0);
      acc[3] = __builtin_amdgcn_mfma_f32_16x16x32_bf16(a_x, wf[3][kk], acc[3], 0, 0, 0);
      acc[4] = __builtin_amdgcn_mfma_f32_16x16x32_bf16(a_x, wf[4][kk], acc[4], 0, 0, 0);
      acc[5] = __builtin_amdgcn_mfma_f32_16x16x32_bf16(a_x, wf[5][kk], acc[5], 0, 0, 0);
    }
#pragma unroll
    for (int r = 0; r < 4; r++) {
      int orow = row0 + kblk * 4 + r;
      if (orow >= M) continue;
      size_t idx = (size_t)orow * 128 + c;
      float ir = acc[0][r] + bi0;
      float iz = acc[1][r] + bi1;
      float in_ = acc[2][r] + bi2;
      float hr = acc[3][r] + bh0;
      float hz = acc[4][r] + bh1;
      float hn = acc[5][r] + bh2;
      float rg = sigm_f(ir + hr);
      float zg = sigm_f(iz + hz);
      float ng = tanh_f(in_ + rg * hn);
      float h = bf2f(xb[idx]);
      float nv = (1.f - zg) * ng + zg * h;
      if (LAST) nv += bf2f(h0b[idx]);
      out[idx] = f2bf(nv);
    }
  }
}

// ---------------------------------------------------------------------------
// cat pair: hidden (+)= [outs_z0 | outs_z1] @ cat_w[:, p*256:(p+1)*256]^T
// (+cat_b at pair==0).  K=256 across the two outs buffers.
// ---------------------------------------------------------------------------
__global__ __launch_bounds__(256) void cat_mfma2_k(
    const unsigned short* __restrict__ outs,   // [2][NH]
    const unsigned short* __restrict__ wcatb,  // [128][512]
    const float* __restrict__ cat_b, float* __restrict__ hidden, int M, int pair) {
  const int lane = threadIdx.x & 63;
  const int wave = threadIdx.x >> 6;
  const int row0 = blockIdx.x * 64 + wave * 16;
  const int c0 = blockIdx.y * 32;
  const int lrow = lane & 15;
  const int kb = lane >> 4;
  int arow = row0 + lrow;
  if (arow >= M) arow = M - 1;

  f32x4 acc[2];
  acc[0] = (f32x4)(0.f);
  acc[1] = (f32x4)(0.f);
#pragma unroll
  for (int kk = 0; kk < 8; kk++) {
    const unsigned short* ob = outs + (size_t)(kk >> 2) * NH;
    bf16x8 a = *reinterpret_cast<const bf16x8*>(
        ob + (size_t)arow * 128 + (kk & 3) * 32 + kb * 8);
#pragma unroll
    for (int t = 0; t < 2; t++) {
      bf16x8 b = *reinterpret_cast<const bf16x8*>(
          wcatb + (size_t)(c0 + t * 16 + lrow) * 512 + pair * 256 + (kk >> 2) * 128 +
          (kk & 3) * 32 + kb * 8);
      acc[t] = __builtin_amdgcn_mfma_f32_16x16x32_bf16(a, b, acc[t], 0, 0, 0);
    }
  }
#pragma unroll
  for (int r = 0; r < 4; r++) {
    int orow = row0 + kb * 4 + r;
    if (orow >= M) continue;
#pragma unroll
    for (int t = 0; t < 2; t++) {
      int c = c0 + t * 16 + lrow;
      size_t idx = (size_t)orow * 128 + c;
      float v = acc[t][r];
      v += (pair == 0) ? cat_b[c] : hidden[idx];
      hidden[idx] = v;
    }
  }
}

// ---------------------------------------------------------------------------
// CSR build
// ---------------------------------------------------------------------------
__global__ __launch_bounds__(256) void deg_hist_k(const int* __restrict__ dst,
                                                  int* __restrict__ deg) {
  int e = blockIdx.x * 256 + threadIdx.x;
  if (e >= N_EDGES) return;
  atomicAdd(&deg[dst[e]], 1);
}

__global__ __launch_bounds__(256) void scan1_k(const int* __restrict__ deg,
                                               int* __restrict__ offsets,
                                               int* __restrict__ bsum) {
  __shared__ int buf[256];
  int tid = threadIdx.x;
  int idx = blockIdx.x * 256 + tid;
  int v = (idx < N_NODES) ? deg[idx] : 0;
  buf[tid] = v;
  __syncthreads();
  for (int off = 1; off < 256; off <<= 1) {
    int t = (tid >= off) ? buf[tid - off] : 0;
    __syncthreads();
    buf[tid] += t;
    __syncthreads();
  }
  if (idx < N_NODES) offsets[idx] = buf[tid] - v;
  if (tid == 255) bsum[blockIdx.x] = buf[255];
}

__global__ __launch_bounds__(512) void scan2_k(int* __restrict__ bsum, int nb) {
  __shared__ int buf[512];
  int tid = threadIdx.x;
  int v = (tid < nb) ? bsum[tid] : 0;
  buf[tid] = v;
  __syncthreads();
  for (int off = 1; off < 512; off <<= 1) {
    int t = (tid >= off) ? buf[tid - off] : 0;
    __syncthreads();
    buf[tid] += t;
    __syncthreads();
  }
  if (tid < nb) bsum[tid] = buf[tid] - v;
}

__global__ __launch_bounds__(256) void scan3_k(int* __restrict__ offsets,
                                               const int* __restrict__ bsum) {
  int idx = blockIdx.x * 256 + threadIdx.x;
  if (idx < N_NODES) offsets[idx] += bsum[idx >> 8];
  if (idx == 0) offsets[N_NODES] = N_EDGES;
}

__global__ __launch_bounds__(256) void copy_int_k(const int* __restrict__ a,
                                                  int* __restrict__ b, int n) {
  int i = blockIdx.x * 256 + threadIdx.x;
  if (i < n) b[i] = a[i];
}

__global__ __launch_bounds__(256) void fill_k(const int* __restrict__ src,
                                              const int* __restrict__ dst,
                                              int* __restrict__ cursor,
                                              int* __restrict__ srcs_sorted) {
  int e = blockIdx.x * 256 + threadIdx.x;
  if (e >= N_EDGES) return;
  int pos = atomicAdd(&cursor[dst[e]], 1);
  srcs_sorted[pos] = src[e];
}

// ---------------------------------------------------------------------------
// gather, 2-way batched + 2-deep pipelined: wave -> (z, node); lanes split
// 32/32 over even/odd edges; 2 independent row loads in flight per half.
// ---------------------------------------------------------------------------
__global__ __launch_bounds__(256) void gather4_k(
    const unsigned short* __restrict__ xb_base, size_t xstride,
    const int* __restrict__ offsets, const int* __restrict__ srcs,
    unsigned short* __restrict__ aggb) {
  int wid = (blockIdx.x * 256 + threadIdx.x) >> 6;
  int lane = threadIdx.x & 63;
  if (wid >= 2 * N_NODES) return;
  int z = (wid >= N_NODES) ? 1 : 0;
  int node = wid - z * N_NODES;
  const unsigned short* xb = xb_base + (size_t)z * xstride;
  int beg = offsets[node], end = offsets[node + 1];
  int half = lane >> 5;
  int cg = (lane & 31) * 4;
  float a0 = 0.f, a1 = 0.f, a2 = 0.f, a3 = 0.f;
  int e = beg + half;
  for (; e + 2 < end; e += 4) {
    int s0 = srcs[e], s1 = srcs[e + 2];
    uint2 v0 = *reinterpret_cast<const uint2*>(xb + (size_t)s0 * 128 + cg);
    uint2 v1 = *reinterpret_cast<const uint2*>(xb + (size_t)s1 * 128 + cg);
    a0 += bf2f((unsigned short)(v0.x & 0xFFFFu));
    a1 += bf2f((unsigned short)(v0.x >> 16));
    a2 += bf2f((unsigned short)(v0.y & 0xFFFFu));
    a3 += bf2f((unsigned short)(v0.y >> 16));
    a0 += bf2f((unsigned short)(v1.x & 0xFFFFu));
    a1 += bf2f((unsigned short)(v1.x >> 16));
    a2 += bf2f((unsigned short)(v1.y & 0xFFFFu));
    a3 += bf2f((unsigned short)(v1.y >> 16));
  }
  if (e < end) {
    int s0 = srcs[e];
    uint2 v0 = *reinterpret_cast<const uint2*>(xb + (size_t)s0 * 128 + cg);
    a0 += bf2f((unsigned short)(v0.x & 0xFFFFu));
    a1 += bf2f((unsigned short)(v0.x >> 16));
    a2 += bf2f((unsigned short)(v0.y & 0xFFFFu));
    a3 += bf2f((unsigned short)(v0.y >> 16));
  }
  a0 += __shfl_down(a0, 32);
  a1 += __shfl_down(a1, 32);
  a2 += __shfl_down(a2, 32);
  a3 += __shfl_down(a3, 32);
  if (half == 0) {
    uint2 o;
    o.x = (unsigned)f2bf(a0) | ((unsigned)f2bf(a1) << 16);
    o.y = (unsigned)f2bf(a2) | ((unsigned)f2bf(a3) << 16);
    *reinterpret_cast<uint2*>(aggb + (size_t)z * NH + (size_t)node * 128 + cg) = o;
  }
}

// lineout = hidden @ line_w^T + line_b
__global__ __launch_bounds__(256) void lineout_k(
    const float* __restrict__ hidden, const float* __restrict__ W,
    const float* __restrict__ b, float* __restrict__ out) {
  __shared__ float Ws[16 * 128];
  for (int i = threadIdx.x; i < 2048; i += 256) Ws[i] = W[i];
  __syncthreads();
  int r = threadIdx.x >> 4, c = threadIdx.x & 15;
  int n = blockIdx.x * 16 + r;
  if (n >= N_NODES) return;
  const float* h = hidden + (size_t)n * 128;
  const float* w = Ws + c * 128;
  float acc = 0.f;
#pragma unroll 8
  for (int k = 0; k < 128; k++) acc += h[k] * w[k];
  out[(size_t)n * 16 + c] = acc + b[c];
}

// gate[n] = hidden[n] . gate_w + gate_b
__global__ __launch_bounds__(256) void gate_k(
    const float* __restrict__ hidden, const float* __restrict__ gw,
    const float* __restrict__ gb, float* __restrict__ gate) {
  int wid = (blockIdx.x * 256 + threadIdx.x) >> 6;
  int lane = threadIdx.x & 63;
  if (wid >= N_NODES) return;
  const float* h = hidden + (size_t)wid * 128;
  float s = h[lane] * gw[lane] + h[64 + lane] * gw[64 + lane];
#pragma unroll
  for (int off = 32; off; off >>= 1) s += __shfl_down(s, off);
  if (lane == 0) gate[wid] = s + gb[0];
}

// gs[g] = lower_bound(batch, g)
__global__ void graph_start_k(const int* __restrict__ batch, int* __restrict__ gs) {
  int g = threadIdx.x;
  if (g > 512) return;
  if (g == 512) {
    gs[512] = N_NODES;
    return;
  }
  int lo = 0, hi = N_NODES;
  while (lo < hi) {
    int mid = (lo + hi) >> 1;
    if (batch[mid] < g) lo = mid + 1;
    else hi = mid;
  }
  gs[g] = lo;
}

// ---------------------------------------------------------------------------
// Per-graph attention pool (batch sorted, no atomics)
// ---------------------------------------------------------------------------
__global__ __launch_bounds__(256) void pool_fused_k(
    const float* __restrict__ hidden, const float* __restrict__ gate,
    const int* __restrict__ gs, float* __restrict__ ex,
    float* __restrict__ pooled) {
  const int g = blockIdx.x;
  const int beg = gs[g], end = gs[g + 1];
  const int tid = threadIdx.x, lane = tid & 63, wv = tid >> 6;
  __shared__ float red[4];
  __shared__ float sval;
  __shared__ float colbuf[256];

  if (end <= beg) {
    if (tid < 128) pooled[(size_t)g * 128 + tid] = 0.f;
    return;
  }
  float m = -3.4e38f;
  for (int n = beg + tid; n < end; n += 256) m = fmaxf(m, gate[n]);
#pragma unroll
  for (int off = 32; off; off >>= 1) m = fmaxf(m, __shfl_down(m, off));
  if (lane == 0) red[wv] = m;
  __syncthreads();
  if (tid == 0) sval = fmaxf(fmaxf(red[0], red[1]), fmaxf(red[2], red[3]));
  __syncthreads();
  const float mx = sval;
  float s = 0.f;
  for (int n = beg + tid; n < end; n += 256) {
    float e = __expf(gate[n] - mx);
    ex[n] = e;
    s += e;
  }
#pragma unroll
  for (int off = 32; off; off >>= 1) s += __shfl_down(s, off);
  if (lane == 0) red[wv] = s;
  __syncthreads();
  if (tid == 0) sval = red[0] + red[1] + red[2] + red[3];
  __syncthreads();
  const float denom = sval;
  const int col = tid & 127, half = tid >> 7;
  float acc = 0.f;
  for (int n = beg + half; n < end; n += 2)
    acc += ex[n] * hidden[(size_t)n * 128 + col];
  colbuf[tid] = acc;
  __syncthreads();
  if (tid < 128)
    pooled[(size_t)g * 128 + tid] = (colbuf[tid] + colbuf[tid + 128]) / denom;
}

__global__ void mlp1_k(const float* __restrict__ pooled, const float* __restrict__ w,
                       const float* __restrict__ b, float* __restrict__ h1) {
  int g = blockIdx.x, j = threadIdx.x;
  const float* p = pooled + (size_t)g * 128;
  const float* wr = w + (size_t)j * 128;
  float acc = 0.f;
#pragma unroll 8
  for (int k = 0; k < 128; k++) acc += p[k] * wr[k];
  acc += b[j];
  h1[g * 64 + j] = acc > 0.f ? acc : 0.f;
}

__global__ void mlp2_k(const float* __restrict__ h1, const float* __restrict__ w,
                       const float* __restrict__ b, float* __restrict__ h2) {
  int g = blockIdx.x, j = threadIdx.x;
  const float* p = h1 + (size_t)g * 64;
  const float* wr = w + (size_t)j * 64;
  float acc = 0.f;
#pragma unroll 8
  for (int k = 0; k < 64; k++) acc += p[k] * wr[k];
  acc += b[j];
  h2[g * 64 + j] = acc > 0.f ? acc : 0.f;
}

__global__ void outhead_k(const float* __restrict__ h2, const float* __restrict__ w,
                          const float* __restrict__ b, float* __restrict__ out) {
  int g = blockIdx.x, j = threadIdx.x;
  if (j >= 16) return;
  const float* p = h2 + (size_t)g * 64;
  const float* wr = w + (size_t)j * 64;
  float acc = 0.f;
#pragma unroll 8
  for (int k = 0; k < 64; k++) acc += p[k] * wr[k];
  out[g * 16 + j] = acc + b[j];
}

extern "C" void kernel_launch(void* const* d_in, const int* in_sizes, int n_in,
                              void* d_out, int out_size, void* d_ws, size_t ws_size,
                              hipStream_t stream) {
  const float* node_embed = (const float*)d_in[0];
  const int* eidx = (const int*)d_in[1];
  const int* batch = (const int*)d_in[2];
  const float* node_w = (const float*)d_in[3];
  const float* node_b = (const float*)d_in[4];
  const float* ggc_w = (const float*)d_in[5];
  const float* w_ih = (const float*)d_in[6];
  const float* w_hh = (const float*)d_in[7];
  const float* b_ih = (const float*)d_in[8];
  const float* b_hh = (const float*)d_in[9];
  const float* cat_w = (const float*)d_in[10];
  const float* cat_b = (const float*)d_in[11];
  const float* gate_w = (const float*)d_in[12];
  const float* gate_b = (const float*)d_in[13];
  const float* mlp_w1 = (const float*)d_in[14];
  const float* mlp_b1 = (const float*)d_in[15];
  const float* mlp_w2 = (const float*)d_in[16];
  const float* mlp_b2 = (const float*)d_in[17];
  const float* out_w = (const float*)d_in[18];
  const float* out_b = (const float*)d_in[19];
  const float* line_w = (const float*)d_in[20];
  const float* line_b = (const float*)d_in[21];

  const int* src = eidx;
  const int* dst = eidx + N_EDGES;

  // workspace ~254 MB:
  // hidden f32 [NH] | h0b [NH] | X0 [2NH] | X1 [2NH] | aggb [2NH] (all bf16)
  // | wctb | whhb | wcatb | CSR ints
  float* hidden = (float*)d_ws;
  unsigned short* h0b = (unsigned short*)(hidden + (size_t)NH);
  unsigned short* X0 = h0b + (size_t)NH;
  unsigned short* X1 = X0 + (size_t)2 * NH;
  unsigned short* aggb = X1 + (size_t)2 * NH;
  unsigned short* wctb = aggb + (size_t)2 * NH;     // 16*384*128
  unsigned short* whhb = wctb + 16 * 384 * 128;     // 4*384*128
  unsigned short* wcatb = whhb + 4 * 384 * 128;     // 128*512
  int* offsets = (int*)(wcatb + 128 * 512);         // [N+1]
  int* cursor = offsets + N_NODES + 1;              // [N]
  int* srcs_sorted = cursor + N_NODES;              // [E]
  int* bsum = srcs_sorted + N_EDGES;                // [512]
  int* gs = bsum + 512;                             // [513]
  float* WcTf = (float*)aggb;                       // fp32 staging overlay (pre-loop)

  float* out_graph = (float*)d_out;
  float* out_line = (float*)d_out + 512 * 16;

  dim3 blk(256);
  const int gM128 = (N_NODES + 127) / 128;
  const int gM64 = (N_NODES + 63) / 64;
  const int gE = (N_EDGES + 255) / 256;
  const int nScanBlk = (N_NODES + 255) / 256;
  const int nRowTiles = (N_NODES + 15) / 16;  // 6250 per chain
  const size_t S = (size_t)384 * 128;

  // ---- CSR build ----
  hipMemsetAsync(cursor, 0, N_NODES * sizeof(int), stream);
  deg_hist_k<<<gE, blk, 0, stream>>>(dst, cursor);
  scan1_k<<<nScanBlk, blk, 0, stream>>>(cursor, offsets, bsum);
  scan2_k<<<1, 512, 0, stream>>>(bsum, nScanBlk);
  scan3_k<<<nScanBlk, blk, 0, stream>>>(offsets, bsum);
  copy_int_k<<<(N_NODES + 255) / 256, blk, 0, stream>>>(offsets, cursor, N_NODES);
  fill_k<<<gE, blk, 0, stream>>>(src, dst, cursor, srcs_sorted);
  graph_start_k<<<1, 576, 0, stream>>>(batch, gs);

  // ---- weights: WcT fold (fp32, staged in dead aggb) -> bf16; w_hh, cat_w ----
  gemm_wct_k<<<dim3(3, 2, 16), blk, 0, stream>>>(w_ih, ggc_w, WcTf);
  f2b_k<<<(16 * 384 * 128 / 4 + 255) / 256, blk, 0, stream>>>(WcTf, wctb, 16 * 384 * 128);
  f2b_k<<<(4 * 384 * 128 / 4 + 255) / 256, blk, 0, stream>>>(w_hh, whhb, 4 * 384 * 128);
  f2b_k<<<(128 * 512 / 4 + 255) / 256, blk, 0, stream>>>(cat_w, wcatb, 128 * 512);

  // ---- h0b = bf16(node_embed @ node_w^T + node_b) ----
  gemm_h0_k<<<dim3(gM128, 2), blk, 0, stream>>>(node_embed, node_w, node_b, h0b, N_NODES);

  // ---- 2 pairs of independent GGC chains, 2-way batched ----
  const int gGather = (2 * N_NODES * 64 + 255) / 256;  // 50000
  const dim3 gruGrid(200, 8, 2);
  for (int p = 0; p < 2; p++) {
    const float* bih_p = b_ih + (size_t)p * 2 * 384;
    const float* bhh_p = b_hh + (size_t)p * 2 * 384;
    const unsigned short* whh_p = whhb + (size_t)p * 2 * S;
    for (int i = 0; i < 4; i++) {
      const unsigned short* wct_pi = wctb + ((size_t)8 * p + i) * S;
      const unsigned short* xin;
      size_t xs;
      unsigned short* xout;
      if (i == 0) { xin = h0b; xs = 0; xout = X0; }
      else if (i == 1) { xin = X0; xs = NH; xout = X1; }
      else if (i == 2) { xin = X1; xs = NH; xout = X0; }
      else { xin = X0; xs = NH; xout = X1; }
      gather4_k<<<gGather, blk, 0, stream>>>(xin, xs, offsets, srcs_sorted, aggb);
      if (i < 3)
        gru_mfma4_k<false><<<gruGrid, blk, 0, stream>>>(
            aggb, xin, xs, h0b, wct_pi, 4 * S, whh_p, S, bih_p, bhh_p, xout,
            N_NODES, nRowTiles);
      else
        gru_mfma4_k<true><<<gruGrid, blk, 0, stream>>>(
            aggb, xin, xs, h0b, wct_pi, 4 * S, whh_p, S, bih_p, bhh_p, xout,
            N_NODES, nRowTiles);
    }
    // hidden (+)= [X1_z0 | X1_z1] @ cat_w[:, p*256:(p+1)*256]^T (+cat_b at p==0)
    cat_mfma2_k<<<dim3(gM64, 4), blk, 0, stream>>>(X1, wcatb, cat_b, hidden, N_NODES, p);
  }

  // ---- heads ----
  lineout_k<<<(N_NODES + 15) / 16, blk, 0, stream>>>(hidden, line_w, line_b, out_line);

  float* gate = (float*)X0;
  float* ex = (float*)X0 + N_NODES;
  float* pooled = (float*)aggb;
  float* h1 = pooled + 512 * 128;
  float* h2 = h1 + 512 * 64;

  gate_k<<<(N_NODES * 64 + 255) / 256, blk, 0, stream>>>(hidden, gate_w, gate_b, gate);
  pool_fused_k<<<512, blk, 0, stream>>>(hidden, gate, gs, ex, pooled);
  mlp1_k<<<512, 64, 0, stream>>>(pooled, mlp_w1, mlp_b1, h1);
  mlp2_k<<<512, 64, 0, stream>>>(h1, mlp_w2, mlp_b2, h2);
  outhead_k<<<512, 64, 0, stream>>>(h2, out_w, out_b, out_graph);
}

// Round 9
// 2795.592 us; speedup vs baseline: 21.7583x; 1.0177x over previous
//
#include <hip/hip_runtime.h>

#define N_NODES 100000
#define N_EDGES 1600000
#define HD 128
#define NH (N_NODES * HD)

typedef __attribute__((ext_vector_type(8))) short bf16x8;
typedef __attribute__((ext_vector_type(4))) float f32x4;

__device__ inline unsigned short f2bf(float f) {
  unsigned u = __float_as_uint(f);
  unsigned r = (u + 0x7FFFu + ((u >> 16) & 1u)) >> 16;
  return (unsigned short)r;
}
__device__ inline float bf2f(unsigned short b) {
  return __uint_as_float(((unsigned)b) << 16);
}
__device__ inline float sigm_f(float x) {
  return __builtin_amdgcn_rcpf(1.f + __expf(-x));
}
__device__ inline float tanh_f(float x) {
  return 1.f - 2.f * __builtin_amdgcn_rcpf(__expf(2.f * x) + 1.f);
}

// ---------------------------------------------------------------------------
// h0 GEMM: h0b = bf16(node_embed @ node_w^T + node_b)
// ---------------------------------------------------------------------------
__global__ __launch_bounds__(256) void gemm_h0_k(
    const float* __restrict__ A, const float* __restrict__ B,
    const float* __restrict__ bias, unsigned short* __restrict__ Cb, int M) {
  __shared__ float As[16][132];
  __shared__ float Bs[16][68];
  const int tid = threadIdx.x;
  const int row0 = blockIdx.x * 128;
  const int col0 = blockIdx.y * 64;
  const int tx = tid & 15, ty = tid >> 4;

  float acc[8][4];
#pragma unroll
  for (int i = 0; i < 8; i++)
#pragma unroll
    for (int j = 0; j < 4; j++) acc[i][j] = 0.f;

  const int lr = tid >> 2;
  const int kg = (tid & 3) * 4;

  for (int k0 = 0; k0 < 128; k0 += 16) {
#pragma unroll
    for (int h = 0; h < 2; ++h) {
      int r = lr + h * 64;
      float4 v = make_float4(0.f, 0.f, 0.f, 0.f);
      if (row0 + r < M)
        v = *reinterpret_cast<const float4*>(A + (size_t)(row0 + r) * 128 + k0 + kg);
      As[kg + 0][r] = v.x;
      As[kg + 1][r] = v.y;
      As[kg + 2][r] = v.z;
      As[kg + 3][r] = v.w;
    }
    {
      int c = lr;
      float4 v = *reinterpret_cast<const float4*>(B + (size_t)(col0 + c) * 128 + k0 + kg);
      Bs[kg + 0][c] = v.x;
      Bs[kg + 1][c] = v.y;
      Bs[kg + 2][c] = v.z;
      Bs[kg + 3][c] = v.w;
    }
    __syncthreads();
#pragma unroll
    for (int kk = 0; kk < 16; ++kk) {
      float a[8], b[4];
#pragma unroll
      for (int i = 0; i < 8; i++) a[i] = As[kk][ty * 8 + i];
#pragma unroll
      for (int j = 0; j < 4; j++) b[j] = Bs[kk][tx * 4 + j];
#pragma unroll
      for (int i = 0; i < 8; i++)
#pragma unroll
        for (int j = 0; j < 4; j++) acc[i][j] += a[i] * b[j];
    }
    __syncthreads();
  }

#pragma unroll
  for (int i = 0; i < 8; i++) {
    int r = row0 + ty * 8 + i;
    if (r < M) {
#pragma unroll
      for (int j = 0; j < 4; j++) {
        int c = col0 + tx * 4 + j;
        Cb[(size_t)r * 128 + c] = f2bf(acc[i][j] + bias[c]);
      }
    }
  }
}

// ---------------------------------------------------------------------------
// Batched WcT fold: C[z] = w_ih[z>>2] @ ggc_w[z]^T   ([384,128] each, z=0..15)
// ---------------------------------------------------------------------------
__global__ __launch_bounds__(256) void gemm_wct_k(
    const float* __restrict__ w_ih, const float* __restrict__ ggc_w,
    float* __restrict__ Cout) {
  const int z = blockIdx.z;
  const float* A = w_ih + (size_t)(z >> 2) * 384 * 128;
  const float* B = ggc_w + (size_t)z * 128 * 128;
  float* C = Cout + (size_t)z * 384 * 128;
  __shared__ float As[16][132];
  __shared__ float Bs[16][68];
  const int tid = threadIdx.x;
  const int row0 = blockIdx.x * 128;
  const int col0 = blockIdx.y * 64;
  const int tx = tid & 15, ty = tid >> 4;

  float acc[8][4];
#pragma unroll
  for (int i = 0; i < 8; i++)
#pragma unroll
    for (int j = 0; j < 4; j++) acc[i][j] = 0.f;

  const int lr = tid >> 2;
  const int kg = (tid & 3) * 4;

  for (int k0 = 0; k0 < 128; k0 += 16) {
#pragma unroll
    for (int h = 0; h < 2; ++h) {
      int r = lr + h * 64;
      float4 v = *reinterpret_cast<const float4*>(A + (size_t)(row0 + r) * 128 + k0 + kg);
      As[kg + 0][r] = v.x;
      As[kg + 1][r] = v.y;
      As[kg + 2][r] = v.z;
      As[kg + 3][r] = v.w;
    }
    {
      int c = lr;
      float4 v = *reinterpret_cast<const float4*>(B + (size_t)(col0 + c) * 128 + k0 + kg);
      Bs[kg + 0][c] = v.x;
      Bs[kg + 1][c] = v.y;
      Bs[kg + 2][c] = v.z;
      Bs[kg + 3][c] = v.w;
    }
    __syncthreads();
#pragma unroll
    for (int kk = 0; kk < 16; ++kk) {
      float a[8], b[4];
#pragma unroll
      for (int i = 0; i < 8; i++) a[i] = As[kk][ty * 8 + i];
#pragma unroll
      for (int j = 0; j < 4; j++) b[j] = Bs[kk][tx * 4 + j];
#pragma unroll
      for (int i = 0; i < 8; i++)
#pragma unroll
        for (int j = 0; j < 4; j++) acc[i][j] += a[i] * b[j];
    }
    __syncthreads();
  }

#pragma unroll
  for (int i = 0; i < 8; i++) {
    int r = row0 + ty * 8 + i;
#pragma unroll
    for (int j = 0; j < 4; j++) {
      int c = col0 + tx * 4 + j;
      C[(size_t)r * 128 + c] = acc[i][j];
    }
  }
}

// ---------------------------------------------------------------------------
// float -> bf16, 4 elems/thread
// ---------------------------------------------------------------------------
__global__ __launch_bounds__(256) void f2b_k(const float* __restrict__ a,
                                             unsigned short* __restrict__ b, int n) {
  int i = blockIdx.x * 256 + threadIdx.x;
  if (i * 4 >= n) return;
  float4 v = reinterpret_cast<const float4*>(a)[i];
  ushort4 o;
  o.x = f2bf(v.x);
  o.y = f2bf(v.y);
  o.z = f2bf(v.z);
  o.w = f2bf(v.w);
  reinterpret_cast<ushort4*>(b)[i] = o;
}

// ---------------------------------------------------------------------------
// GRU v5: 2-way block-batched, bf16 state, 24 persistent weight fragments,
// grid-stride over 16-row tiles; epilogue scalars (xb, h0b) PREFETCHED at
// iteration start so their latency overlaps the MFMA block.
// agg_zs = 0 lets both chains read one shared agg buffer (step i==0).
// ---------------------------------------------------------------------------
template <bool LAST>
__global__ __launch_bounds__(256) void gru_mfma5_k(
    const unsigned short* __restrict__ agg_base, size_t agg_zs,
    const unsigned short* __restrict__ xb_base, size_t xstride,
    const unsigned short* __restrict__ h0b,
    const unsigned short* __restrict__ wct_base, size_t wct_zs,
    const unsigned short* __restrict__ whh_base, size_t whh_zs,
    const float* __restrict__ bih_base, const float* __restrict__ bhh_base,
    unsigned short* __restrict__ xbout, int nRowTiles) {
  const int z = blockIdx.z;
  const unsigned short* agg = agg_base + (size_t)z * agg_zs;
  const unsigned short* xb = xb_base + (size_t)z * xstride;
  unsigned short* out = xbout + (size_t)z * NH;
  const unsigned short* wctb = wct_base + (size_t)z * wct_zs;
  const unsigned short* whhb = whh_base + (size_t)z * whh_zs;
  const float* b_ih = bih_base + z * 384;
  const float* b_hh = bhh_base + z * 384;

  const int lane = threadIdx.x & 63;
  const int wave = threadIdx.x >> 6;
  const int lrow = lane & 15;
  const int kblk = lane >> 4;  // 0..3
  const int c = blockIdx.y * 16 + lrow;

  bf16x8 wf[6][4];
#pragma unroll
  for (int s = 0; s < 3; s++)
#pragma unroll
    for (int kk = 0; kk < 4; kk++) {
      size_t off = (size_t)(s * 128 + c) * 128 + kk * 32 + kblk * 8;
      wf[s][kk] = *reinterpret_cast<const bf16x8*>(wctb + off);
      wf[s + 3][kk] = *reinterpret_cast<const bf16x8*>(whhb + off);
    }
  const float bi0 = b_ih[c], bi1 = b_ih[128 + c], bi2 = b_ih[256 + c];
  const float bh0 = b_hh[c], bh1 = b_hh[128 + c], bh2 = b_hh[256 + c];

  const int tstride = gridDim.x * 4;
  for (int rt = blockIdx.x * 4 + wave; rt < nRowTiles; rt += tstride) {
    const int row0 = rt * 16;  // N_NODES % 16 == 0 -> rows always in-bounds
    const size_t abase = (size_t)(row0 + lrow) * 128 + kblk * 8;
    const int ob = row0 + kblk * 4;

    // prefetch epilogue scalars (hide their latency under the MFMAs)
    unsigned short hxv[4], h0v[4];
#pragma unroll
    for (int r = 0; r < 4; r++) {
      hxv[r] = xb[(size_t)(ob + r) * 128 + c];
      if (LAST) h0v[r] = h0b[(size_t)(ob + r) * 128 + c];
    }

    f32x4 acc[6];
#pragma unroll
    for (int s = 0; s < 6; s++) acc[s] = (f32x4)(0.f);
#pragma unroll
    for (int kk = 0; kk < 4; kk++) {
      bf16x8 a_ag = *reinterpret_cast<const bf16x8*>(agg + abase + kk * 32);
      bf16x8 a_x = *reinterpret_cast<const bf16x8*>(xb + abase + kk * 32);
      acc[0] = __builtin_amdgcn_mfma_f32_16x16x32_bf16(a_ag, wf[0][kk], acc[0], 0, 0, 0);
      acc[1] = __builtin_amdgcn_mfma_f32_16x16x32_bf16(a_ag, wf[1][kk], acc[1], 0, 0, 0);
      acc[2] = __builtin_amdgcn_mfma_f32_16x16x32_bf16(a_ag, wf[2][kk], acc[2], 0, 0, 0);
      acc[3] = __builtin_amdgcn_mfma_f32_16x16x32_bf16(a_x, wf[3][kk], acc[3], 0, 0, 0);
      acc[4] = __builtin_amdgcn_mfma_f32_16x16x32_bf16(a_x, wf[4][kk], acc[4], 0, 0, 0);
      acc[5] = __builtin_amdgcn_mfma_f32_16x16x32_bf16(a_x, wf[5][kk], acc[5], 0, 0, 0);
    }
#pragma unroll
    for (int r = 0; r < 4; r++) {
      size_t idx = (size_t)(ob + r) * 128 + c;
      float ir = acc[0][r] + bi0;
      float iz = acc[1][r] + bi1;
      float in_ = acc[2][r] + bi2;
      float hr = acc[3][r] + bh0;
      float hz = acc[4][r] + bh1;
      float hn = acc[5][r] + bh2;
      float rg = sigm_f(ir + hr);
      float zg = sigm_f(iz + hz);
      float ng = tanh_f(in_ + rg * hn);
      float h = bf2f(hxv[r]);
      float nv = (1.f - zg) * ng + zg * h;
      if (LAST) nv += bf2f(h0v[r]);
      out[idx] = f2bf(nv);
    }
  }
}

// ---------------------------------------------------------------------------
// cat pair: hidden (+)= [outs_z0 | outs_z1] @ cat_w[:, p*256:(p+1)*256]^T
// ---------------------------------------------------------------------------
__global__ __launch_bounds__(256) void cat_mfma2_k(
    const unsigned short* __restrict__ outs, const unsigned short* __restrict__ wcatb,
    const float* __restrict__ cat_b, float* __restrict__ hidden, int M, int pair) {
  const int lane = threadIdx.x & 63;
  const int wave = threadIdx.x >> 6;
  const int row0 = blockIdx.x * 64 + wave * 16;
  const int c0 = blockIdx.y * 32;
  const int lrow = lane & 15;
  const int kb = lane >> 4;
  int arow = row0 + lrow;
  if (arow >= M) arow = M - 1;

  f32x4 acc[2];
  acc[0] = (f32x4)(0.f);
  acc[1] = (f32x4)(0.f);
#pragma unroll
  for (int kk = 0; kk < 8; kk++) {
    const unsigned short* ob = outs + (size_t)(kk >> 2) * NH;
    bf16x8 a = *reinterpret_cast<const bf16x8*>(
        ob + (size_t)arow * 128 + (kk & 3) * 32 + kb * 8);
#pragma unroll
    for (int t = 0; t < 2; t++) {
      bf16x8 b = *reinterpret_cast<const bf16x8*>(
          wcatb + (size_t)(c0 + t * 16 + lrow) * 512 + pair * 256 + (kk >> 2) * 128 +
          (kk & 3) * 32 + kb * 8);
      acc[t] = __builtin_amdgcn_mfma_f32_16x16x32_bf16(a, b, acc[t], 0, 0, 0);
    }
  }
#pragma unroll
  for (int r = 0; r < 4; r++) {
    int orow = row0 + kb * 4 + r;
    if (orow >= M) continue;
#pragma unroll
    for (int t = 0; t < 2; t++) {
      int c = c0 + t * 16 + lrow;
      size_t idx = (size_t)orow * 128 + c;
      float v = acc[t][r];
      v += (pair == 0) ? cat_b[c] : hidden[idx];
      hidden[idx] = v;
    }
  }
}

// ---------------------------------------------------------------------------
// CSR build
// ---------------------------------------------------------------------------
__global__ __launch_bounds__(256) void deg_hist_k(const int* __restrict__ dst,
                                                  int* __restrict__ deg) {
  int e = blockIdx.x * 256 + threadIdx.x;
  if (e >= N_EDGES) return;
  atomicAdd(&deg[dst[e]], 1);
}

__global__ __launch_bounds__(256) void scan1_k(const int* __restrict__ deg,
                                               int* __restrict__ offsets,
                                               int* __restrict__ bsum) {
  __shared__ int buf[256];
  int tid = threadIdx.x;
  int idx = blockIdx.x * 256 + tid;
  int v = (idx < N_NODES) ? deg[idx] : 0;
  buf[tid] = v;
  __syncthreads();
  for (int off = 1; off < 256; off <<= 1) {
    int t = (tid >= off) ? buf[tid - off] : 0;
    __syncthreads();
    buf[tid] += t;
    __syncthreads();
  }
  if (idx < N_NODES) offsets[idx] = buf[tid] - v;
  if (tid == 255) bsum[blockIdx.x] = buf[255];
}

__global__ __launch_bounds__(512) void scan2_k(int* __restrict__ bsum, int nb) {
  __shared__ int buf[512];
  int tid = threadIdx.x;
  int v = (tid < nb) ? bsum[tid] : 0;
  buf[tid] = v;
  __syncthreads();
  for (int off = 1; off < 512; off <<= 1) {
    int t = (tid >= off) ? buf[tid - off] : 0;
    __syncthreads();
    buf[tid] += t;
    __syncthreads();
  }
  if (tid < nb) bsum[tid] = buf[tid] - v;
}

__global__ __launch_bounds__(256) void scan3_k(int* __restrict__ offsets,
                                               const int* __restrict__ bsum) {
  int idx = blockIdx.x * 256 + threadIdx.x;
  if (idx < N_NODES) offsets[idx] += bsum[idx >> 8];
  if (idx == 0) offsets[N_NODES] = N_EDGES;
}

__global__ __launch_bounds__(256) void copy_int_k(const int* __restrict__ a,
                                                  int* __restrict__ b, int n) {
  int i = blockIdx.x * 256 + threadIdx.x;
  if (i < n) b[i] = a[i];
}

__global__ __launch_bounds__(256) void fill_k(const int* __restrict__ src,
                                              const int* __restrict__ dst,
                                              int* __restrict__ cursor,
                                              int* __restrict__ srcs_sorted) {
  int e = blockIdx.x * 256 + threadIdx.x;
  if (e >= N_EDGES) return;
  int pos = atomicAdd(&cursor[dst[e]], 1);
  srcs_sorted[pos] = src[e];
}

// ---------------------------------------------------------------------------
// gather: nz chains, wave per (z,node); lanes split 32/32 over even/odd
// edges; 4 row loads in flight per half-wave.
// ---------------------------------------------------------------------------
__global__ __launch_bounds__(256) void gather5_k(
    const unsigned short* __restrict__ xb_base, size_t xstride,
    const int* __restrict__ offsets, const int* __restrict__ srcs,
    unsigned short* __restrict__ aggb, int nz) {
  int wid = (blockIdx.x * 256 + threadIdx.x) >> 6;
  int lane = threadIdx.x & 63;
  if (wid >= nz * N_NODES) return;
  int z = (wid >= N_NODES) ? 1 : 0;
  int node = wid - z * N_NODES;
  const unsigned short* xb = xb_base + (size_t)z * xstride;
  int beg = offsets[node], end = offsets[node + 1];
  int half = lane >> 5;
  int cg = (lane & 31) * 4;
  float a0 = 0.f, a1 = 0.f, a2 = 0.f, a3 = 0.f;
  int e = beg + half;
  for (; e + 6 < end; e += 8) {
    int s0 = srcs[e], s1 = srcs[e + 2], s2 = srcs[e + 4], s3 = srcs[e + 6];
    uint2 v0 = *reinterpret_cast<const uint2*>(xb + (size_t)s0 * 128 + cg);
    uint2 v1 = *reinterpret_cast<const uint2*>(xb + (size_t)s1 * 128 + cg);
    uint2 v2 = *reinterpret_cast<const uint2*>(xb + (size_t)s2 * 128 + cg);
    uint2 v3 = *reinterpret_cast<const uint2*>(xb + (size_t)s3 * 128 + cg);
    a0 += bf2f((unsigned short)(v0.x & 0xFFFFu)) + bf2f((unsigned short)(v1.x & 0xFFFFu)) +
          bf2f((unsigned short)(v2.x & 0xFFFFu)) + bf2f((unsigned short)(v3.x & 0xFFFFu));
    a1 += bf2f((unsigned short)(v0.x >> 16)) + bf2f((unsigned short)(v1.x >> 16)) +
          bf2f((unsigned short)(v2.x >> 16)) + bf2f((unsigned short)(v3.x >> 16));
    a2 += bf2f((unsigned short)(v0.y & 0xFFFFu)) + bf2f((unsigned short)(v1.y & 0xFFFFu)) +
          bf2f((unsigned short)(v2.y & 0xFFFFu)) + bf2f((unsigned short)(v3.y & 0xFFFFu));
    a3 += bf2f((unsigned short)(v0.y >> 16)) + bf2f((unsigned short)(v1.y >> 16)) +
          bf2f((unsigned short)(v2.y >> 16)) + bf2f((unsigned short)(v3.y >> 16));
  }
  for (; e < end; e += 2) {
    int s0 = srcs[e];
    uint2 v0 = *reinterpret_cast<const uint2*>(xb + (size_t)s0 * 128 + cg);
    a0 += bf2f((unsigned short)(v0.x & 0xFFFFu));
    a1 += bf2f((unsigned short)(v0.x >> 16));
    a2 += bf2f((unsigned short)(v0.y & 0xFFFFu));
    a3 += bf2f((unsigned short)(v0.y >> 16));
  }
  a0 += __shfl_down(a0, 32);
  a1 += __shfl_down(a1, 32);
  a2 += __shfl_down(a2, 32);
  a3 += __shfl_down(a3, 32);
  if (half == 0) {
    uint2 o;
    o.x = (unsigned)f2bf(a0) | ((unsigned)f2bf(a1) << 16);
    o.y = (unsigned)f2bf(a2) | ((unsigned)f2bf(a3) << 16);
    *reinterpret_cast<uint2*>(aggb + (size_t)z * NH + (size_t)node * 128 + cg) = o;
  }
}

// lineout = hidden @ line_w^T + line_b
__global__ __launch_bounds__(256) void lineout_k(
    const float* __restrict__ hidden, const float* __restrict__ W,
    const float* __restrict__ b, float* __restrict__ out) {
  __shared__ float Ws[16 * 128];
  for (int i = threadIdx.x; i < 2048; i += 256) Ws[i] = W[i];
  __syncthreads();
  int r = threadIdx.x >> 4, c = threadIdx.x & 15;
  int n = blockIdx.x * 16 + r;
  if (n >= N_NODES) return;
  const float* h = hidden + (size_t)n * 128;
  const float* w = Ws + c * 128;
  float acc = 0.f;
#pragma unroll 8
  for (int k = 0; k < 128; k++) acc += h[k] * w[k];
  out[(size_t)n * 16 + c] = acc + b[c];
}

// gate[n] = hidden[n] . gate_w + gate_b
__global__ __launch_bounds__(256) void gate_k(
    const float* __restrict__ hidden, const float* __restrict__ gw,
    const float* __restrict__ gb, float* __restrict__ gate) {
  int wid = (blockIdx.x * 256 + threadIdx.x) >> 6;
  int lane = threadIdx.x & 63;
  if (wid >= N_NODES) return;
  const float* h = hidden + (size_t)wid * 128;
  float s = h[lane] * gw[lane] + h[64 + lane] * gw[64 + lane];
#pragma unroll
  for (int off = 32; off; off >>= 1) s += __shfl_down(s, off);
  if (lane == 0) gate[wid] = s + gb[0];
}

// gs[g] = lower_bound(batch, g)
__global__ void graph_start_k(const int* __restrict__ batch, int* __restrict__ gs) {
  int g = threadIdx.x;
  if (g > 512) return;
  if (g == 512) {
    gs[512] = N_NODES;
    return;
  }
  int lo = 0, hi = N_NODES;
  while (lo < hi) {
    int mid = (lo + hi) >> 1;
    if (batch[mid] < g) lo = mid + 1;
    else hi = mid;
  }
  gs[g] = lo;
}

// ---------------------------------------------------------------------------
// Per-graph attention pool (batch sorted, no atomics)
// ---------------------------------------------------------------------------
__global__ __launch_bounds__(256) void pool_fused_k(
    const float* __restrict__ hidden, const float* __restrict__ gate,
    const int* __restrict__ gs, float* __restrict__ ex,
    float* __restrict__ pooled) {
  const int g = blockIdx.x;
  const int beg = gs[g], end = gs[g + 1];
  const int tid = threadIdx.x, lane = tid & 63, wv = tid >> 6;
  __shared__ float red[4];
  __shared__ float sval;
  __shared__ float colbuf[256];

  if (end <= beg) {
    if (tid < 128) pooled[(size_t)g * 128 + tid] = 0.f;
    return;
  }
  float m = -3.4e38f;
  for (int n = beg + tid; n < end; n += 256) m = fmaxf(m, gate[n]);
#pragma unroll
  for (int off = 32; off; off >>= 1) m = fmaxf(m, __shfl_down(m, off));
  if (lane == 0) red[wv] = m;
  __syncthreads();
  if (tid == 0) sval = fmaxf(fmaxf(red[0], red[1]), fmaxf(red[2], red[3]));
  __syncthreads();
  const float mx = sval;
  float s = 0.f;
  for (int n = beg + tid; n < end; n += 256) {
    float e = __expf(gate[n] - mx);
    ex[n] = e;
    s += e;
  }
#pragma unroll
  for (int off = 32; off; off >>= 1) s += __shfl_down(s, off);
  if (lane == 0) red[wv] = s;
  __syncthreads();
  if (tid == 0) sval = red[0] + red[1] + red[2] + red[3];
  __syncthreads();
  const float denom = sval;
  const int col = tid & 127, half = tid >> 7;
  float acc = 0.f;
  for (int n = beg + half; n < end; n += 2)
    acc += ex[n] * hidden[(size_t)n * 128 + col];
  colbuf[tid] = acc;
  __syncthreads();
  if (tid < 128)
    pooled[(size_t)g * 128 + tid] = (colbuf[tid] + colbuf[tid + 128]) / denom;
}

__global__ void mlp1_k(const float* __restrict__ pooled, const float* __restrict__ w,
                       const float* __restrict__ b, float* __restrict__ h1) {
  int g = blockIdx.x, j = threadIdx.x;
  const float* p = pooled + (size_t)g * 128;
  const float* wr = w + (size_t)j * 128;
  float acc = 0.f;
#pragma unroll 8
  for (int k = 0; k < 128; k++) acc += p[k] * wr[k];
  acc += b[j];
  h1[g * 64 + j] = acc > 0.f ? acc : 0.f;
}

__global__ void mlp2_k(const float* __restrict__ h1, const float* __restrict__ w,
                       const float* __restrict__ b, float* __restrict__ h2) {
  int g = blockIdx.x, j = threadIdx.x;
  const float* p = h1 + (size_t)g * 64;
  const float* wr = w + (size_t)j * 64;
  float acc = 0.f;
#pragma unroll 8
  for (int k = 0; k < 64; k++) acc += p[k] * wr[k];
  acc += b[j];
  h2[g * 64 + j] = acc > 0.f ? acc : 0.f;
}

__global__ void outhead_k(const float* __restrict__ h2, const float* __restrict__ w,
                          const float* __restrict__ b, float* __restrict__ out) {
  int g = blockIdx.x, j = threadIdx.x;
  if (j >= 16) return;
  const float* p = h2 + (size_t)g * 64;
  const float* wr = w + (size_t)j * 64;
  float acc = 0.f;
#pragma unroll 8
  for (int k = 0; k < 64; k++) acc += p[k] * wr[k];
  out[g * 16 + j] = acc + b[j];
}

extern "C" void kernel_launch(void* const* d_in, const int* in_sizes, int n_in,
                              void* d_out, int out_size, void* d_ws, size_t ws_size,
                              hipStream_t stream) {
  const float* node_embed = (const float*)d_in[0];
  const int* eidx = (const int*)d_in[1];
  const int* batch = (const int*)d_in[2];
  const float* node_w = (const float*)d_in[3];
  const float* node_b = (const float*)d_in[4];
  const float* ggc_w = (const float*)d_in[5];
  const float* w_ih = (const float*)d_in[6];
  const float* w_hh = (const float*)d_in[7];
  const float* b_ih = (const float*)d_in[8];
  const float* b_hh = (const float*)d_in[9];
  const float* cat_w = (const float*)d_in[10];
  const float* cat_b = (const float*)d_in[11];
  const float* gate_w = (const float*)d_in[12];
  const float* gate_b = (const float*)d_in[13];
  const float* mlp_w1 = (const float*)d_in[14];
  const float* mlp_b1 = (const float*)d_in[15];
  const float* mlp_w2 = (const float*)d_in[16];
  const float* mlp_b2 = (const float*)d_in[17];
  const float* out_w = (const float*)d_in[18];
  const float* out_b = (const float*)d_in[19];
  const float* line_w = (const float*)d_in[20];
  const float* line_b = (const float*)d_in[21];

  const int* src = eidx;
  const int* dst = eidx + N_EDGES;

  // workspace ~254 MB (same extent as proven round-8 layout)
  float* hidden = (float*)d_ws;
  unsigned short* h0b = (unsigned short*)(hidden + (size_t)NH);
  unsigned short* X0 = h0b + (size_t)NH;
  unsigned short* X1 = X0 + (size_t)2 * NH;
  unsigned short* aggb = X1 + (size_t)2 * NH;
  unsigned short* wctb = aggb + (size_t)2 * NH;     // 16*384*128
  unsigned short* whhb = wctb + 16 * 384 * 128;     // 4*384*128
  unsigned short* wcatb = whhb + 4 * 384 * 128;     // 128*512
  int* offsets = (int*)(wcatb + 128 * 512);         // [N+1]
  int* cursor = offsets + N_NODES + 1;              // [N]
  int* srcs_sorted = cursor + N_NODES;              // [E]
  int* bsum = srcs_sorted + N_EDGES;                // [512]
  int* gs = bsum + 512;                             // [513]
  float* WcTf = (float*)aggb;                       // fp32 staging overlay (pre-loop)

  float* out_graph = (float*)d_out;
  float* out_line = (float*)d_out + 512 * 16;

  dim3 blk(256);
  const int gM128 = (N_NODES + 127) / 128;
  const int gM64 = (N_NODES + 63) / 64;
  const int gE = (N_EDGES + 255) / 256;
  const int nScanBlk = (N_NODES + 255) / 256;
  const int nRowTiles = N_NODES / 16;  // 6250, exact
  const size_t S = (size_t)384 * 128;

  // ---- CSR build ----
  hipMemsetAsync(cursor, 0, N_NODES * sizeof(int), stream);
  deg_hist_k<<<gE, blk, 0, stream>>>(dst, cursor);
  scan1_k<<<nScanBlk, blk, 0, stream>>>(cursor, offsets, bsum);
  scan2_k<<<1, 512, 0, stream>>>(bsum, nScanBlk);
  scan3_k<<<nScanBlk, blk, 0, stream>>>(offsets, bsum);
  copy_int_k<<<(N_NODES + 255) / 256, blk, 0, stream>>>(offsets, cursor, N_NODES);
  fill_k<<<gE, blk, 0, stream>>>(src, dst, cursor, srcs_sorted);
  graph_start_k<<<1, 576, 0, stream>>>(batch, gs);

  // ---- weights: WcT fold -> bf16; w_hh, cat_w -> bf16 ----
  gemm_wct_k<<<dim3(3, 2, 16), blk, 0, stream>>>(w_ih, ggc_w, WcTf);
  f2b_k<<<(16 * 384 * 128 / 4 + 255) / 256, blk, 0, stream>>>(WcTf, wctb, 16 * 384 * 128);
  f2b_k<<<(4 * 384 * 128 / 4 + 255) / 256, blk, 0, stream>>>(w_hh, whhb, 4 * 384 * 128);
  f2b_k<<<(128 * 512 / 4 + 255) / 256, blk, 0, stream>>>(cat_w, wcatb, 128 * 512);

  // ---- h0b = bf16(node_embed @ node_w^T + node_b) ----
  gemm_h0_k<<<dim3(gM128, 2), blk, 0, stream>>>(node_embed, node_w, node_b, h0b, N_NODES);

  // ---- 2 pairs of independent GGC chains, 2-way batched ----
  const int gGather2 = (2 * N_NODES * 64 + 255) / 256;
  const int gGather1 = (N_NODES * 64 + 255) / 256;
  const dim3 gruGrid(400, 8, 2);
  for (int p = 0; p < 2; p++) {
    const float* bih_p = b_ih + (size_t)p * 2 * 384;
    const float* bhh_p = b_hh + (size_t)p * 2 * 384;
    const unsigned short* whh_p = whhb + (size_t)p * 2 * S;
    for (int i = 0; i < 4; i++) {
      const unsigned short* wct_pi = wctb + ((size_t)8 * p + i) * S;
      const unsigned short* xin;
      size_t xs;
      unsigned short* xout;
      if (i == 0) { xin = h0b; xs = 0; xout = X0; }
      else if (i == 1) { xin = X0; xs = NH; xout = X1; }
      else if (i == 2) { xin = X1; xs = NH; xout = X0; }
      else { xin = X0; xs = NH; xout = X1; }
      // step 0: both chains share the same input -> gather once, agg_zs=0
      const size_t agg_zs = (i == 0) ? 0 : (size_t)NH;
      gather5_k<<<(i == 0 ? gGather1 : gGather2), blk, 0, stream>>>(
          xin, xs, offsets, srcs_sorted, aggb, (i == 0 ? 1 : 2));
      if (i < 3)
        gru_mfma5_k<false><<<gruGrid, blk, 0, stream>>>(
            aggb, agg_zs, xin, xs, h0b, wct_pi, 4 * S, whh_p, S, bih_p, bhh_p,
            xout, nRowTiles);
      else
        gru_mfma5_k<true><<<gruGrid, blk, 0, stream>>>(
            aggb, agg_zs, xin, xs, h0b, wct_pi, 4 * S, whh_p, S, bih_p, bhh_p,
            xout, nRowTiles);
    }
    cat_mfma2_k<<<dim3(gM64, 4), blk, 0, stream>>>(X1, wcatb, cat_b, hidden, N_NODES, p);
  }

  // ---- heads ----
  lineout_k<<<(N_NODES + 15) / 16, blk, 0, stream>>>(hidden, line_w, line_b, out_line);

  float* gate = (float*)X0;
  float* ex = (float*)X0 + N_NODES;
  float* pooled = (float*)aggb;
  float* h1 = pooled + 512 * 128;
  float* h2 = h1 + 512 * 64;

  gate_k<<<(N_NODES * 64 + 255) / 256, blk, 0, stream>>>(hidden, gate_w, gate_b, gate);
  pool_fused_k<<<512, blk, 0, stream>>>(hidden, gate, gs, ex, pooled);
  mlp1_k<<<512, 64, 0, stream>>>(pooled, mlp_w1, mlp_b1, h1);
  mlp2_k<<<512, 64, 0, stream>>>(h1, mlp_w2, mlp_b2, h2);
  outhead_k<<<512, 64, 0, stream>>>(h2, out_w, out_b, out_graph);
}

// Round 10
// 2571.827 us; speedup vs baseline: 23.6514x; 1.0870x over previous
//
#include <hip/hip_runtime.h>

#define N_NODES 100000
#define N_EDGES 1600000
#define HD 128
#define NH (N_NODES * HD)

typedef __attribute__((ext_vector_type(8))) short bf16x8;
typedef __attribute__((ext_vector_type(4))) float f32x4;

__device__ inline unsigned short f2bf(float f) {
  unsigned u = __float_as_uint(f);
  unsigned r = (u + 0x7FFFu + ((u >> 16) & 1u)) >> 16;
  return (unsigned short)r;
}
__device__ inline float bf2f(unsigned short b) {
  return __uint_as_float(((unsigned)b) << 16);
}
__device__ inline float sigm_f(float x) {
  return __builtin_amdgcn_rcpf(1.f + __expf(-x));
}
__device__ inline float tanh_f(float x) {
  return 1.f - 2.f * __builtin_amdgcn_rcpf(__expf(2.f * x) + 1.f);
}

// ---------------------------------------------------------------------------
// h0 GEMM: h0b = bf16(node_embed @ node_w^T + node_b)
// ---------------------------------------------------------------------------
__global__ __launch_bounds__(256) void gemm_h0_k(
    const float* __restrict__ A, const float* __restrict__ B,
    const float* __restrict__ bias, unsigned short* __restrict__ Cb, int M) {
  __shared__ float As[16][132];
  __shared__ float Bs[16][68];
  const int tid = threadIdx.x;
  const int row0 = blockIdx.x * 128;
  const int col0 = blockIdx.y * 64;
  const int tx = tid & 15, ty = tid >> 4;

  float acc[8][4];
#pragma unroll
  for (int i = 0; i < 8; i++)
#pragma unroll
    for (int j = 0; j < 4; j++) acc[i][j] = 0.f;

  const int lr = tid >> 2;
  const int kg = (tid & 3) * 4;

  for (int k0 = 0; k0 < 128; k0 += 16) {
#pragma unroll
    for (int h = 0; h < 2; ++h) {
      int r = lr + h * 64;
      float4 v = make_float4(0.f, 0.f, 0.f, 0.f);
      if (row0 + r < M)
        v = *reinterpret_cast<const float4*>(A + (size_t)(row0 + r) * 128 + k0 + kg);
      As[kg + 0][r] = v.x;
      As[kg + 1][r] = v.y;
      As[kg + 2][r] = v.z;
      As[kg + 3][r] = v.w;
    }
    {
      int c = lr;
      float4 v = *reinterpret_cast<const float4*>(B + (size_t)(col0 + c) * 128 + k0 + kg);
      Bs[kg + 0][c] = v.x;
      Bs[kg + 1][c] = v.y;
      Bs[kg + 2][c] = v.z;
      Bs[kg + 3][c] = v.w;
    }
    __syncthreads();
#pragma unroll
    for (int kk = 0; kk < 16; ++kk) {
      float a[8], b[4];
#pragma unroll
      for (int i = 0; i < 8; i++) a[i] = As[kk][ty * 8 + i];
#pragma unroll
      for (int j = 0; j < 4; j++) b[j] = Bs[kk][tx * 4 + j];
#pragma unroll
      for (int i = 0; i < 8; i++)
#pragma unroll
        for (int j = 0; j < 4; j++) acc[i][j] += a[i] * b[j];
    }
    __syncthreads();
  }

#pragma unroll
  for (int i = 0; i < 8; i++) {
    int r = row0 + ty * 8 + i;
    if (r < M) {
#pragma unroll
      for (int j = 0; j < 4; j++) {
        int c = col0 + tx * 4 + j;
        Cb[(size_t)r * 128 + c] = f2bf(acc[i][j] + bias[c]);
      }
    }
  }
}

// ---------------------------------------------------------------------------
// Batched WcT fold: C[z] = w_ih[z>>2] @ ggc_w[z]^T   ([384,128] each, z=0..15)
// ---------------------------------------------------------------------------
__global__ __launch_bounds__(256) void gemm_wct_k(
    const float* __restrict__ w_ih, const float* __restrict__ ggc_w,
    float* __restrict__ Cout) {
  const int z = blockIdx.z;
  const float* A = w_ih + (size_t)(z >> 2) * 384 * 128;
  const float* B = ggc_w + (size_t)z * 128 * 128;
  float* C = Cout + (size_t)z * 384 * 128;
  __shared__ float As[16][132];
  __shared__ float Bs[16][68];
  const int tid = threadIdx.x;
  const int row0 = blockIdx.x * 128;
  const int col0 = blockIdx.y * 64;
  const int tx = tid & 15, ty = tid >> 4;

  float acc[8][4];
#pragma unroll
  for (int i = 0; i < 8; i++)
#pragma unroll
    for (int j = 0; j < 4; j++) acc[i][j] = 0.f;

  const int lr = tid >> 2;
  const int kg = (tid & 3) * 4;

  for (int k0 = 0; k0 < 128; k0 += 16) {
#pragma unroll
    for (int h = 0; h < 2; ++h) {
      int r = lr + h * 64;
      float4 v = *reinterpret_cast<const float4*>(A + (size_t)(row0 + r) * 128 + k0 + kg);
      As[kg + 0][r] = v.x;
      As[kg + 1][r] = v.y;
      As[kg + 2][r] = v.z;
      As[kg + 3][r] = v.w;
    }
    {
      int c = lr;
      float4 v = *reinterpret_cast<const float4*>(B + (size_t)(col0 + c) * 128 + k0 + kg);
      Bs[kg + 0][c] = v.x;
      Bs[kg + 1][c] = v.y;
      Bs[kg + 2][c] = v.z;
      Bs[kg + 3][c] = v.w;
    }
    __syncthreads();
#pragma unroll
    for (int kk = 0; kk < 16; ++kk) {
      float a[8], b[4];
#pragma unroll
      for (int i = 0; i < 8; i++) a[i] = As[kk][ty * 8 + i];
#pragma unroll
      for (int j = 0; j < 4; j++) b[j] = Bs[kk][tx * 4 + j];
#pragma unroll
      for (int i = 0; i < 8; i++)
#pragma unroll
        for (int j = 0; j < 4; j++) acc[i][j] += a[i] * b[j];
    }
    __syncthreads();
  }

#pragma unroll
  for (int i = 0; i < 8; i++) {
    int r = row0 + ty * 8 + i;
#pragma unroll
    for (int j = 0; j < 4; j++) {
      int c = col0 + tx * 4 + j;
      C[(size_t)r * 128 + c] = acc[i][j];
    }
  }
}

// ---------------------------------------------------------------------------
// float -> bf16, 4 elems/thread
// ---------------------------------------------------------------------------
__global__ __launch_bounds__(256) void f2b_k(const float* __restrict__ a,
                                             unsigned short* __restrict__ b, int n) {
  int i = blockIdx.x * 256 + threadIdx.x;
  if (i * 4 >= n) return;
  float4 v = reinterpret_cast<const float4*>(a)[i];
  ushort4 o;
  o.x = f2bf(v.x);
  o.y = f2bf(v.y);
  o.z = f2bf(v.z);
  o.w = f2bf(v.w);
  reinterpret_cast<ushort4*>(b)[i] = o;
}

// ---------------------------------------------------------------------------
// GRU v6: round-8 structure (no epilogue prefetch, grid.x=200) + explicit
// preload of all 8 A-fragments for deeper load ILP. 2-way block-batched,
// bf16 state, 24 persistent weight fragments, grid-stride over 16-row tiles.
// agg_zs = 0 lets both chains read one shared agg buffer (step i==0).
// ---------------------------------------------------------------------------
template <bool LAST>
__global__ __launch_bounds__(256) void gru_mfma6_k(
    const unsigned short* __restrict__ agg_base, size_t agg_zs,
    const unsigned short* __restrict__ xb_base, size_t xstride,
    const unsigned short* __restrict__ h0b,
    const unsigned short* __restrict__ wct_base, size_t wct_zs,
    const unsigned short* __restrict__ whh_base, size_t whh_zs,
    const float* __restrict__ bih_base, const float* __restrict__ bhh_base,
    unsigned short* __restrict__ xbout, int nRowTiles) {
  const int z = blockIdx.z;
  const unsigned short* agg = agg_base + (size_t)z * agg_zs;
  const unsigned short* xb = xb_base + (size_t)z * xstride;
  unsigned short* out = xbout + (size_t)z * NH;
  const unsigned short* wctb = wct_base + (size_t)z * wct_zs;
  const unsigned short* whhb = whh_base + (size_t)z * whh_zs;
  const float* b_ih = bih_base + z * 384;
  const float* b_hh = bhh_base + z * 384;

  const int lane = threadIdx.x & 63;
  const int wave = threadIdx.x >> 6;
  const int lrow = lane & 15;
  const int kblk = lane >> 4;  // 0..3
  const int c = blockIdx.y * 16 + lrow;

  bf16x8 wf[6][4];
#pragma unroll
  for (int s = 0; s < 3; s++)
#pragma unroll
    for (int kk = 0; kk < 4; kk++) {
      size_t off = (size_t)(s * 128 + c) * 128 + kk * 32 + kblk * 8;
      wf[s][kk] = *reinterpret_cast<const bf16x8*>(wctb + off);
      wf[s + 3][kk] = *reinterpret_cast<const bf16x8*>(whhb + off);
    }
  const float bi0 = b_ih[c], bi1 = b_ih[128 + c], bi2 = b_ih[256 + c];
  const float bh0 = b_hh[c], bh1 = b_hh[128 + c], bh2 = b_hh[256 + c];

  const int tstride = gridDim.x * 4;
  for (int rt = blockIdx.x * 4 + wave; rt < nRowTiles; rt += tstride) {
    const int row0 = rt * 16;  // N_NODES % 16 == 0 -> rows in-bounds
    const size_t abase = (size_t)(row0 + lrow) * 128 + kblk * 8;

    // issue all 8 fragment loads up-front (deep ILP)
    bf16x8 a_ag[4], a_x[4];
#pragma unroll
    for (int kk = 0; kk < 4; kk++) {
      a_ag[kk] = *reinterpret_cast<const bf16x8*>(agg + abase + kk * 32);
      a_x[kk] = *reinterpret_cast<const bf16x8*>(xb + abase + kk * 32);
    }

    f32x4 acc[6];
#pragma unroll
    for (int s = 0; s < 6; s++) acc[s] = (f32x4)(0.f);
#pragma unroll
    for (int kk = 0; kk < 4; kk++) {
      acc[0] = __builtin_amdgcn_mfma_f32_16x16x32_bf16(a_ag[kk], wf[0][kk], acc[0], 0, 0, 0);
      acc[1] = __builtin_amdgcn_mfma_f32_16x16x32_bf16(a_ag[kk], wf[1][kk], acc[1], 0, 0, 0);
      acc[2] = __builtin_amdgcn_mfma_f32_16x16x32_bf16(a_ag[kk], wf[2][kk], acc[2], 0, 0, 0);
      acc[3] = __builtin_amdgcn_mfma_f32_16x16x32_bf16(a_x[kk], wf[3][kk], acc[3], 0, 0, 0);
      acc[4] = __builtin_amdgcn_mfma_f32_16x16x32_bf16(a_x[kk], wf[4][kk], acc[4], 0, 0, 0);
      acc[5] = __builtin_amdgcn_mfma_f32_16x16x32_bf16(a_x[kk], wf[5][kk], acc[5], 0, 0, 0);
    }
    // C/D: col = lane&15 (= lrow -> c), row = kblk*4 + r
#pragma unroll
    for (int r = 0; r < 4; r++) {
      int orow = row0 + kblk * 4 + r;
      size_t idx = (size_t)orow * 128 + c;
      float ir = acc[0][r] + bi0;
      float iz = acc[1][r] + bi1;
      float in_ = acc[2][r] + bi2;
      float hr = acc[3][r] + bh0;
      float hz = acc[4][r] + bh1;
      float hn = acc[5][r] + bh2;
      float rg = sigm_f(ir + hr);
      float zg = sigm_f(iz + hz);
      float ng = tanh_f(in_ + rg * hn);
      float h = bf2f(xb[idx]);
      float nv = (1.f - zg) * ng + zg * h;
      if (LAST) nv += bf2f(h0b[idx]);
      out[idx] = f2bf(nv);
    }
  }
}

// ---------------------------------------------------------------------------
// cat pair: hidden (+)= [outs_z0 | outs_z1] @ cat_w[:, p*256:(p+1)*256]^T
// ---------------------------------------------------------------------------
__global__ __launch_bounds__(256) void cat_mfma2_k(
    const unsigned short* __restrict__ outs, const unsigned short* __restrict__ wcatb,
    const float* __restrict__ cat_b, float* __restrict__ hidden, int M, int pair) {
  const int lane = threadIdx.x & 63;
  const int wave = threadIdx.x >> 6;
  const int row0 = blockIdx.x * 64 + wave * 16;
  const int c0 = blockIdx.y * 32;
  const int lrow = lane & 15;
  const int kb = lane >> 4;
  int arow = row0 + lrow;
  if (arow >= M) arow = M - 1;

  f32x4 acc[2];
  acc[0] = (f32x4)(0.f);
  acc[1] = (f32x4)(0.f);
#pragma unroll
  for (int kk = 0; kk < 8; kk++) {
    const unsigned short* ob = outs + (size_t)(kk >> 2) * NH;
    bf16x8 a = *reinterpret_cast<const bf16x8*>(
        ob + (size_t)arow * 128 + (kk & 3) * 32 + kb * 8);
#pragma unroll
    for (int t = 0; t < 2; t++) {
      bf16x8 b = *reinterpret_cast<const bf16x8*>(
          wcatb + (size_t)(c0 + t * 16 + lrow) * 512 + pair * 256 + (kk >> 2) * 128 +
          (kk & 3) * 32 + kb * 8);
      acc[t] = __builtin_amdgcn_mfma_f32_16x16x32_bf16(a, b, acc[t], 0, 0, 0);
    }
  }
#pragma unroll
  for (int r = 0; r < 4; r++) {
    int orow = row0 + kb * 4 + r;
    if (orow >= M) continue;
#pragma unroll
    for (int t = 0; t < 2; t++) {
      int c = c0 + t * 16 + lrow;
      size_t idx = (size_t)orow * 128 + c;
      float v = acc[t][r];
      v += (pair == 0) ? cat_b[c] : hidden[idx];
      hidden[idx] = v;
    }
  }
}

// ---------------------------------------------------------------------------
// CSR build
// ---------------------------------------------------------------------------
__global__ __launch_bounds__(256) void deg_hist_k(const int* __restrict__ dst,
                                                  int* __restrict__ deg) {
  int e = blockIdx.x * 256 + threadIdx.x;
  if (e >= N_EDGES) return;
  atomicAdd(&deg[dst[e]], 1);
}

__global__ __launch_bounds__(256) void scan1_k(const int* __restrict__ deg,
                                               int* __restrict__ offsets,
                                               int* __restrict__ bsum) {
  __shared__ int buf[256];
  int tid = threadIdx.x;
  int idx = blockIdx.x * 256 + tid;
  int v = (idx < N_NODES) ? deg[idx] : 0;
  buf[tid] = v;
  __syncthreads();
  for (int off = 1; off < 256; off <<= 1) {
    int t = (tid >= off) ? buf[tid - off] : 0;
    __syncthreads();
    buf[tid] += t;
    __syncthreads();
  }
  if (idx < N_NODES) offsets[idx] = buf[tid] - v;
  if (tid == 255) bsum[blockIdx.x] = buf[255];
}

__global__ __launch_bounds__(512) void scan2_k(int* __restrict__ bsum, int nb) {
  __shared__ int buf[512];
  int tid = threadIdx.x;
  int v = (tid < nb) ? bsum[tid] : 0;
  buf[tid] = v;
  __syncthreads();
  for (int off = 1; off < 512; off <<= 1) {
    int t = (tid >= off) ? buf[tid - off] : 0;
    __syncthreads();
    buf[tid] += t;
    __syncthreads();
  }
  if (tid < nb) bsum[tid] = buf[tid] - v;
}

__global__ __launch_bounds__(256) void scan3_k(int* __restrict__ offsets,
                                               const int* __restrict__ bsum) {
  int idx = blockIdx.x * 256 + threadIdx.x;
  if (idx < N_NODES) offsets[idx] += bsum[idx >> 8];
  if (idx == 0) offsets[N_NODES] = N_EDGES;
}

__global__ __launch_bounds__(256) void copy_int_k(const int* __restrict__ a,
                                                  int* __restrict__ b, int n) {
  int i = blockIdx.x * 256 + threadIdx.x;
  if (i < n) b[i] = a[i];
}

__global__ __launch_bounds__(256) void fill_k(const int* __restrict__ src,
                                              const int* __restrict__ dst,
                                              int* __restrict__ cursor,
                                              int* __restrict__ srcs_sorted) {
  int e = blockIdx.x * 256 + threadIdx.x;
  if (e >= N_EDGES) return;
  int pos = atomicAdd(&cursor[dst[e]], 1);
  srcs_sorted[pos] = src[e];
}

// ---------------------------------------------------------------------------
// gather: nz chains, wave per (z,node); lanes split 32/32 over even/odd
// edges; 4 row loads in flight per half-wave.
// ---------------------------------------------------------------------------
__global__ __launch_bounds__(256) void gather5_k(
    const unsigned short* __restrict__ xb_base, size_t xstride,
    const int* __restrict__ offsets, const int* __restrict__ srcs,
    unsigned short* __restrict__ aggb, int nz) {
  int wid = (blockIdx.x * 256 + threadIdx.x) >> 6;
  int lane = threadIdx.x & 63;
  if (wid >= nz * N_NODES) return;
  int z = (wid >= N_NODES) ? 1 : 0;
  int node = wid - z * N_NODES;
  const unsigned short* xb = xb_base + (size_t)z * xstride;
  int beg = offsets[node], end = offsets[node + 1];
  int half = lane >> 5;
  int cg = (lane & 31) * 4;
  float a0 = 0.f, a1 = 0.f, a2 = 0.f, a3 = 0.f;
  int e = beg + half;
  for (; e + 6 < end; e += 8) {
    int s0 = srcs[e], s1 = srcs[e + 2], s2 = srcs[e + 4], s3 = srcs[e + 6];
    uint2 v0 = *reinterpret_cast<const uint2*>(xb + (size_t)s0 * 128 + cg);
    uint2 v1 = *reinterpret_cast<const uint2*>(xb + (size_t)s1 * 128 + cg);
    uint2 v2 = *reinterpret_cast<const uint2*>(xb + (size_t)s2 * 128 + cg);
    uint2 v3 = *reinterpret_cast<const uint2*>(xb + (size_t)s3 * 128 + cg);
    a0 += bf2f((unsigned short)(v0.x & 0xFFFFu)) + bf2f((unsigned short)(v1.x & 0xFFFFu)) +
          bf2f((unsigned short)(v2.x & 0xFFFFu)) + bf2f((unsigned short)(v3.x & 0xFFFFu));
    a1 += bf2f((unsigned short)(v0.x >> 16)) + bf2f((unsigned short)(v1.x >> 16)) +
          bf2f((unsigned short)(v2.x >> 16)) + bf2f((unsigned short)(v3.x >> 16));
    a2 += bf2f((unsigned short)(v0.y & 0xFFFFu)) + bf2f((unsigned short)(v1.y & 0xFFFFu)) +
          bf2f((unsigned short)(v2.y & 0xFFFFu)) + bf2f((unsigned short)(v3.y & 0xFFFFu));
    a3 += bf2f((unsigned short)(v0.y >> 16)) + bf2f((unsigned short)(v1.y >> 16)) +
          bf2f((unsigned short)(v2.y >> 16)) + bf2f((unsigned short)(v3.y >> 16));
  }
  for (; e < end; e += 2) {
    int s0 = srcs[e];
    uint2 v0 = *reinterpret_cast<const uint2*>(xb + (size_t)s0 * 128 + cg);
    a0 += bf2f((unsigned short)(v0.x & 0xFFFFu));
    a1 += bf2f((unsigned short)(v0.x >> 16));
    a2 += bf2f((unsigned short)(v0.y & 0xFFFFu));
    a3 += bf2f((unsigned short)(v0.y >> 16));
  }
  a0 += __shfl_down(a0, 32);
  a1 += __shfl_down(a1, 32);
  a2 += __shfl_down(a2, 32);
  a3 += __shfl_down(a3, 32);
  if (half == 0) {
    uint2 o;
    o.x = (unsigned)f2bf(a0) | ((unsigned)f2bf(a1) << 16);
    o.y = (unsigned)f2bf(a2) | ((unsigned)f2bf(a3) << 16);
    *reinterpret_cast<uint2*>(aggb + (size_t)z * NH + (size_t)node * 128 + cg) = o;
  }
}

// lineout = hidden @ line_w^T + line_b
__global__ __launch_bounds__(256) void lineout_k(
    const float* __restrict__ hidden, const float* __restrict__ W,
    const float* __restrict__ b, float* __restrict__ out) {
  __shared__ float Ws[16 * 128];
  for (int i = threadIdx.x; i < 2048; i += 256) Ws[i] = W[i];
  __syncthreads();
  int r = threadIdx.x >> 4, c = threadIdx.x & 15;
  int n = blockIdx.x * 16 + r;
  if (n >= N_NODES) return;
  const float* h = hidden + (size_t)n * 128;
  const float* w = Ws + c * 128;
  float acc = 0.f;
#pragma unroll 8
  for (int k = 0; k < 128; k++) acc += h[k] * w[k];
  out[(size_t)n * 16 + c] = acc + b[c];
}

// gate[n] = hidden[n] . gate_w + gate_b
__global__ __launch_bounds__(256) void gate_k(
    const float* __restrict__ hidden, const float* __restrict__ gw,
    const float* __restrict__ gb, float* __restrict__ gate) {
  int wid = (blockIdx.x * 256 + threadIdx.x) >> 6;
  int lane = threadIdx.x & 63;
  if (wid >= N_NODES) return;
  const float* h = hidden + (size_t)wid * 128;
  float s = h[lane] * gw[lane] + h[64 + lane] * gw[64 + lane];
#pragma unroll
  for (int off = 32; off; off >>= 1) s += __shfl_down(s, off);
  if (lane == 0) gate[wid] = s + gb[0];
}

// gs[g] = lower_bound(batch, g)
__global__ void graph_start_k(const int* __restrict__ batch, int* __restrict__ gs) {
  int g = threadIdx.x;
  if (g > 512) return;
  if (g == 512) {
    gs[512] = N_NODES;
    return;
  }
  int lo = 0, hi = N_NODES;
  while (lo < hi) {
    int mid = (lo + hi) >> 1;
    if (batch[mid] < g) lo = mid + 1;
    else hi = mid;
  }
  gs[g] = lo;
}

// ---------------------------------------------------------------------------
// Per-graph attention pool (batch sorted, no atomics)
// ---------------------------------------------------------------------------
__global__ __launch_bounds__(256) void pool_fused_k(
    const float* __restrict__ hidden, const float* __restrict__ gate,
    const int* __restrict__ gs, float* __restrict__ ex,
    float* __restrict__ pooled) {
  const int g = blockIdx.x;
  const int beg = gs[g], end = gs[g + 1];
  const int tid = threadIdx.x, lane = tid & 63, wv = tid >> 6;
  __shared__ float red[4];
  __shared__ float sval;
  __shared__ float colbuf[256];

  if (end <= beg) {
    if (tid < 128) pooled[(size_t)g * 128 + tid] = 0.f;
    return;
  }
  float m = -3.4e38f;
  for (int n = beg + tid; n < end; n += 256) m = fmaxf(m, gate[n]);
#pragma unroll
  for (int off = 32; off; off >>= 1) m = fmaxf(m, __shfl_down(m, off));
  if (lane == 0) red[wv] = m;
  __syncthreads();
  if (tid == 0) sval = fmaxf(fmaxf(red[0], red[1]), fmaxf(red[2], red[3]));
  __syncthreads();
  const float mx = sval;
  float s = 0.f;
  for (int n = beg + tid; n < end; n += 256) {
    float e = __expf(gate[n] - mx);
    ex[n] = e;
    s += e;
  }
#pragma unroll
  for (int off = 32; off; off >>= 1) s += __shfl_down(s, off);
  if (lane == 0) red[wv] = s;
  __syncthreads();
  if (tid == 0) sval = red[0] + red[1] + red[2] + red[3];
  __syncthreads();
  const float denom = sval;
  const int col = tid & 127, half = tid >> 7;
  float acc = 0.f;
  for (int n = beg + half; n < end; n += 2)
    acc += ex[n] * hidden[(size_t)n * 128 + col];
  colbuf[tid] = acc;
  __syncthreads();
  if (tid < 128)
    pooled[(size_t)g * 128 + tid] = (colbuf[tid] + colbuf[tid + 128]) / denom;
}

__global__ void mlp1_k(const float* __restrict__ pooled, const float* __restrict__ w,
                       const float* __restrict__ b, float* __restrict__ h1) {
  int g = blockIdx.x, j = threadIdx.x;
  const float* p = pooled + (size_t)g * 128;
  const float* wr = w + (size_t)j * 128;
  float acc = 0.f;
#pragma unroll 8
  for (int k = 0; k < 128; k++) acc += p[k] * wr[k];
  acc += b[j];
  h1[g * 64 + j] = acc > 0.f ? acc : 0.f;
}

__global__ void mlp2_k(const float* __restrict__ h1, const float* __restrict__ w,
                       const float* __restrict__ b, float* __restrict__ h2) {
  int g = blockIdx.x, j = threadIdx.x;
  const float* p = h1 + (size_t)g * 64;
  const float* wr = w + (size_t)j * 64;
  float acc = 0.f;
#pragma unroll 8
  for (int k = 0; k < 64; k++) acc += p[k] * wr[k];
  acc += b[j];
  h2[g * 64 + j] = acc > 0.f ? acc : 0.f;
}

__global__ void outhead_k(const float* __restrict__ h2, const float* __restrict__ w,
                          const float* __restrict__ b, float* __restrict__ out) {
  int g = blockIdx.x, j = threadIdx.x;
  if (j >= 16) return;
  const float* p = h2 + (size_t)g * 64;
  const float* wr = w + (size_t)j * 64;
  float acc = 0.f;
#pragma unroll 8
  for (int k = 0; k < 64; k++) acc += p[k] * wr[k];
  out[g * 16 + j] = acc + b[j];
}

extern "C" void kernel_launch(void* const* d_in, const int* in_sizes, int n_in,
                              void* d_out, int out_size, void* d_ws, size_t ws_size,
                              hipStream_t stream) {
  const float* node_embed = (const float*)d_in[0];
  const int* eidx = (const int*)d_in[1];
  const int* batch = (const int*)d_in[2];
  const float* node_w = (const float*)d_in[3];
  const float* node_b = (const float*)d_in[4];
  const float* ggc_w = (const float*)d_in[5];
  const float* w_ih = (const float*)d_in[6];
  const float* w_hh = (const float*)d_in[7];
  const float* b_ih = (const float*)d_in[8];
  const float* b_hh = (const float*)d_in[9];
  const float* cat_w = (const float*)d_in[10];
  const float* cat_b = (const float*)d_in[11];
  const float* gate_w = (const float*)d_in[12];
  const float* gate_b = (const float*)d_in[13];
  const float* mlp_w1 = (const float*)d_in[14];
  const float* mlp_b1 = (const float*)d_in[15];
  const float* mlp_w2 = (const float*)d_in[16];
  const float* mlp_b2 = (const float*)d_in[17];
  const float* out_w = (const float*)d_in[18];
  const float* out_b = (const float*)d_in[19];
  const float* line_w = (const float*)d_in[20];
  const float* line_b = (const float*)d_in[21];

  const int* src = eidx;
  const int* dst = eidx + N_EDGES;

  // workspace ~254 MB (same extent as proven round-8 layout)
  float* hidden = (float*)d_ws;
  unsigned short* h0b = (unsigned short*)(hidden + (size_t)NH);
  unsigned short* X0 = h0b + (size_t)NH;
  unsigned short* X1 = X0 + (size_t)2 * NH;
  unsigned short* aggb = X1 + (size_t)2 * NH;
  unsigned short* wctb = aggb + (size_t)2 * NH;     // 16*384*128
  unsigned short* whhb = wctb + 16 * 384 * 128;     // 4*384*128
  unsigned short* wcatb = whhb + 4 * 384 * 128;     // 128*512
  int* offsets = (int*)(wcatb + 128 * 512);         // [N+1]
  int* cursor = offsets + N_NODES + 1;              // [N]
  int* srcs_sorted = cursor + N_NODES;              // [E]
  int* bsum = srcs_sorted + N_EDGES;                // [512]
  int* gs = bsum + 512;                             // [513]
  float* WcTf = (float*)aggb;                       // fp32 staging overlay (pre-loop)

  float* out_graph = (float*)d_out;
  float* out_line = (float*)d_out + 512 * 16;

  dim3 blk(256);
  const int gM128 = (N_NODES + 127) / 128;
  const int gM64 = (N_NODES + 63) / 64;
  const int gE = (N_EDGES + 255) / 256;
  const int nScanBlk = (N_NODES + 255) / 256;
  const int nRowTiles = N_NODES / 16;  // 6250, exact
  const size_t S = (size_t)384 * 128;

  // ---- CSR build ----
  hipMemsetAsync(cursor, 0, N_NODES * sizeof(int), stream);
  deg_hist_k<<<gE, blk, 0, stream>>>(dst, cursor);
  scan1_k<<<nScanBlk, blk, 0, stream>>>(cursor, offsets, bsum);
  scan2_k<<<1, 512, 0, stream>>>(bsum, nScanBlk);
  scan3_k<<<nScanBlk, blk, 0, stream>>>(offsets, bsum);
  copy_int_k<<<(N_NODES + 255) / 256, blk, 0, stream>>>(offsets, cursor, N_NODES);
  fill_k<<<gE, blk, 0, stream>>>(src, dst, cursor, srcs_sorted);
  graph_start_k<<<1, 576, 0, stream>>>(batch, gs);

  // ---- weights: WcT fold -> bf16; w_hh, cat_w -> bf16 ----
  gemm_wct_k<<<dim3(3, 2, 16), blk, 0, stream>>>(w_ih, ggc_w, WcTf);
  f2b_k<<<(16 * 384 * 128 / 4 + 255) / 256, blk, 0, stream>>>(WcTf, wctb, 16 * 384 * 128);
  f2b_k<<<(4 * 384 * 128 / 4 + 255) / 256, blk, 0, stream>>>(w_hh, whhb, 4 * 384 * 128);
  f2b_k<<<(128 * 512 / 4 + 255) / 256, blk, 0, stream>>>(cat_w, wcatb, 128 * 512);

  // ---- h0b = bf16(node_embed @ node_w^T + node_b) ----
  gemm_h0_k<<<dim3(gM128, 2), blk, 0, stream>>>(node_embed, node_w, node_b, h0b, N_NODES);

  // ---- 2 pairs of independent GGC chains, 2-way batched ----
  const int gGather2 = (2 * N_NODES * 64 + 255) / 256;
  const int gGather1 = (N_NODES * 64 + 255) / 256;
  const dim3 gruGrid(200, 8, 2);  // gridDim.x % 8 == 0 -> col-tiles share XCD
  for (int p = 0; p < 2; p++) {
    const float* bih_p = b_ih + (size_t)p * 2 * 384;
    const float* bhh_p = b_hh + (size_t)p * 2 * 384;
    const unsigned short* whh_p = whhb + (size_t)p * 2 * S;
    for (int i = 0; i < 4; i++) {
      const unsigned short* wct_pi = wctb + ((size_t)8 * p + i) * S;
      const unsigned short* xin;
      size_t xs;
      unsigned short* xout;
      if (i == 0) { xin = h0b; xs = 0; xout = X0; }
      else if (i == 1) { xin = X0; xs = NH; xout = X1; }
      else if (i == 2) { xin = X1; xs = NH; xout = X0; }
      else { xin = X0; xs = NH; xout = X1; }
      // step 0: both chains share the same input -> gather once, agg_zs=0
      const size_t agg_zs = (i == 0) ? 0 : (size_t)NH;
      gather5_k<<<(i == 0 ? gGather1 : gGather2), blk, 0, stream>>>(
          xin, xs, offsets, srcs_sorted, aggb, (i == 0 ? 1 : 2));
      if (i < 3)
        gru_mfma6_k<false><<<gruGrid, blk, 0, stream>>>(
            aggb, agg_zs, xin, xs, h0b, wct_pi, 4 * S, whh_p, S, bih_p, bhh_p,
            xout, nRowTiles);
      else
        gru_mfma6_k<true><<<gruGrid, blk, 0, stream>>>(
            aggb, agg_zs, xin, xs, h0b, wct_pi, 4 * S, whh_p, S, bih_p, bhh_p,
            xout, nRowTiles);
    }
    cat_mfma2_k<<<dim3(gM64, 4), blk, 0, stream>>>(X1, wcatb, cat_b, hidden, N_NODES, p);
  }

  // ---- heads ----
  lineout_k<<<(N_NODES + 15) / 16, blk, 0, stream>>>(hidden, line_w, line_b, out_line);

  float* gate = (float*)X0;
  float* ex = (float*)X0 + N_NODES;
  float* pooled = (float*)aggb;
  float* h1 = pooled + 512 * 128;
  float* h2 = h1 + 512 * 64;

  gate_k<<<(N_NODES * 64 + 255) / 256, blk, 0, stream>>>(hidden, gate_w, gate_b, gate);
  pool_fused_k<<<512, blk, 0, stream>>>(hidden, gate, gs, ex, pooled);
  mlp1_k<<<512, 64, 0, stream>>>(pooled, mlp_w1, mlp_b1, h1);
  mlp2_k<<<512, 64, 0, stream>>>(h1, mlp_w2, mlp_b2, h2);
  outhead_k<<<512, 64, 0, stream>>>(h2, out_w, out_b, out_graph);
}

// Round 11
// 2296.363 us; speedup vs baseline: 26.4886x; 1.1200x over previous
//
#include <hip/hip_runtime.h>

#define N_NODES 100000
#define N_EDGES 1600000
#define HD 128
#define NH (N_NODES * HD)

typedef __attribute__((ext_vector_type(8))) short bf16x8;
typedef __attribute__((ext_vector_type(4))) float f32x4;

__device__ inline unsigned short f2bf(float f) {
  unsigned u = __float_as_uint(f);
  unsigned r = (u + 0x7FFFu + ((u >> 16) & 1u)) >> 16;
  return (unsigned short)r;
}
__device__ inline float bf2f(unsigned short b) {
  return __uint_as_float(((unsigned)b) << 16);
}
__device__ inline float sigm_f(float x) {
  return __builtin_amdgcn_rcpf(1.f + __expf(-x));
}
__device__ inline float tanh_f(float x) {
  return 1.f - 2.f * __builtin_amdgcn_rcpf(__expf(2.f * x) + 1.f);
}

// ---------------------------------------------------------------------------
// h0 GEMM: h0b = bf16(node_embed @ node_w^T + node_b)
// ---------------------------------------------------------------------------
__global__ __launch_bounds__(256) void gemm_h0_k(
    const float* __restrict__ A, const float* __restrict__ B,
    const float* __restrict__ bias, unsigned short* __restrict__ Cb, int M) {
  __shared__ float As[16][132];
  __shared__ float Bs[16][68];
  const int tid = threadIdx.x;
  const int row0 = blockIdx.x * 128;
  const int col0 = blockIdx.y * 64;
  const int tx = tid & 15, ty = tid >> 4;

  float acc[8][4];
#pragma unroll
  for (int i = 0; i < 8; i++)
#pragma unroll
    for (int j = 0; j < 4; j++) acc[i][j] = 0.f;

  const int lr = tid >> 2;
  const int kg = (tid & 3) * 4;

  for (int k0 = 0; k0 < 128; k0 += 16) {
#pragma unroll
    for (int h = 0; h < 2; ++h) {
      int r = lr + h * 64;
      float4 v = make_float4(0.f, 0.f, 0.f, 0.f);
      if (row0 + r < M)
        v = *reinterpret_cast<const float4*>(A + (size_t)(row0 + r) * 128 + k0 + kg);
      As[kg + 0][r] = v.x;
      As[kg + 1][r] = v.y;
      As[kg + 2][r] = v.z;
      As[kg + 3][r] = v.w;
    }
    {
      int c = lr;
      float4 v = *reinterpret_cast<const float4*>(B + (size_t)(col0 + c) * 128 + k0 + kg);
      Bs[kg + 0][c] = v.x;
      Bs[kg + 1][c] = v.y;
      Bs[kg + 2][c] = v.z;
      Bs[kg + 3][c] = v.w;
    }
    __syncthreads();
#pragma unroll
    for (int kk = 0; kk < 16; ++kk) {
      float a[8], b[4];
#pragma unroll
      for (int i = 0; i < 8; i++) a[i] = As[kk][ty * 8 + i];
#pragma unroll
      for (int j = 0; j < 4; j++) b[j] = Bs[kk][tx * 4 + j];
#pragma unroll
      for (int i = 0; i < 8; i++)
#pragma unroll
        for (int j = 0; j < 4; j++) acc[i][j] += a[i] * b[j];
    }
    __syncthreads();
  }

#pragma unroll
  for (int i = 0; i < 8; i++) {
    int r = row0 + ty * 8 + i;
    if (r < M) {
#pragma unroll
      for (int j = 0; j < 4; j++) {
        int c = col0 + tx * 4 + j;
        Cb[(size_t)r * 128 + c] = f2bf(acc[i][j] + bias[c]);
      }
    }
  }
}

// ---------------------------------------------------------------------------
// Batched WcT fold: C[z] = w_ih[z>>2] @ ggc_w[z]^T   ([384,128] each, z=0..15)
// ---------------------------------------------------------------------------
__global__ __launch_bounds__(256) void gemm_wct_k(
    const float* __restrict__ w_ih, const float* __restrict__ ggc_w,
    float* __restrict__ Cout) {
  const int z = blockIdx.z;
  const float* A = w_ih + (size_t)(z >> 2) * 384 * 128;
  const float* B = ggc_w + (size_t)z * 128 * 128;
  float* C = Cout + (size_t)z * 384 * 128;
  __shared__ float As[16][132];
  __shared__ float Bs[16][68];
  const int tid = threadIdx.x;
  const int row0 = blockIdx.x * 128;
  const int col0 = blockIdx.y * 64;
  const int tx = tid & 15, ty = tid >> 4;

  float acc[8][4];
#pragma unroll
  for (int i = 0; i < 8; i++)
#pragma unroll
    for (int j = 0; j < 4; j++) acc[i][j] = 0.f;

  const int lr = tid >> 2;
  const int kg = (tid & 3) * 4;

  for (int k0 = 0; k0 < 128; k0 += 16) {
#pragma unroll
    for (int h = 0; h < 2; ++h) {
      int r = lr + h * 64;
      float4 v = *reinterpret_cast<const float4*>(A + (size_t)(row0 + r) * 128 + k0 + kg);
      As[kg + 0][r] = v.x;
      As[kg + 1][r] = v.y;
      As[kg + 2][r] = v.z;
      As[kg + 3][r] = v.w;
    }
    {
      int c = lr;
      float4 v = *reinterpret_cast<const float4*>(B + (size_t)(col0 + c) * 128 + k0 + kg);
      Bs[kg + 0][c] = v.x;
      Bs[kg + 1][c] = v.y;
      Bs[kg + 2][c] = v.z;
      Bs[kg + 3][c] = v.w;
    }
    __syncthreads();
#pragma unroll
    for (int kk = 0; kk < 16; ++kk) {
      float a[8], b[4];
#pragma unroll
      for (int i = 0; i < 8; i++) a[i] = As[kk][ty * 8 + i];
#pragma unroll
      for (int j = 0; j < 4; j++) b[j] = Bs[kk][tx * 4 + j];
#pragma unroll
      for (int i = 0; i < 8; i++)
#pragma unroll
        for (int j = 0; j < 4; j++) acc[i][j] += a[i] * b[j];
    }
    __syncthreads();
  }

#pragma unroll
  for (int i = 0; i < 8; i++) {
    int r = row0 + ty * 8 + i;
#pragma unroll
    for (int j = 0; j < 4; j++) {
      int c = col0 + tx * 4 + j;
      C[(size_t)r * 128 + c] = acc[i][j];
    }
  }
}

// ---------------------------------------------------------------------------
// float -> bf16, 4 elems/thread
// ---------------------------------------------------------------------------
__global__ __launch_bounds__(256) void f2b_k(const float* __restrict__ a,
                                             unsigned short* __restrict__ b, int n) {
  int i = blockIdx.x * 256 + threadIdx.x;
  if (i * 4 >= n) return;
  float4 v = reinterpret_cast<const float4*>(a)[i];
  ushort4 o;
  o.x = f2bf(v.x);
  o.y = f2bf(v.y);
  o.z = f2bf(v.z);
  o.w = f2bf(v.w);
  reinterpret_cast<ushort4*>(b)[i] = o;
}

// ---------------------------------------------------------------------------
// GRU v7: 4-way chain-batched (blockIdx.y = chain), IN-PLACE state update.
// Block = 512 thr = 8 waves; wave w owns cols w*16..w*16+15 for the block's
// current 16-row tile; block covers ALL 128 cols -> in-place is safe with one
// __syncthreads() between the (cross-col) fragment loads/MFMAs and the
// (per-col) epilogue stores. 24 weight fragments persistent per wave.
//   LAST=0: X[idx] = bf16(x_new);  LAST=1: X[idx] = bf16(x_new + h0b)
// ---------------------------------------------------------------------------
template <bool LAST>
__global__ __launch_bounds__(512) void gru_mfma7_k(
    const unsigned short* __restrict__ agg_base, size_t agg_zs,
    const unsigned short* __restrict__ xb_base, size_t xb_zs,
    const unsigned short* __restrict__ h0b,
    const unsigned short* __restrict__ wct_base, size_t wct_zs,
    const unsigned short* __restrict__ whh_base, size_t whh_zs,
    const float* __restrict__ bih_base, const float* __restrict__ bhh_base,
    unsigned short* __restrict__ Xout, int nRowTiles) {
  const int z = blockIdx.y;
  const unsigned short* agg = agg_base + (size_t)z * agg_zs;
  const unsigned short* xb = xb_base + (size_t)z * xb_zs;
  unsigned short* out = Xout + (size_t)z * NH;
  const unsigned short* wctb = wct_base + (size_t)z * wct_zs;
  const unsigned short* whhb = whh_base + (size_t)z * whh_zs;
  const float* b_ih = bih_base + z * 384;
  const float* b_hh = bhh_base + z * 384;

  const int lane = threadIdx.x & 63;
  const int wave = threadIdx.x >> 6;  // 0..7 -> col tile
  const int lrow = lane & 15;
  const int kblk = lane >> 4;  // 0..3
  const int c = wave * 16 + lrow;

  bf16x8 wf[6][4];
#pragma unroll
  for (int s = 0; s < 3; s++)
#pragma unroll
    for (int kk = 0; kk < 4; kk++) {
      size_t off = (size_t)(s * 128 + c) * 128 + kk * 32 + kblk * 8;
      wf[s][kk] = *reinterpret_cast<const bf16x8*>(wctb + off);
      wf[s + 3][kk] = *reinterpret_cast<const bf16x8*>(whhb + off);
    }
  const float bi0 = b_ih[c], bi1 = b_ih[128 + c], bi2 = b_ih[256 + c];
  const float bh0 = b_hh[c], bh1 = b_hh[128 + c], bh2 = b_hh[256 + c];

  for (int rt = blockIdx.x; rt < nRowTiles; rt += gridDim.x) {
    const int row0 = rt * 16;  // N_NODES % 16 == 0 -> rows in-bounds
    const size_t abase = (size_t)(row0 + lrow) * 128 + kblk * 8;

    f32x4 acc[6];
#pragma unroll
    for (int s = 0; s < 6; s++) acc[s] = (f32x4)(0.f);
#pragma unroll
    for (int kk = 0; kk < 4; kk++) {
      bf16x8 a_ag = *reinterpret_cast<const bf16x8*>(agg + abase + kk * 32);
      bf16x8 a_x = *reinterpret_cast<const bf16x8*>(xb + abase + kk * 32);
      acc[0] = __builtin_amdgcn_mfma_f32_16x16x32_bf16(a_ag, wf[0][kk], acc[0], 0, 0, 0);
      acc[1] = __builtin_amdgcn_mfma_f32_16x16x32_bf16(a_ag, wf[1][kk], acc[1], 0, 0, 0);
      acc[2] = __builtin_amdgcn_mfma_f32_16x16x32_bf16(a_ag, wf[2][kk], acc[2], 0, 0, 0);
      acc[3] = __builtin_amdgcn_mfma_f32_16x16x32_bf16(a_x, wf[3][kk], acc[3], 0, 0, 0);
      acc[4] = __builtin_amdgcn_mfma_f32_16x16x32_bf16(a_x, wf[4][kk], acc[4], 0, 0, 0);
      acc[5] = __builtin_amdgcn_mfma_f32_16x16x32_bf16(a_x, wf[5][kk], acc[5], 0, 0, 0);
    }
    // all cross-col reads of this tile are consumed; make stores safe
    __syncthreads();
    // C/D: col = lane&15 (= lrow -> c), row = kblk*4 + r
#pragma unroll
    for (int r = 0; r < 4; r++) {
      int orow = row0 + kblk * 4 + r;
      size_t idx = (size_t)orow * 128 + c;
      float ir = acc[0][r] + bi0;
      float iz = acc[1][r] + bi1;
      float in_ = acc[2][r] + bi2;
      float hr = acc[3][r] + bh0;
      float hz = acc[4][r] + bh1;
      float hn = acc[5][r] + bh2;
      float rg = sigm_f(ir + hr);
      float zg = sigm_f(iz + hz);
      float ng = tanh_f(in_ + rg * hn);
      float h = bf2f(xb[idx]);  // own column: written only by this lane, below
      float nv = (1.f - zg) * ng + zg * h;
      if (LAST) nv += bf2f(h0b[idx]);
      out[idx] = f2bf(nv);
    }
  }
}

// ---------------------------------------------------------------------------
// cat full: hidden = concat(X[0..3]) @ cat_w^T + cat_b  (K=512, one pass)
// ---------------------------------------------------------------------------
__global__ __launch_bounds__(256) void cat_full_k(
    const unsigned short* __restrict__ X,      // [4][NH] (outs, residual fused)
    const unsigned short* __restrict__ wcatb,  // [128][512]
    const float* __restrict__ cat_b, float* __restrict__ hidden, int M) {
  const int lane = threadIdx.x & 63;
  const int wave = threadIdx.x >> 6;
  const int row0 = blockIdx.x * 64 + wave * 16;
  const int c0 = blockIdx.y * 32;
  const int lrow = lane & 15;
  const int kb = lane >> 4;
  int arow = row0 + lrow;
  if (arow >= M) arow = M - 1;

  f32x4 acc[2];
  acc[0] = (f32x4)(0.f);
  acc[1] = (f32x4)(0.f);
#pragma unroll
  for (int kk = 0; kk < 16; kk++) {
    const unsigned short* ob = X + (size_t)(kk >> 2) * NH;
    bf16x8 a = *reinterpret_cast<const bf16x8*>(
        ob + (size_t)arow * 128 + (kk & 3) * 32 + kb * 8);
#pragma unroll
    for (int t = 0; t < 2; t++) {
      bf16x8 b = *reinterpret_cast<const bf16x8*>(
          wcatb + (size_t)(c0 + t * 16 + lrow) * 512 + (kk >> 2) * 128 +
          (kk & 3) * 32 + kb * 8);
      acc[t] = __builtin_amdgcn_mfma_f32_16x16x32_bf16(a, b, acc[t], 0, 0, 0);
    }
  }
#pragma unroll
  for (int r = 0; r < 4; r++) {
    int orow = row0 + kb * 4 + r;
    if (orow >= M) continue;
#pragma unroll
    for (int t = 0; t < 2; t++) {
      int c = c0 + t * 16 + lrow;
      hidden[(size_t)orow * 128 + c] = acc[t][r] + cat_b[c];
    }
  }
}

// ---------------------------------------------------------------------------
// CSR build
// ---------------------------------------------------------------------------
__global__ __launch_bounds__(256) void deg_hist_k(const int* __restrict__ dst,
                                                  int* __restrict__ deg) {
  int e = blockIdx.x * 256 + threadIdx.x;
  if (e >= N_EDGES) return;
  atomicAdd(&deg[dst[e]], 1);
}

__global__ __launch_bounds__(256) void scan1_k(const int* __restrict__ deg,
                                               int* __restrict__ offsets,
                                               int* __restrict__ bsum) {
  __shared__ int buf[256];
  int tid = threadIdx.x;
  int idx = blockIdx.x * 256 + tid;
  int v = (idx < N_NODES) ? deg[idx] : 0;
  buf[tid] = v;
  __syncthreads();
  for (int off = 1; off < 256; off <<= 1) {
    int t = (tid >= off) ? buf[tid - off] : 0;
    __syncthreads();
    buf[tid] += t;
    __syncthreads();
  }
  if (idx < N_NODES) offsets[idx] = buf[tid] - v;
  if (tid == 255) bsum[blockIdx.x] = buf[255];
}

__global__ __launch_bounds__(512) void scan2_k(int* __restrict__ bsum, int nb) {
  __shared__ int buf[512];
  int tid = threadIdx.x;
  int v = (tid < nb) ? bsum[tid] : 0;
  buf[tid] = v;
  __syncthreads();
  for (int off = 1; off < 512; off <<= 1) {
    int t = (tid >= off) ? buf[tid - off] : 0;
    __syncthreads();
    buf[tid] += t;
    __syncthreads();
  }
  if (tid < nb) bsum[tid] = buf[tid] - v;
}

__global__ __launch_bounds__(256) void scan3_k(int* __restrict__ offsets,
                                               const int* __restrict__ bsum) {
  int idx = blockIdx.x * 256 + threadIdx.x;
  if (idx < N_NODES) offsets[idx] += bsum[idx >> 8];
  if (idx == 0) offsets[N_NODES] = N_EDGES;
}

__global__ __launch_bounds__(256) void copy_int_k(const int* __restrict__ a,
                                                  int* __restrict__ b, int n) {
  int i = blockIdx.x * 256 + threadIdx.x;
  if (i < n) b[i] = a[i];
}

__global__ __launch_bounds__(256) void fill_k(const int* __restrict__ src,
                                              const int* __restrict__ dst,
                                              int* __restrict__ cursor,
                                              int* __restrict__ srcs_sorted) {
  int e = blockIdx.x * 256 + threadIdx.x;
  if (e >= N_EDGES) return;
  int pos = atomicAdd(&cursor[dst[e]], 1);
  srcs_sorted[pos] = src[e];
}

// ---------------------------------------------------------------------------
// gather: nz chains (1 or 4), wave per (z,node); lanes split 32/32 over
// even/odd edges; 4 row loads in flight per half-wave.
// ---------------------------------------------------------------------------
__global__ __launch_bounds__(256) void gather5_k(
    const unsigned short* __restrict__ xb_base, size_t xstride,
    const int* __restrict__ offsets, const int* __restrict__ srcs,
    unsigned short* __restrict__ aggb, int nz) {
  int wid = (blockIdx.x * 256 + threadIdx.x) >> 6;
  int lane = threadIdx.x & 63;
  if (wid >= nz * N_NODES) return;
  int z = 0, node = wid;
  if (node >= 2 * N_NODES) { z = 2; node -= 2 * N_NODES; }
  if (node >= N_NODES) { z += 1; node -= N_NODES; }
  const unsigned short* xb = xb_base + (size_t)z * xstride;
  int beg = offsets[node], end = offsets[node + 1];
  int half = lane >> 5;
  int cg = (lane & 31) * 4;
  float a0 = 0.f, a1 = 0.f, a2 = 0.f, a3 = 0.f;
  int e = beg + half;
  for (; e + 6 < end; e += 8) {
    int s0 = srcs[e], s1 = srcs[e + 2], s2 = srcs[e + 4], s3 = srcs[e + 6];
    uint2 v0 = *reinterpret_cast<const uint2*>(xb + (size_t)s0 * 128 + cg);
    uint2 v1 = *reinterpret_cast<const uint2*>(xb + (size_t)s1 * 128 + cg);
    uint2 v2 = *reinterpret_cast<const uint2*>(xb + (size_t)s2 * 128 + cg);
    uint2 v3 = *reinterpret_cast<const uint2*>(xb + (size_t)s3 * 128 + cg);
    a0 += bf2f((unsigned short)(v0.x & 0xFFFFu)) + bf2f((unsigned short)(v1.x & 0xFFFFu)) +
          bf2f((unsigned short)(v2.x & 0xFFFFu)) + bf2f((unsigned short)(v3.x & 0xFFFFu));
    a1 += bf2f((unsigned short)(v0.x >> 16)) + bf2f((unsigned short)(v1.x >> 16)) +
          bf2f((unsigned short)(v2.x >> 16)) + bf2f((unsigned short)(v3.x >> 16));
    a2 += bf2f((unsigned short)(v0.y & 0xFFFFu)) + bf2f((unsigned short)(v1.y & 0xFFFFu)) +
          bf2f((unsigned short)(v2.y & 0xFFFFu)) + bf2f((unsigned short)(v3.y & 0xFFFFu));
    a3 += bf2f((unsigned short)(v0.y >> 16)) + bf2f((unsigned short)(v1.y >> 16)) +
          bf2f((unsigned short)(v2.y >> 16)) + bf2f((unsigned short)(v3.y >> 16));
  }
  for (; e < end; e += 2) {
    int s0 = srcs[e];
    uint2 v0 = *reinterpret_cast<const uint2*>(xb + (size_t)s0 * 128 + cg);
    a0 += bf2f((unsigned short)(v0.x & 0xFFFFu));
    a1 += bf2f((unsigned short)(v0.x >> 16));
    a2 += bf2f((unsigned short)(v0.y & 0xFFFFu));
    a3 += bf2f((unsigned short)(v0.y >> 16));
  }
  a0 += __shfl_down(a0, 32);
  a1 += __shfl_down(a1, 32);
  a2 += __shfl_down(a2, 32);
  a3 += __shfl_down(a3, 32);
  if (half == 0) {
    uint2 o;
    o.x = (unsigned)f2bf(a0) | ((unsigned)f2bf(a1) << 16);
    o.y = (unsigned)f2bf(a2) | ((unsigned)f2bf(a3) << 16);
    *reinterpret_cast<uint2*>(aggb + (size_t)z * NH + (size_t)node * 128 + cg) = o;
  }
}

// lineout = hidden @ line_w^T + line_b
__global__ __launch_bounds__(256) void lineout_k(
    const float* __restrict__ hidden, const float* __restrict__ W,
    const float* __restrict__ b, float* __restrict__ out) {
  __shared__ float Ws[16 * 128];
  for (int i = threadIdx.x; i < 2048; i += 256) Ws[i] = W[i];
  __syncthreads();
  int r = threadIdx.x >> 4, c = threadIdx.x & 15;
  int n = blockIdx.x * 16 + r;
  if (n >= N_NODES) return;
  const float* h = hidden + (size_t)n * 128;
  const float* w = Ws + c * 128;
  float acc = 0.f;
#pragma unroll 8
  for (int k = 0; k < 128; k++) acc += h[k] * w[k];
  out[(size_t)n * 16 + c] = acc + b[c];
}

// gate[n] = hidden[n] . gate_w + gate_b
__global__ __launch_bounds__(256) void gate_k(
    const float* __restrict__ hidden, const float* __restrict__ gw,
    const float* __restrict__ gb, float* __restrict__ gate) {
  int wid = (blockIdx.x * 256 + threadIdx.x) >> 6;
  int lane = threadIdx.x & 63;
  if (wid >= N_NODES) return;
  const float* h = hidden + (size_t)wid * 128;
  float s = h[lane] * gw[lane] + h[64 + lane] * gw[64 + lane];
#pragma unroll
  for (int off = 32; off; off >>= 1) s += __shfl_down(s, off);
  if (lane == 0) gate[wid] = s + gb[0];
}

// gs[g] = lower_bound(batch, g)
__global__ void graph_start_k(const int* __restrict__ batch, int* __restrict__ gs) {
  int g = threadIdx.x;
  if (g > 512) return;
  if (g == 512) {
    gs[512] = N_NODES;
    return;
  }
  int lo = 0, hi = N_NODES;
  while (lo < hi) {
    int mid = (lo + hi) >> 1;
    if (batch[mid] < g) lo = mid + 1;
    else hi = mid;
  }
  gs[g] = lo;
}

// ---------------------------------------------------------------------------
// Per-graph attention pool (batch sorted, no atomics)
// ---------------------------------------------------------------------------
__global__ __launch_bounds__(256) void pool_fused_k(
    const float* __restrict__ hidden, const float* __restrict__ gate,
    const int* __restrict__ gs, float* __restrict__ ex,
    float* __restrict__ pooled) {
  const int g = blockIdx.x;
  const int beg = gs[g], end = gs[g + 1];
  const int tid = threadIdx.x, lane = tid & 63, wv = tid >> 6;
  __shared__ float red[4];
  __shared__ float sval;
  __shared__ float colbuf[256];

  if (end <= beg) {
    if (tid < 128) pooled[(size_t)g * 128 + tid] = 0.f;
    return;
  }
  float m = -3.4e38f;
  for (int n = beg + tid; n < end; n += 256) m = fmaxf(m, gate[n]);
#pragma unroll
  for (int off = 32; off; off >>= 1) m = fmaxf(m, __shfl_down(m, off));
  if (lane == 0) red[wv] = m;
  __syncthreads();
  if (tid == 0) sval = fmaxf(fmaxf(red[0], red[1]), fmaxf(red[2], red[3]));
  __syncthreads();
  const float mx = sval;
  float s = 0.f;
  for (int n = beg + tid; n < end; n += 256) {
    float e = __expf(gate[n] - mx);
    ex[n] = e;
    s += e;
  }
#pragma unroll
  for (int off = 32; off; off >>= 1) s += __shfl_down(s, off);
  if (lane == 0) red[wv] = s;
  __syncthreads();
  if (tid == 0) sval = red[0] + red[1] + red[2] + red[3];
  __syncthreads();
  const float denom = sval;
  const int col = tid & 127, half = tid >> 7;
  float acc = 0.f;
  for (int n = beg + half; n < end; n += 2)
    acc += ex[n] * hidden[(size_t)n * 128 + col];
  colbuf[tid] = acc;
  __syncthreads();
  if (tid < 128)
    pooled[(size_t)g * 128 + tid] = (colbuf[tid] + colbuf[tid + 128]) / denom;
}

__global__ void mlp1_k(const float* __restrict__ pooled, const float* __restrict__ w,
                       const float* __restrict__ b, float* __restrict__ h1) {
  int g = blockIdx.x, j = threadIdx.x;
  const float* p = pooled + (size_t)g * 128;
  const float* wr = w + (size_t)j * 128;
  float acc = 0.f;
#pragma unroll 8
  for (int k = 0; k < 128; k++) acc += p[k] * wr[k];
  acc += b[j];
  h1[g * 64 + j] = acc > 0.f ? acc : 0.f;
}

__global__ void mlp2_k(const float* __restrict__ h1, const float* __restrict__ w,
                       const float* __restrict__ b, float* __restrict__ h2) {
  int g = blockIdx.x, j = threadIdx.x;
  const float* p = h1 + (size_t)g * 64;
  const float* wr = w + (size_t)j * 64;
  float acc = 0.f;
#pragma unroll 8
  for (int k = 0; k < 64; k++) acc += p[k] * wr[k];
  acc += b[j];
  h2[g * 64 + j] = acc > 0.f ? acc : 0.f;
}

__global__ void outhead_k(const float* __restrict__ h2, const float* __restrict__ w,
                          const float* __restrict__ b, float* __restrict__ out) {
  int g = blockIdx.x, j = threadIdx.x;
  if (j >= 16) return;
  const float* p = h2 + (size_t)g * 64;
  const float* wr = w + (size_t)j * 64;
  float acc = 0.f;
#pragma unroll 8
  for (int k = 0; k < 64; k++) acc += p[k] * wr[k];
  out[g * 16 + j] = acc + b[j];
}

extern "C" void kernel_launch(void* const* d_in, const int* in_sizes, int n_in,
                              void* d_out, int out_size, void* d_ws, size_t ws_size,
                              hipStream_t stream) {
  const float* node_embed = (const float*)d_in[0];
  const int* eidx = (const int*)d_in[1];
  const int* batch = (const int*)d_in[2];
  const float* node_w = (const float*)d_in[3];
  const float* node_b = (const float*)d_in[4];
  const float* ggc_w = (const float*)d_in[5];
  const float* w_ih = (const float*)d_in[6];
  const float* w_hh = (const float*)d_in[7];
  const float* b_ih = (const float*)d_in[8];
  const float* b_hh = (const float*)d_in[9];
  const float* cat_w = (const float*)d_in[10];
  const float* cat_b = (const float*)d_in[11];
  const float* gate_w = (const float*)d_in[12];
  const float* gate_b = (const float*)d_in[13];
  const float* mlp_w1 = (const float*)d_in[14];
  const float* mlp_b1 = (const float*)d_in[15];
  const float* mlp_w2 = (const float*)d_in[16];
  const float* mlp_b2 = (const float*)d_in[17];
  const float* out_w = (const float*)d_in[18];
  const float* out_b = (const float*)d_in[19];
  const float* line_w = (const float*)d_in[20];
  const float* line_b = (const float*)d_in[21];

  const int* src = eidx;
  const int* dst = eidx + N_EDGES;

  // workspace ~240 MB:
  // h0b [NH] | X [4][NH] (in-place states, then outs) | agg [4][NH]
  // | wctb | whhb | wcatb | CSR ints
  // overlays: WcTf (fp32, pre-loop) and hidden/pooled/h1/h2 (post-loop) on agg;
  //           gate/ex (post-cat) on X.
  unsigned short* h0b = (unsigned short*)d_ws;
  unsigned short* X = h0b + (size_t)NH;             // 4NH bf16
  unsigned short* aggb = X + (size_t)4 * NH;        // 4NH bf16
  unsigned short* wctb = aggb + (size_t)4 * NH;     // 16*384*128
  unsigned short* whhb = wctb + 16 * 384 * 128;     // 4*384*128
  unsigned short* wcatb = whhb + 4 * 384 * 128;     // 128*512
  int* offsets = (int*)(wcatb + 128 * 512);         // [N+1]
  int* cursor = offsets + N_NODES + 1;              // [N]
  int* srcs_sorted = cursor + N_NODES;              // [E]
  int* bsum = srcs_sorted + N_EDGES;                // [512]
  int* gs = bsum + 512;                             // [513]
  float* WcTf = (float*)aggb;                       // fp32 staging (pre-loop)
  float* hidden = (float*)aggb;                     // post-loop overlay

  float* out_graph = (float*)d_out;
  float* out_line = (float*)d_out + 512 * 16;

  dim3 blk(256);
  const int gM128 = (N_NODES + 127) / 128;
  const int gM64 = (N_NODES + 63) / 64;
  const int gE = (N_EDGES + 255) / 256;
  const int nScanBlk = (N_NODES + 255) / 256;
  const int nRowTiles = N_NODES / 16;  // 6250, exact
  const size_t S = (size_t)384 * 128;

  // ---- CSR build ----
  hipMemsetAsync(cursor, 0, N_NODES * sizeof(int), stream);
  deg_hist_k<<<gE, blk, 0, stream>>>(dst, cursor);
  scan1_k<<<nScanBlk, blk, 0, stream>>>(cursor, offsets, bsum);
  scan2_k<<<1, 512, 0, stream>>>(bsum, nScanBlk);
  scan3_k<<<nScanBlk, blk, 0, stream>>>(offsets, bsum);
  copy_int_k<<<(N_NODES + 255) / 256, blk, 0, stream>>>(offsets, cursor, N_NODES);
  fill_k<<<gE, blk, 0, stream>>>(src, dst, cursor, srcs_sorted);
  graph_start_k<<<1, 576, 0, stream>>>(batch, gs);

  // ---- weights: WcT fold -> bf16; w_hh, cat_w -> bf16 ----
  gemm_wct_k<<<dim3(3, 2, 16), blk, 0, stream>>>(w_ih, ggc_w, WcTf);
  f2b_k<<<(16 * 384 * 128 / 4 + 255) / 256, blk, 0, stream>>>(WcTf, wctb, 16 * 384 * 128);
  f2b_k<<<(4 * 384 * 128 / 4 + 255) / 256, blk, 0, stream>>>(w_hh, whhb, 4 * 384 * 128);
  f2b_k<<<(128 * 512 / 4 + 255) / 256, blk, 0, stream>>>(cat_w, wcatb, 128 * 512);

  // ---- h0b = bf16(node_embed @ node_w^T + node_b) ----
  gemm_h0_k<<<dim3(gM128, 2), blk, 0, stream>>>(node_embed, node_w, node_b, h0b, N_NODES);

  // ---- 4 independent GGC chains, all batched; in-place state in X ----
  const dim3 gruGrid(128, 4);
  for (int i = 0; i < 4; i++) {
    const unsigned short* xin = (i == 0) ? h0b : X;
    const size_t xzs = (i == 0) ? 0 : (size_t)NH;
    const int nz = (i == 0) ? 1 : 4;
    const size_t agg_zs = (i == 0) ? 0 : (size_t)NH;
    gather5_k<<<(nz * N_NODES * 64 + 255) / 256, blk, 0, stream>>>(
        xin, xzs, offsets, srcs_sorted, aggb, nz);
    const unsigned short* wct_i = wctb + (size_t)i * S;  // chain z adds z*4S
    if (i < 3)
      gru_mfma7_k<false><<<gruGrid, 512, 0, stream>>>(
          aggb, agg_zs, xin, xzs, h0b, wct_i, 4 * S, whhb, S, b_ih, b_hh, X,
          nRowTiles);
    else
      gru_mfma7_k<true><<<gruGrid, 512, 0, stream>>>(
          aggb, agg_zs, xin, xzs, h0b, wct_i, 4 * S, whhb, S, b_ih, b_hh, X,
          nRowTiles);
  }

  // ---- hidden = concat(X) @ cat_w^T + cat_b (one K=512 GEMM) ----
  cat_full_k<<<dim3(gM64, 4), blk, 0, stream>>>(X, wcatb, cat_b, hidden, N_NODES);

  // ---- heads ----
  lineout_k<<<(N_NODES + 15) / 16, blk, 0, stream>>>(hidden, line_w, line_b, out_line);

  float* gate = (float*)X;
  float* ex = (float*)X + N_NODES;
  float* pooled = hidden + (size_t)NH;
  float* h1 = pooled + 512 * 128;
  float* h2 = h1 + 512 * 64;

  gate_k<<<(N_NODES * 64 + 255) / 256, blk, 0, stream>>>(hidden, gate_w, gate_b, gate);
  pool_fused_k<<<512, blk, 0, stream>>>(hidden, gate, gs, ex, pooled);
  mlp1_k<<<512, 64, 0, stream>>>(pooled, mlp_w1, mlp_b1, h1);
  mlp2_k<<<512, 64, 0, stream>>>(h1, mlp_w2, mlp_b2, h2);
  outhead_k<<<512, 64, 0, stream>>>(h2, out_w, out_b, out_graph);
}